// Round 7
// baseline (396.119 us; speedup 1.0000x reference)
//
#include <hip/hip_runtime.h>
#include <math.h>

#define N_NODES 50000
#define N_EDGES 800000
#define ETOT    (N_EDGES + N_NODES)   // self-loops appended
#define GGRAPHS 64
#define EPS_BN  1e-5f

typedef __attribute__((ext_vector_type(8))) short short8;
typedef __attribute__((ext_vector_type(4))) float f32x4;
typedef __attribute__((ext_vector_type(2))) float f32x2;

__device__ __forceinline__ unsigned short f2bf(float f) {
    union { float f; unsigned u; } v; v.f = f;
    unsigned r = v.u + 0x7fffu + ((v.u >> 16) & 1u);   // round-nearest-even
    return (unsigned short)(r >> 16);
}
__device__ __forceinline__ float leaky(float e) {
    return fmaxf(e, 0.2f * e);
}
// pack 4 f32 -> 4 fp8 (e4m3, OCP on gfx950)
__device__ __forceinline__ unsigned pack4_fp8(float a, float b, float c, float d) {
    int v = __builtin_amdgcn_cvt_pk_fp8_f32(a, b, 0, false);
    v = __builtin_amdgcn_cvt_pk_fp8_f32(c, d, v, true);
    return (unsigned)v;
}
__device__ __forceinline__ float readlane_f(float v, int l) {
    return __int_as_float(__builtin_amdgcn_readlane(__float_as_int(v), l));
}

// ---------------- prep (x->bf16, W1T, W2T) + hist, merged ----------------

#define XQ (N_NODES * 64 / 4)
#define NPREPB ((XQ + 32768 + 255) / 256)
#define NEDGEB ((ETOT + 255) / 256)

__global__ void k_prep(const float* __restrict__ x, const float* __restrict__ W1,
                       const float* __restrict__ W2, const int* __restrict__ ei,
                       unsigned short* __restrict__ xbf,
                       unsigned short* __restrict__ W1T,
                       unsigned short* __restrict__ W2T,
                       int* __restrict__ cnt) {
    int b = blockIdx.x;
    if (b < NPREPB) {
        int t = b * 256 + threadIdx.x;
        if (t < XQ) {
            float4 v = *(const float4*)&x[t * 4];
            ushort4 o;
            o.x = f2bf(v.x); o.y = f2bf(v.y); o.z = f2bf(v.z); o.w = f2bf(v.w);
            *(ushort4*)&xbf[t * 4] = o;
        } else if (t < XQ + 16384) {
            int i = t - XQ;                 // W1T[n*64+k] = W1[k*256+n]
            int n = i >> 6, k = i & 63;
            W1T[i] = f2bf(W1[k * 256 + n]);
        } else if (t < XQ + 32768) {
            int i = t - XQ - 16384;         // W2T[n*256+k'] = W2[real(k')*64+n]
            int n = i >> 8, kp = i & 255;
            int rk = (kp & 15) * 16 + (kp >> 4);
            W2T[i] = f2bf(W2[rk * 64 + n]);
        }
    } else {
        int e = (b - NPREPB) * 256 + threadIdx.x;
        if (e < ETOT) {
            int d = (e < N_EDGES) ? ei[N_EDGES + e] : (e - N_EDGES);
            atomicAdd(&cnt[d], 1);
        }
    }
}

// ---------------- CSR build (scan + fill) ----------------

__global__ void k_scan_local(const int* __restrict__ cnt, int* __restrict__ offs,
                             int* __restrict__ bsums) {
    __shared__ int s[256];
    int t = threadIdx.x, idx = blockIdx.x * 256 + t;
    int v = (idx < N_NODES) ? cnt[idx] : 0;
    s[t] = v; __syncthreads();
    for (int d2 = 1; d2 < 256; d2 <<= 1) {
        int add = (t >= d2) ? s[t - d2] : 0;
        __syncthreads();
        s[t] += add;
        __syncthreads();
    }
    if (idx < N_NODES) offs[idx] = s[t] - v;       // local exclusive
    if (t == 255) bsums[blockIdx.x] = s[255];
}

__global__ void k_scan_sums(int* __restrict__ bsums, int nb) {
    __shared__ int s[256];
    int t = threadIdx.x;
    int v = (t < nb) ? bsums[t] : 0;
    s[t] = v; __syncthreads();
    for (int d2 = 1; d2 < 256; d2 <<= 1) {
        int add = (t >= d2) ? s[t - d2] : 0;
        __syncthreads();
        s[t] += add;
        __syncthreads();
    }
    if (t < nb) bsums[t] = s[t] - v;               // exclusive
}

__global__ void k_scan_add(int* __restrict__ offs, int* __restrict__ cursor,
                           const int* __restrict__ bsums) {
    int idx = blockIdx.x * 256 + threadIdx.x;
    if (idx < N_NODES) {
        int o = offs[idx] + bsums[blockIdx.x];
        offs[idx] = o;
        cursor[idx] = o;
    }
    if (idx == 0) offs[N_NODES] = ETOT;
}

__global__ void k_fill(const int* __restrict__ ei, int* __restrict__ cursor,
                       int* __restrict__ csr) {
    int e = blockIdx.x * 256 + threadIdx.x;
    if (e >= ETOT) return;
    int s, d;
    if (e < N_EDGES) { s = ei[e]; d = ei[N_EDGES + e]; }
    else             { s = d = e - N_EDGES; }
    int pos = atomicAdd(&cursor[d], 1);
    csr[pos] = s;
}

// ---------------- GEMM1 (MFMA): h1(fp8, perm layout) = x @ W1, scores ----------
// h1 slot s of a row holds real channel (s&15)*16 + (s>>4).

__global__ __launch_bounds__(256)
void k_gemm1(const unsigned short* __restrict__ xbf, const unsigned short* __restrict__ W1Tg,
             const float* __restrict__ a_s, const float* __restrict__ a_d,
             unsigned char* __restrict__ h1f8, float* __restrict__ es1, float* __restrict__ ed1) {
    __shared__ unsigned short W1T[256 * 72];
    int t = threadIdx.x;
    for (int c = t; c < 2048; c += 256) {            // 2048 chunks of 8 bf16
        int n = c >> 3, k8 = (c & 7) * 8;
        *(short8*)&W1T[n * 72 + k8] = *(const short8*)&W1Tg[n * 64 + k8];
    }
    __syncthreads();
    int wid = t >> 6, lane = t & 63;
    int quad = lane >> 4, col = lane & 15;
    float as_r[16], ad_r[16];
#pragma unroll
    for (int i = 0; i < 16; ++i) {
        as_r[i] = a_s[i * 16 + col];
        ad_r[i] = a_d[i * 16 + col];
    }
    int tile = blockIdx.x * 4 + wid;
    if (tile >= 3125) return;
    int base = tile * 16;
    short8 a0 = *(const short8*)&xbf[(size_t)(base + col) * 64 + quad * 8];
    short8 a1 = *(const short8*)&xbf[(size_t)(base + col) * 64 + 32 + quad * 8];
    f32x4 acc[16];
#pragma unroll
    for (int nt = 0; nt < 16; ++nt) acc[nt] = (f32x4){0.f, 0.f, 0.f, 0.f};
#pragma unroll
    for (int nt = 0; nt < 16; ++nt) {
        short8 b0 = *(const short8*)&W1T[(nt * 16 + col) * 72 + quad * 8];
        short8 b1 = *(const short8*)&W1T[(nt * 16 + col) * 72 + 32 + quad * 8];
        acc[nt] = __builtin_amdgcn_mfma_f32_16x16x32_bf16(a0, b0, acc[nt], 0, 0, 0);
        acc[nt] = __builtin_amdgcn_mfma_f32_16x16x32_bf16(a1, b1, acc[nt], 0, 0, 0);
    }
    float esp[16], edp[16];
#pragma unroll
    for (int i = 0; i < 16; ++i) { esp[i] = 0.f; edp[i] = 0.f; }
#pragma unroll
    for (int nt = 0; nt < 16; ++nt) {
        int hd = nt >> 2;
#pragma unroll
        for (int r = 0; r < 4; ++r) {
            esp[hd * 4 + r] += acc[nt][r] * as_r[nt];
            edp[hd * 4 + r] += acc[nt][r] * ad_r[nt];
        }
    }
#pragma unroll
    for (int i = 0; i < 16; ++i) {
        float v = esp[i], w = edp[i];
#pragma unroll
        for (int m = 1; m <= 8; m <<= 1) { v += __shfl_xor(v, m); w += __shfl_xor(w, m); }
        esp[i] = v; edp[i] = w;
    }
    if (col == 0) {
#pragma unroll
        for (int hd = 0; hd < 4; ++hd)
#pragma unroll
            for (int r = 0; r < 4; ++r) {
                int node = base + quad * 4 + r;
                es1[node * 4 + hd] = esp[hd * 4 + r];
                ed1[node * 4 + hd] = edp[hd * 4 + r];
            }
    }
    // h1 fp8 store, permuted: byte slot col*16+nt  (16B vector store per row)
#pragma unroll
    for (int r = 0; r < 4; ++r) {
        uint4 pk;
        pk.x = pack4_fp8(acc[0][r],  acc[1][r],  acc[2][r],  acc[3][r]);
        pk.y = pack4_fp8(acc[4][r],  acc[5][r],  acc[6][r],  acc[7][r]);
        pk.z = pack4_fp8(acc[8][r],  acc[9][r],  acc[10][r], acc[11][r]);
        pk.w = pack4_fp8(acc[12][r], acc[13][r], acc[14][r], acc[15][r]);
        *(uint4*)&h1f8[(size_t)(base + quad * 4 + r) * 256 + col * 16] = pk;
    }
}

// ---------------- GAT1: phase A (weights once/edge) + phase B (gather-FMA) ----
// wave per dst node (4/block); lane owns byte slots lane*4..+3.
// Phase A: lane computes w for edges r*16+(lane>>2), its own head (lane&3).
// Phase B: s via readlane (scalar), w via one bpermute, one 4B load, 4 FMA.

__global__ __launch_bounds__(256)
void k_gat1(const unsigned char* __restrict__ h1f8, const float* __restrict__ es1,
            const float* __restrict__ ed1, const int* __restrict__ offs,
            const int* __restrict__ csr, const float* __restrict__ b1,
            const float* __restrict__ g1, const float* __restrict__ be1,
            const float* __restrict__ m1, const float* __restrict__ v1,
            unsigned short* __restrict__ hb) {
    int wave = threadIdx.x >> 6, lane = threadIdx.x & 63;
    int d = blockIdx.x * 4 + wave;
    if (d >= N_NODES) return;
    int start = offs[d], deg = offs[d + 1] - start;
    int hd = lane & 3;
    float edv = ed1[d * 4 + hd];
    float a0 = 0.f, a1 = 0.f, a2 = 0.f, a3 = 0.f, dn = 0.f;
    for (int c0 = 0; c0 < deg; c0 += 64) {
        int cnt = min(64, deg - c0);
        int csr_reg = csr[start + c0 + min(lane, cnt - 1)];
        // phase A: weights (one exp per edge per head, not per lane)
        float wreg[4];
        int eidx = lane >> 2;
#pragma unroll
        for (int r = 0; r < 4; ++r) {
            int e = r * 16 + eidx;
            int s = __shfl(csr_reg, e);
            float w = 0.f;
            if (e < cnt) w = __expf(leaky(es1[s * 4 + hd] + edv));
            wreg[r] = w;
        }
        // phase B: 4-granular unrolled gather-FMA (zero-w padding)
#pragma unroll
        for (int r = 0; r < 4; ++r) {
#pragma unroll
            for (int q = 0; q < 4; ++q) {
                int jq = r * 16 + q * 4;
                if (jq < cnt) {
#pragma unroll
                    for (int u = 0; u < 4; ++u) {
                        int m = q * 4 + u;                       // compile-time
                        int s = __builtin_amdgcn_readlane(csr_reg, jq + u);
                        float w = __shfl(wreg[r], (m << 2) | hd);
                        unsigned rv = *(const unsigned*)(h1f8 + ((size_t)(unsigned)s << 8) + lane * 4);
                        f32x2 lo = __builtin_amdgcn_cvt_pk_f32_fp8((int)rv, false);
                        f32x2 hi = __builtin_amdgcn_cvt_pk_f32_fp8((int)rv, true);
                        dn += w;
                        a0 += w * lo.x; a1 += w * lo.y;
                        a2 += w * hi.x; a3 += w * hi.y;
                    }
                }
            }
        }
    }
    float inv = 1.f / dn;
    int rc = (lane & 3) * 64 + (lane >> 2);    // real channel for slot lane*4 (+i*16)
    float o0 = a0 * inv + b1[rc];
    float o1 = a1 * inv + b1[rc + 16];
    float o2 = a2 * inv + b1[rc + 32];
    float o3 = a3 * inv + b1[rc + 48];
    o0 = (o0 - m1[rc])      * rsqrtf(v1[rc]      + EPS_BN) * g1[rc]      + be1[rc];
    o1 = (o1 - m1[rc + 16]) * rsqrtf(v1[rc + 16] + EPS_BN) * g1[rc + 16] + be1[rc + 16];
    o2 = (o2 - m1[rc + 32]) * rsqrtf(v1[rc + 32] + EPS_BN) * g1[rc + 32] + be1[rc + 32];
    o3 = (o3 - m1[rc + 48]) * rsqrtf(v1[rc + 48] + EPS_BN) * g1[rc + 48] + be1[rc + 48];
    o0 = (o0 > 0.f) ? o0 : expm1f(o0);
    o1 = (o1 > 0.f) ? o1 : expm1f(o1);
    o2 = (o2 > 0.f) ? o2 : expm1f(o2);
    o3 = (o3 > 0.f) ? o3 : expm1f(o3);
    ushort4 ov;
    ov.x = f2bf(o0); ov.y = f2bf(o1); ov.z = f2bf(o2); ov.w = f2bf(o3);
    *(ushort4*)&hb[(size_t)d * 256 + lane * 4] = ov;   // permuted slot layout
}

// ---------------- GEMM2 (MFMA): h2(fp8, perm) = hb @ W2, scores es2/ed2 --------
// h2 slot s of a row holds real channel (s&3)*16 + (s>>2).

__global__ __launch_bounds__(256)
void k_gemm2(const unsigned short* __restrict__ hbbf, const unsigned short* __restrict__ W2Tg,
             const float* __restrict__ a_s, const float* __restrict__ a_d,
             unsigned char* __restrict__ h2f8, float* __restrict__ es2, float* __restrict__ ed2) {
    __shared__ unsigned short W2T[64 * 264];
    int t = threadIdx.x;
    for (int c = t; c < 2048; c += 256) {            // 2048 chunks of 8 bf16
        int n = c >> 5, k8 = (c & 31) * 8;
        *(short8*)&W2T[n * 264 + k8] = *(const short8*)&W2Tg[n * 256 + k8];
    }
    __syncthreads();
    int wid = t >> 6, lane = t & 63;
    int quad = lane >> 4, col = lane & 15;
    float as_r[4], ad_r[4];
#pragma unroll
    for (int i = 0; i < 4; ++i) {
        as_r[i] = a_s[i * 16 + col];
        ad_r[i] = a_d[i * 16 + col];
    }
    int tile = blockIdx.x * 4 + wid;
    if (tile >= 3125) return;
    int base = tile * 16;
    short8 af[8];
#pragma unroll
    for (int kk = 0; kk < 8; ++kk)
        af[kk] = *(const short8*)&hbbf[(size_t)(base + col) * 256 + kk * 32 + quad * 8];
    f32x4 acc[4];
#pragma unroll
    for (int nt = 0; nt < 4; ++nt) acc[nt] = (f32x4){0.f, 0.f, 0.f, 0.f};
#pragma unroll
    for (int kk = 0; kk < 8; ++kk) {
#pragma unroll
        for (int nt = 0; nt < 4; ++nt) {
            short8 b = *(const short8*)&W2T[(nt * 16 + col) * 264 + kk * 32 + quad * 8];
            acc[nt] = __builtin_amdgcn_mfma_f32_16x16x32_bf16(af[kk], b, acc[nt], 0, 0, 0);
        }
    }
    float esp[4], edp[4];
#pragma unroll
    for (int r = 0; r < 4; ++r) { esp[r] = 0.f; edp[r] = 0.f; }
#pragma unroll
    for (int nt = 0; nt < 4; ++nt)
#pragma unroll
        for (int r = 0; r < 4; ++r) {
            esp[r] += acc[nt][r] * as_r[nt];
            edp[r] += acc[nt][r] * ad_r[nt];
        }
#pragma unroll
    for (int r = 0; r < 4; ++r) {
        float v = esp[r], w = edp[r];
#pragma unroll
        for (int m = 1; m <= 8; m <<= 1) { v += __shfl_xor(v, m); w += __shfl_xor(w, m); }
        esp[r] = v; edp[r] = w;
    }
    if (col == 0) {
#pragma unroll
        for (int r = 0; r < 4; ++r) {
            int node = base + quad * 4 + r;
            es2[node] = esp[r];
            ed2[node] = edp[r];
        }
    }
    // h2 fp8 store, permuted: byte slot col*4+nt (4B store per row)
#pragma unroll
    for (int r = 0; r < 4; ++r) {
        unsigned pk = pack4_fp8(acc[0][r], acc[1][r], acc[2][r], acc[3][r]);
        *(unsigned*)&h2f8[(size_t)(base + quad * 4 + r) * 64 + col * 4] = pk;
    }
}

// ---------------- GAT2: phase A/B, full wave per edge, 1B/lane ----------------
// lane owns byte slot `lane` = real channel (lane&3)*16 + (lane>>2).

__global__ __launch_bounds__(256)
void k_gat2(const unsigned char* __restrict__ h2f8, const float* __restrict__ es2,
            const float* __restrict__ ed2, const int* __restrict__ offs,
            const int* __restrict__ csr, const float* __restrict__ b2,
            const float* __restrict__ g2, const float* __restrict__ be2,
            const float* __restrict__ m2, const float* __restrict__ v2,
            float* __restrict__ out2) {
    int wave = threadIdx.x >> 6, lane = threadIdx.x & 63;
    int d = blockIdx.x * 4 + wave;
    if (d >= N_NODES) return;
    int start = offs[d], deg = offs[d + 1] - start;
    float edv = ed2[d];
    float a = 0.f, dn = 0.f;
    for (int c0 = 0; c0 < deg; c0 += 64) {
        int cnt = min(64, deg - c0);
        int csr_reg = csr[start + c0 + min(lane, cnt - 1)];
        float wr = 0.f;
        if (lane < cnt) wr = __expf(leaky(es2[csr_reg] + edv));
#pragma unroll
        for (int q = 0; q < 16; ++q) {
            int jq = q * 4;
            if (jq < cnt) {
#pragma unroll
                for (int u = 0; u < 4; ++u) {
                    int s = __builtin_amdgcn_readlane(csr_reg, jq + u);
                    float w = readlane_f(wr, jq + u);
                    unsigned char rv = *(h2f8 + ((size_t)(unsigned)s << 6) + lane);
                    f32x2 lo = __builtin_amdgcn_cvt_pk_f32_fp8((int)rv, false);
                    dn += w;
                    a += w * lo.x;
                }
            }
        }
    }
    float inv = 1.f / dn;
    int rc = (lane & 3) * 16 + (lane >> 2);
    float o = a * inv + b2[rc];
    o = (o - m2[rc]) * rsqrtf(v2[rc] + EPS_BN) * g2[rc] + be2[rc];
    out2[(size_t)d * 64 + lane] = o;     // slot layout (same mapping as before)
}

// ---------------- mean pool per graph (slot layout, channel-agnostic) --------

__device__ int lower_bound_i(const int* a, int n, int key) {
    int lo = 0, hi = n;
    while (lo < hi) {
        int mid = (lo + hi) >> 1;
        if (a[mid] < key) lo = mid + 1; else hi = mid;
    }
    return lo;
}

__global__ __launch_bounds__(256)
void k_pool(const float* __restrict__ out2, const int* __restrict__ batch,
            float* __restrict__ pooled) {
    int g = blockIdx.x;
    __shared__ int ssh[2];
    __shared__ float red[256];
    if (threadIdx.x == 0) {
        ssh[0] = lower_bound_i(batch, N_NODES, g);
        ssh[1] = lower_bound_i(batch, N_NODES, g + 1);
    }
    __syncthreads();
    int start = ssh[0], end = ssh[1];
    int t = threadIdx.x, sub = t >> 6, lane = t & 63;
    float acc = 0.f;
    for (int i = start + sub; i < end; i += 4) acc += out2[(size_t)i * 64 + lane];
    red[t] = acc; __syncthreads();
    if (t < 64) {
        float s = red[t] + red[t + 64] + red[t + 128] + red[t + 192];
        int cnt = end - start;
        pooled[g * 64 + t] = s / (float)((cnt > 0) ? cnt : 1);
    }
}

// ---------------- MLP head + log_softmax (maps slots -> real channels) -------

__global__ void k_head(const float* __restrict__ pooled, const float* __restrict__ lw1,
                       const float* __restrict__ lb1, const float* __restrict__ lw2,
                       const float* __restrict__ lb2, float* __restrict__ out) {
    int g = threadIdx.x;
    if (g >= GGRAPHS) return;
    float p[64];
#pragma unroll
    for (int c = 0; c < 64; ++c) p[c] = pooled[g * 64 + c];
    float z0 = lb2[0], z1 = lb2[1], z2 = lb2[2];
    for (int j = 0; j < 32; ++j) {
        float hj = lb1[j];
#pragma unroll
        for (int c = 0; c < 64; ++c) {
            int rc = (c & 3) * 16 + (c >> 2);    // slot c holds real channel rc
            hj += p[c] * lw1[rc * 32 + j];
        }
        hj = fmaxf(hj, 0.f);
        z0 += hj * lw2[j * 3 + 0];
        z1 += hj * lw2[j * 3 + 1];
        z2 += hj * lw2[j * 3 + 2];
    }
    float m = fmaxf(z0, fmaxf(z1, z2));
    float lse = logf(expf(z0 - m) + expf(z1 - m) + expf(z2 - m)) + m;
    out[g * 3 + 0] = z0 - lse;
    out[g * 3 + 1] = z1 - lse;
    out[g * 3 + 2] = z2 - lse;
}

// ---------------- launch ----------------

extern "C" void kernel_launch(void* const* d_in, const int* in_sizes, int n_in,
                              void* d_out, int out_size, void* d_ws, size_t ws_size,
                              hipStream_t stream) {
    (void)in_sizes; (void)n_in; (void)out_size; (void)ws_size;
    const float* x    = (const float*)d_in[0];
    const int*   ei   = (const int*)d_in[1];
    const int*   batch= (const int*)d_in[2];
    const float* W1   = (const float*)d_in[3];
    const float* a_s1 = (const float*)d_in[4];
    const float* a_d1 = (const float*)d_in[5];
    const float* b1   = (const float*)d_in[6];
    const float* g1   = (const float*)d_in[7];
    const float* be1  = (const float*)d_in[8];
    const float* m1   = (const float*)d_in[9];
    const float* v1   = (const float*)d_in[10];
    const float* W2   = (const float*)d_in[11];
    const float* a_s2 = (const float*)d_in[12];
    const float* a_d2 = (const float*)d_in[13];
    const float* b2   = (const float*)d_in[14];
    const float* g2   = (const float*)d_in[15];
    const float* be2  = (const float*)d_in[16];
    const float* m2   = (const float*)d_in[17];
    const float* v2   = (const float*)d_in[18];
    const float* lw1  = (const float*)d_in[19];
    const float* lb1  = (const float*)d_in[20];
    const float* lw2  = (const float*)d_in[21];
    const float* lb2  = (const float*)d_in[22];
    float* out = (float*)d_out;

    char* ws = (char*)d_ws;
    size_t off = 0;
    auto alloc = [&](size_t bytes) -> void* {
        void* p = ws + off;
        off += (bytes + 255) & ~(size_t)255;
        return p;
    };
    unsigned short* xbf = (unsigned short*)alloc((size_t)N_NODES * 64 * 2);    // bf16
    unsigned short* W1T = (unsigned short*)alloc((size_t)16384 * 2);           // bf16 [n][k]
    unsigned short* W2T = (unsigned short*)alloc((size_t)16384 * 2);           // bf16 [n][k'] perm
    unsigned char*  h1  = (unsigned char*)alloc((size_t)N_NODES * 256);        // fp8 perm
    unsigned short* hb  = (unsigned short*)alloc((size_t)N_NODES * 256 * 2);   // bf16 perm slots
    unsigned char*  h2  = (unsigned char*)alloc((size_t)N_NODES * 64);         // fp8 perm
    float* out2 = (float*)alloc((size_t)N_NODES * 64 * 4);                     // f32 slot layout
    float* es1  = (float*)alloc((size_t)N_NODES * 4 * 4);
    float* ed1  = (float*)alloc((size_t)N_NODES * 4 * 4);
    float* es2  = (float*)alloc((size_t)N_NODES * 4);
    float* ed2  = (float*)alloc((size_t)N_NODES * 4);
    float* pooled = (float*)alloc((size_t)GGRAPHS * 64 * 4);
    int*   cnt  = (int*)alloc((size_t)N_NODES * 4);
    int*   offs = (int*)alloc((size_t)(N_NODES + 1) * 4);
    int*   curs = (int*)alloc((size_t)N_NODES * 4);
    int*   csr  = (int*)alloc((size_t)ETOT * 4);
    int*   bsums= (int*)alloc(256 * 4);

    const int nscan = (N_NODES + 255) / 256;   // 196
    const int ntileb = (3125 + 3) / 4;         // 782 blocks for MFMA gemms

    hipMemsetAsync(cnt, 0, (size_t)N_NODES * 4, stream);
    k_prep<<<NPREPB + NEDGEB, 256, 0, stream>>>(x, W1, W2, ei, xbf, W1T, W2T, cnt);
    k_scan_local<<<nscan, 256, 0, stream>>>(cnt, offs, bsums);
    k_scan_sums<<<1, 256, 0, stream>>>(bsums, nscan);
    k_scan_add<<<nscan, 256, 0, stream>>>(offs, curs, bsums);
    k_fill<<<NEDGEB, 256, 0, stream>>>(ei, curs, csr);

    k_gemm1<<<ntileb, 256, 0, stream>>>(xbf, W1T, a_s1, a_d1, h1, es1, ed1);
    k_gat1<<<(N_NODES + 3) / 4, 256, 0, stream>>>(h1, es1, ed1, offs, csr, b1, g1, be1, m1, v1, hb);
    k_gemm2<<<ntileb, 256, 0, stream>>>(hb, W2T, a_s2, a_d2, h2, es2, ed2);
    k_gat2<<<(N_NODES + 3) / 4, 256, 0, stream>>>(h2, es2, ed2, offs, csr, b2, g2, be2, m2, v2, out2);
    k_pool<<<GGRAPHS, 256, 0, stream>>>(out2, batch, pooled);
    k_head<<<1, 64, 0, stream>>>(pooled, lw1, lb1, lw2, lb2, out);
}

// Round 8
// 352.928 us; speedup vs baseline: 1.1224x; 1.1224x over previous
//
#include <hip/hip_runtime.h>
#include <math.h>

#define N_NODES 50000
#define N_EDGES 800000
#define ETOT    (N_EDGES + N_NODES)   // self-loops appended
#define GGRAPHS 64
#define EPS_BN  1e-5f

typedef __attribute__((ext_vector_type(8))) short short8;
typedef __attribute__((ext_vector_type(4))) float f32x4;
typedef __attribute__((ext_vector_type(2))) float f32x2;

__device__ __forceinline__ unsigned short f2bf(float f) {
    union { float f; unsigned u; } v; v.f = f;
    unsigned r = v.u + 0x7fffu + ((v.u >> 16) & 1u);   // round-nearest-even
    return (unsigned short)(r >> 16);
}
__device__ __forceinline__ float leaky(float e) {
    return fmaxf(e, 0.2f * e);
}
// pack 4 f32 -> 4 fp8 (e4m3, OCP on gfx950)
__device__ __forceinline__ unsigned pack4_fp8(float a, float b, float c, float d) {
    int v = __builtin_amdgcn_cvt_pk_fp8_f32(a, b, 0, false);
    v = __builtin_amdgcn_cvt_pk_fp8_f32(c, d, v, true);
    return (unsigned)v;
}

// ---------------- prep (x->bf16, W1T, W2T, BN-fold) + hist, merged ----------

#define XQ (N_NODES * 64 / 4)
#define PREP_T (XQ + 32768 + 320)
#define NPREPB ((PREP_T + 255) / 256)
#define NEDGEB ((ETOT + 255) / 256)

__global__ void k_prep(const float* __restrict__ x, const float* __restrict__ W1,
                       const float* __restrict__ W2, const int* __restrict__ ei,
                       const float* __restrict__ b1, const float* __restrict__ g1,
                       const float* __restrict__ be1, const float* __restrict__ m1,
                       const float* __restrict__ v1,
                       const float* __restrict__ b2, const float* __restrict__ g2,
                       const float* __restrict__ be2, const float* __restrict__ m2,
                       const float* __restrict__ v2,
                       unsigned short* __restrict__ xbf,
                       unsigned short* __restrict__ W1T,
                       unsigned short* __restrict__ W2T,
                       float* __restrict__ A1s, float* __restrict__ B1s,
                       float* __restrict__ A2s, float* __restrict__ B2s,
                       int* __restrict__ cnt) {
    int b = blockIdx.x;
    if (b < NPREPB) {
        int t = b * 256 + threadIdx.x;
        if (t < XQ) {
            float4 v = *(const float4*)&x[t * 4];
            ushort4 o;
            o.x = f2bf(v.x); o.y = f2bf(v.y); o.z = f2bf(v.z); o.w = f2bf(v.w);
            *(ushort4*)&xbf[t * 4] = o;
        } else if (t < XQ + 16384) {
            int i = t - XQ;                 // W1T[n*64+k] = W1[k*256+n]
            int n = i >> 6, k = i & 63;
            W1T[i] = f2bf(W1[k * 256 + n]);
        } else if (t < XQ + 32768) {
            int i = t - XQ - 16384;         // W2T[n*256+k'] = W2[real(k')*64+n]
            int n = i >> 8, kp = i & 255;
            int rk = (kp & 15) * 16 + (kp >> 4);
            W2T[i] = f2bf(W2[rk * 64 + n]);
        } else if (t < XQ + 32768 + 256) {
            int z = t - XQ - 32768;         // hb slot z holds real (z&15)*16+(z>>4)
            int r = (z & 15) * 16 + (z >> 4);
            float A = g1[r] * rsqrtf(v1[r] + EPS_BN);
            A1s[z] = A;
            B1s[z] = (b1[r] - m1[r]) * A + be1[r];
        } else if (t < PREP_T) {
            int z = t - XQ - 32768 - 256;   // out2 slot z holds real (z&3)*16+(z>>2)
            int r = (z & 3) * 16 + (z >> 2);
            float A = g2[r] * rsqrtf(v2[r] + EPS_BN);
            A2s[z] = A;
            B2s[z] = (b2[r] - m2[r]) * A + be2[r];
        }
    } else {
        int e = (b - NPREPB) * 256 + threadIdx.x;
        if (e < ETOT) {
            int d = (e < N_EDGES) ? ei[N_EDGES + e] : (e - N_EDGES);
            atomicAdd(&cnt[d], 1);
        }
    }
}

// ---------------- CSR build (scan + fill) ----------------

__global__ void k_scan_local(const int* __restrict__ cnt, int* __restrict__ offs,
                             int* __restrict__ bsums) {
    __shared__ int s[256];
    int t = threadIdx.x, idx = blockIdx.x * 256 + t;
    int v = (idx < N_NODES) ? cnt[idx] : 0;
    s[t] = v; __syncthreads();
    for (int d2 = 1; d2 < 256; d2 <<= 1) {
        int add = (t >= d2) ? s[t - d2] : 0;
        __syncthreads();
        s[t] += add;
        __syncthreads();
    }
    if (idx < N_NODES) offs[idx] = s[t] - v;       // local exclusive
    if (t == 255) bsums[blockIdx.x] = s[255];
}

__global__ void k_scan_sums(int* __restrict__ bsums, int nb) {
    __shared__ int s[256];
    int t = threadIdx.x;
    int v = (t < nb) ? bsums[t] : 0;
    s[t] = v; __syncthreads();
    for (int d2 = 1; d2 < 256; d2 <<= 1) {
        int add = (t >= d2) ? s[t - d2] : 0;
        __syncthreads();
        s[t] += add;
        __syncthreads();
    }
    if (t < nb) bsums[t] = s[t] - v;               // exclusive
}

__global__ void k_scan_add(int* __restrict__ offs, int* __restrict__ cursor,
                           const int* __restrict__ bsums) {
    int idx = blockIdx.x * 256 + threadIdx.x;
    if (idx < N_NODES) {
        int o = offs[idx] + bsums[blockIdx.x];
        offs[idx] = o;
        cursor[idx] = o;
    }
    if (idx == 0) offs[N_NODES] = ETOT;
}

__global__ void k_fill(const int* __restrict__ ei, int* __restrict__ cursor,
                       int* __restrict__ csr) {
    int e = blockIdx.x * 256 + threadIdx.x;
    if (e >= ETOT) return;
    int s, d;
    if (e < N_EDGES) { s = ei[e]; d = ei[N_EDGES + e]; }
    else             { s = d = e - N_EDGES; }
    int pos = atomicAdd(&cursor[d], 1);
    csr[pos] = s;
}

// ---------------- GEMM1 (MFMA): h1(fp8, perm layout) = x @ W1, scores ----------
// h1 slot s of a row holds real channel (s&15)*16 + (s>>4).

__global__ __launch_bounds__(256)
void k_gemm1(const unsigned short* __restrict__ xbf, const unsigned short* __restrict__ W1Tg,
             const float* __restrict__ a_s, const float* __restrict__ a_d,
             unsigned char* __restrict__ h1f8, float* __restrict__ es1, float* __restrict__ ed1) {
    __shared__ unsigned short W1T[256 * 72];
    int t = threadIdx.x;
    for (int c = t; c < 2048; c += 256) {            // 2048 chunks of 8 bf16
        int n = c >> 3, k8 = (c & 7) * 8;
        *(short8*)&W1T[n * 72 + k8] = *(const short8*)&W1Tg[n * 64 + k8];
    }
    __syncthreads();
    int wid = t >> 6, lane = t & 63;
    int quad = lane >> 4, col = lane & 15;
    float as_r[16], ad_r[16];
#pragma unroll
    for (int i = 0; i < 16; ++i) {
        as_r[i] = a_s[i * 16 + col];
        ad_r[i] = a_d[i * 16 + col];
    }
    int tile = blockIdx.x * 4 + wid;
    if (tile >= 3125) return;
    int base = tile * 16;
    short8 a0 = *(const short8*)&xbf[(size_t)(base + col) * 64 + quad * 8];
    short8 a1 = *(const short8*)&xbf[(size_t)(base + col) * 64 + 32 + quad * 8];
    f32x4 acc[16];
#pragma unroll
    for (int nt = 0; nt < 16; ++nt) acc[nt] = (f32x4){0.f, 0.f, 0.f, 0.f};
#pragma unroll
    for (int nt = 0; nt < 16; ++nt) {
        short8 b0 = *(const short8*)&W1T[(nt * 16 + col) * 72 + quad * 8];
        short8 b1 = *(const short8*)&W1T[(nt * 16 + col) * 72 + 32 + quad * 8];
        acc[nt] = __builtin_amdgcn_mfma_f32_16x16x32_bf16(a0, b0, acc[nt], 0, 0, 0);
        acc[nt] = __builtin_amdgcn_mfma_f32_16x16x32_bf16(a1, b1, acc[nt], 0, 0, 0);
    }
    float esp[16], edp[16];
#pragma unroll
    for (int i = 0; i < 16; ++i) { esp[i] = 0.f; edp[i] = 0.f; }
#pragma unroll
    for (int nt = 0; nt < 16; ++nt) {
        int hd = nt >> 2;
#pragma unroll
        for (int r = 0; r < 4; ++r) {
            esp[hd * 4 + r] += acc[nt][r] * as_r[nt];
            edp[hd * 4 + r] += acc[nt][r] * ad_r[nt];
        }
    }
#pragma unroll
    for (int i = 0; i < 16; ++i) {
        float v = esp[i], w = edp[i];
#pragma unroll
        for (int m = 1; m <= 8; m <<= 1) { v += __shfl_xor(v, m); w += __shfl_xor(w, m); }
        esp[i] = v; edp[i] = w;
    }
    if (col == 0) {
#pragma unroll
        for (int hd = 0; hd < 4; ++hd)
#pragma unroll
            for (int r = 0; r < 4; ++r) {
                int node = base + quad * 4 + r;
                es1[node * 4 + hd] = esp[hd * 4 + r];
                ed1[node * 4 + hd] = edp[hd * 4 + r];
            }
    }
    // h1 fp8 store, permuted: byte slot col*16+nt  (16B vector store per row)
#pragma unroll
    for (int r = 0; r < 4; ++r) {
        uint4 pk;
        pk.x = pack4_fp8(acc[0][r],  acc[1][r],  acc[2][r],  acc[3][r]);
        pk.y = pack4_fp8(acc[4][r],  acc[5][r],  acc[6][r],  acc[7][r]);
        pk.z = pack4_fp8(acc[8][r],  acc[9][r],  acc[10][r], acc[11][r]);
        pk.w = pack4_fp8(acc[12][r], acc[13][r], acc[14][r], acc[15][r]);
        *(uint4*)&h1f8[(size_t)(base + quad * 4 + r) * 256 + col * 16] = pk;
    }
}

// ---------------- GAT1: 16-lane group per dst node, chunk=4 edges ----------
// lane q (0..15) owns h1 bytes q*16..+15 (slots q*16+i, real ch i*16+q, head i>>2).
// Phase A: lane q computes w for (edge q>>2, head q&3). Phase B: 4 batched row loads.

__global__ __launch_bounds__(256)
void k_gat1(const unsigned char* __restrict__ h1f8, const float* __restrict__ es1,
            const float* __restrict__ ed1, const int* __restrict__ offs,
            const int* __restrict__ csr,
            const float* __restrict__ A1s, const float* __restrict__ B1s,
            unsigned short* __restrict__ hb) {
    int tid = threadIdx.x;
    int l = tid & 63;
    int gbase = l & 48;
    int q = tid & 15;
    int d = blockIdx.x * 16 + (tid >> 4);
    int start = offs[d], deg = offs[d + 1] - start;
    int e4 = q >> 2, hd = q & 3;
    float edv = ed1[d * 4 + hd];
    const unsigned char* hrow = h1f8 + q * 16;
    float a[16];
#pragma unroll
    for (int i = 0; i < 16; ++i) a[i] = 0.f;
    float wsum = 0.f;
    for (int c0 = 0; c0 < deg; c0 += 4) {
        int idx = c0 + e4;
        int s = csr[start + min(idx, deg - 1)];
        float w = (idx < deg) ? __expf(leaky(es1[s * 4 + hd] + edv)) : 0.f;
        wsum += w;
        int se[4];
#pragma unroll
        for (int e = 0; e < 4; ++e) se[e] = __shfl(s, gbase | (e << 2));
        uint4 rv[4];
#pragma unroll
        for (int e = 0; e < 4; ++e)
            rv[e] = *(const uint4*)(hrow + ((size_t)(unsigned)se[e] << 8));
#pragma unroll
        for (int e = 0; e < 4; ++e) {
            float w0 = __shfl(w, gbase | (e << 2) | 0);
            float w1 = __shfl(w, gbase | (e << 2) | 1);
            float w2 = __shfl(w, gbase | (e << 2) | 2);
            float w3 = __shfl(w, gbase | (e << 2) | 3);
            f32x2 p;
            p = __builtin_amdgcn_cvt_pk_f32_fp8((int)rv[e].x, false); a[0]  += w0 * p.x; a[1]  += w0 * p.y;
            p = __builtin_amdgcn_cvt_pk_f32_fp8((int)rv[e].x, true);  a[2]  += w0 * p.x; a[3]  += w0 * p.y;
            p = __builtin_amdgcn_cvt_pk_f32_fp8((int)rv[e].y, false); a[4]  += w1 * p.x; a[5]  += w1 * p.y;
            p = __builtin_amdgcn_cvt_pk_f32_fp8((int)rv[e].y, true);  a[6]  += w1 * p.x; a[7]  += w1 * p.y;
            p = __builtin_amdgcn_cvt_pk_f32_fp8((int)rv[e].z, false); a[8]  += w2 * p.x; a[9]  += w2 * p.y;
            p = __builtin_amdgcn_cvt_pk_f32_fp8((int)rv[e].z, true);  a[10] += w2 * p.x; a[11] += w2 * p.y;
            p = __builtin_amdgcn_cvt_pk_f32_fp8((int)rv[e].w, false); a[12] += w3 * p.x; a[13] += w3 * p.y;
            p = __builtin_amdgcn_cvt_pk_f32_fp8((int)rv[e].w, true);  a[14] += w3 * p.x; a[15] += w3 * p.y;
        }
    }
    wsum += __shfl_xor(wsum, 4);
    wsum += __shfl_xor(wsum, 8);        // lane q now holds dn[head q&3]
    float inv[4];
#pragma unroll
    for (int h = 0; h < 4; ++h) inv[h] = 1.f / __shfl(wsum, gbase | h);
    ushort4 ov[4];
#pragma unroll
    for (int i0 = 0; i0 < 4; ++i0) {     // head of a[i0*4+j] = i0
        float4 Av = *(const float4*)&A1s[q * 16 + i0 * 4];
        float4 Bv = *(const float4*)&B1s[q * 16 + i0 * 4];
        float o0 = a[i0 * 4 + 0] * inv[i0] * Av.x + Bv.x;
        float o1 = a[i0 * 4 + 1] * inv[i0] * Av.y + Bv.y;
        float o2 = a[i0 * 4 + 2] * inv[i0] * Av.z + Bv.z;
        float o3 = a[i0 * 4 + 3] * inv[i0] * Av.w + Bv.w;
        o0 = (o0 > 0.f) ? o0 : expm1f(o0);
        o1 = (o1 > 0.f) ? o1 : expm1f(o1);
        o2 = (o2 > 0.f) ? o2 : expm1f(o2);
        o3 = (o3 > 0.f) ? o3 : expm1f(o3);
        ov[i0].x = f2bf(o0); ov[i0].y = f2bf(o1); ov[i0].z = f2bf(o2); ov[i0].w = f2bf(o3);
    }
#pragma unroll
    for (int i0 = 0; i0 < 4; ++i0)
        *(ushort4*)&hb[(size_t)d * 256 + q * 16 + i0 * 4] = ov[i0];
}

// ---------------- GEMM2 (MFMA): h2(fp8, perm) = hb @ W2, scores es2/ed2 --------
// h2 slot s of a row holds real channel (s&3)*16 + (s>>2).

__global__ __launch_bounds__(256)
void k_gemm2(const unsigned short* __restrict__ hbbf, const unsigned short* __restrict__ W2Tg,
             const float* __restrict__ a_s, const float* __restrict__ a_d,
             unsigned char* __restrict__ h2f8, float* __restrict__ es2, float* __restrict__ ed2) {
    __shared__ unsigned short W2T[64 * 264];
    int t = threadIdx.x;
    for (int c = t; c < 2048; c += 256) {            // 2048 chunks of 8 bf16
        int n = c >> 5, k8 = (c & 31) * 8;
        *(short8*)&W2T[n * 264 + k8] = *(const short8*)&W2Tg[n * 256 + k8];
    }
    __syncthreads();
    int wid = t >> 6, lane = t & 63;
    int quad = lane >> 4, col = lane & 15;
    float as_r[4], ad_r[4];
#pragma unroll
    for (int i = 0; i < 4; ++i) {
        as_r[i] = a_s[i * 16 + col];
        ad_r[i] = a_d[i * 16 + col];
    }
    int tile = blockIdx.x * 4 + wid;
    if (tile >= 3125) return;
    int base = tile * 16;
    short8 af[8];
#pragma unroll
    for (int kk = 0; kk < 8; ++kk)
        af[kk] = *(const short8*)&hbbf[(size_t)(base + col) * 256 + kk * 32 + quad * 8];
    f32x4 acc[4];
#pragma unroll
    for (int nt = 0; nt < 4; ++nt) acc[nt] = (f32x4){0.f, 0.f, 0.f, 0.f};
#pragma unroll
    for (int kk = 0; kk < 8; ++kk) {
#pragma unroll
        for (int nt = 0; nt < 4; ++nt) {
            short8 b = *(const short8*)&W2T[(nt * 16 + col) * 264 + kk * 32 + quad * 8];
            acc[nt] = __builtin_amdgcn_mfma_f32_16x16x32_bf16(af[kk], b, acc[nt], 0, 0, 0);
        }
    }
    float esp[4], edp[4];
#pragma unroll
    for (int r = 0; r < 4; ++r) { esp[r] = 0.f; edp[r] = 0.f; }
#pragma unroll
    for (int nt = 0; nt < 4; ++nt)
#pragma unroll
        for (int r = 0; r < 4; ++r) {
            esp[r] += acc[nt][r] * as_r[nt];
            edp[r] += acc[nt][r] * ad_r[nt];
        }
#pragma unroll
    for (int r = 0; r < 4; ++r) {
        float v = esp[r], w = edp[r];
#pragma unroll
        for (int m = 1; m <= 8; m <<= 1) { v += __shfl_xor(v, m); w += __shfl_xor(w, m); }
        esp[r] = v; edp[r] = w;
    }
    if (col == 0) {
#pragma unroll
        for (int r = 0; r < 4; ++r) {
            int node = base + quad * 4 + r;
            es2[node] = esp[r];
            ed2[node] = edp[r];
        }
    }
    // h2 fp8 store, permuted: byte slot col*4+nt (4B store per row)
#pragma unroll
    for (int r = 0; r < 4; ++r) {
        unsigned pk = pack4_fp8(acc[0][r], acc[1][r], acc[2][r], acc[3][r]);
        *(unsigned*)&h2f8[(size_t)(base + quad * 4 + r) * 64 + col * 4] = pk;
    }
}

// ---------------- GAT2: 16-lane group per dst node, chunk=4 edges ----------
// lane q owns h2 bytes q*4..+3 (slots q*4+i, real ch i*16+q). Single head.

__global__ __launch_bounds__(256)
void k_gat2(const unsigned char* __restrict__ h2f8, const float* __restrict__ es2,
            const float* __restrict__ ed2, const int* __restrict__ offs,
            const int* __restrict__ csr,
            const float* __restrict__ A2s, const float* __restrict__ B2s,
            float* __restrict__ out2) {
    int tid = threadIdx.x;
    int l = tid & 63;
    int gbase = l & 48;
    int q = tid & 15;
    int d = blockIdx.x * 16 + (tid >> 4);
    int start = offs[d], deg = offs[d + 1] - start;
    float edv = ed2[d];
    const unsigned char* hrow = h2f8 + q * 4;
    float a0 = 0.f, a1 = 0.f, a2 = 0.f, a3 = 0.f, wsum = 0.f;
    int e4 = q & 3;
    for (int c0 = 0; c0 < deg; c0 += 4) {
        int idx = c0 + e4;
        int s = csr[start + min(idx, deg - 1)];
        float w = (idx < deg) ? __expf(leaky(es2[s] + edv)) : 0.f;
        wsum += w;
        int se[4];
#pragma unroll
        for (int e = 0; e < 4; ++e) se[e] = __shfl(s, gbase | e);
        unsigned rv[4];
#pragma unroll
        for (int e = 0; e < 4; ++e)
            rv[e] = *(const unsigned*)(hrow + ((size_t)(unsigned)se[e] << 6));
#pragma unroll
        for (int e = 0; e < 4; ++e) {
            float we = __shfl(w, gbase | e);
            f32x2 p;
            p = __builtin_amdgcn_cvt_pk_f32_fp8((int)rv[e], false); a0 += we * p.x; a1 += we * p.y;
            p = __builtin_amdgcn_cvt_pk_f32_fp8((int)rv[e], true);  a2 += we * p.x; a3 += we * p.y;
        }
    }
    wsum += __shfl_xor(wsum, 1);
    wsum += __shfl_xor(wsum, 2);        // every lane: dn (each lane quartet covers e=0..3)
    float inv = 1.f / wsum;
    float4 Av = *(const float4*)&A2s[q * 4];
    float4 Bv = *(const float4*)&B2s[q * 4];
    float4 o;
    o.x = a0 * inv * Av.x + Bv.x;
    o.y = a1 * inv * Av.y + Bv.y;
    o.z = a2 * inv * Av.z + Bv.z;
    o.w = a3 * inv * Av.w + Bv.w;
    *(float4*)&out2[(size_t)d * 64 + q * 4] = o;
}

// ---------------- mean pool per graph (slot layout, channel-agnostic) --------

__device__ int lower_bound_i(const int* a, int n, int key) {
    int lo = 0, hi = n;
    while (lo < hi) {
        int mid = (lo + hi) >> 1;
        if (a[mid] < key) lo = mid + 1; else hi = mid;
    }
    return lo;
}

__global__ __launch_bounds__(256)
void k_pool(const float* __restrict__ out2, const int* __restrict__ batch,
            float* __restrict__ pooled) {
    int g = blockIdx.x;
    __shared__ int ssh[2];
    __shared__ float red[256];
    if (threadIdx.x == 0) {
        ssh[0] = lower_bound_i(batch, N_NODES, g);
        ssh[1] = lower_bound_i(batch, N_NODES, g + 1);
    }
    __syncthreads();
    int start = ssh[0], end = ssh[1];
    int t = threadIdx.x, sub = t >> 6, lane = t & 63;
    float acc = 0.f;
    for (int i = start + sub; i < end; i += 4) acc += out2[(size_t)i * 64 + lane];
    red[t] = acc; __syncthreads();
    if (t < 64) {
        float s = red[t] + red[t + 64] + red[t + 128] + red[t + 192];
        int cnt = end - start;
        pooled[g * 64 + t] = s / (float)((cnt > 0) ? cnt : 1);
    }
}

// ---------------- MLP head + log_softmax (maps slots -> real channels) -------

__global__ void k_head(const float* __restrict__ pooled, const float* __restrict__ lw1,
                       const float* __restrict__ lb1, const float* __restrict__ lw2,
                       const float* __restrict__ lb2, float* __restrict__ out) {
    int g = threadIdx.x;
    if (g >= GGRAPHS) return;
    float p[64];
#pragma unroll
    for (int c = 0; c < 64; ++c) p[c] = pooled[g * 64 + c];
    float z0 = lb2[0], z1 = lb2[1], z2 = lb2[2];
    for (int j = 0; j < 32; ++j) {
        float hj = lb1[j];
#pragma unroll
        for (int c = 0; c < 64; ++c) {
            int rc = (c & 3) * 16 + (c >> 2);    // slot c holds real channel rc
            hj += p[c] * lw1[rc * 32 + j];
        }
        hj = fmaxf(hj, 0.f);
        z0 += hj * lw2[j * 3 + 0];
        z1 += hj * lw2[j * 3 + 1];
        z2 += hj * lw2[j * 3 + 2];
    }
    float m = fmaxf(z0, fmaxf(z1, z2));
    float lse = logf(expf(z0 - m) + expf(z1 - m) + expf(z2 - m)) + m;
    out[g * 3 + 0] = z0 - lse;
    out[g * 3 + 1] = z1 - lse;
    out[g * 3 + 2] = z2 - lse;
}

// ---------------- launch ----------------

extern "C" void kernel_launch(void* const* d_in, const int* in_sizes, int n_in,
                              void* d_out, int out_size, void* d_ws, size_t ws_size,
                              hipStream_t stream) {
    (void)in_sizes; (void)n_in; (void)out_size; (void)ws_size;
    const float* x    = (const float*)d_in[0];
    const int*   ei   = (const int*)d_in[1];
    const int*   batch= (const int*)d_in[2];
    const float* W1   = (const float*)d_in[3];
    const float* a_s1 = (const float*)d_in[4];
    const float* a_d1 = (const float*)d_in[5];
    const float* b1   = (const float*)d_in[6];
    const float* g1   = (const float*)d_in[7];
    const float* be1  = (const float*)d_in[8];
    const float* m1   = (const float*)d_in[9];
    const float* v1   = (const float*)d_in[10];
    const float* W2   = (const float*)d_in[11];
    const float* a_s2 = (const float*)d_in[12];
    const float* a_d2 = (const float*)d_in[13];
    const float* b2   = (const float*)d_in[14];
    const float* g2   = (const float*)d_in[15];
    const float* be2  = (const float*)d_in[16];
    const float* m2   = (const float*)d_in[17];
    const float* v2   = (const float*)d_in[18];
    const float* lw1  = (const float*)d_in[19];
    const float* lb1  = (const float*)d_in[20];
    const float* lw2  = (const float*)d_in[21];
    const float* lb2  = (const float*)d_in[22];
    float* out = (float*)d_out;

    char* ws = (char*)d_ws;
    size_t off = 0;
    auto alloc = [&](size_t bytes) -> void* {
        void* p = ws + off;
        off += (bytes + 255) & ~(size_t)255;
        return p;
    };
    unsigned short* xbf = (unsigned short*)alloc((size_t)N_NODES * 64 * 2);    // bf16
    unsigned short* W1T = (unsigned short*)alloc((size_t)16384 * 2);           // bf16 [n][k]
    unsigned short* W2T = (unsigned short*)alloc((size_t)16384 * 2);           // bf16 [n][k'] perm
    unsigned char*  h1  = (unsigned char*)alloc((size_t)N_NODES * 256);        // fp8 perm
    unsigned short* hb  = (unsigned short*)alloc((size_t)N_NODES * 256 * 2);   // bf16 perm slots
    unsigned char*  h2  = (unsigned char*)alloc((size_t)N_NODES * 64);         // fp8 perm
    float* out2 = (float*)alloc((size_t)N_NODES * 64 * 4);                     // f32 slot layout
    float* es1  = (float*)alloc((size_t)N_NODES * 4 * 4);
    float* ed1  = (float*)alloc((size_t)N_NODES * 4 * 4);
    float* es2  = (float*)alloc((size_t)N_NODES * 4);
    float* ed2  = (float*)alloc((size_t)N_NODES * 4);
    float* pooled = (float*)alloc((size_t)GGRAPHS * 64 * 4);
    float* A1s  = (float*)alloc(256 * 4);
    float* B1s  = (float*)alloc(256 * 4);
    float* A2s  = (float*)alloc(64 * 4);
    float* B2s  = (float*)alloc(64 * 4);
    int*   cnt  = (int*)alloc((size_t)N_NODES * 4);
    int*   offs = (int*)alloc((size_t)(N_NODES + 1) * 4);
    int*   curs = (int*)alloc((size_t)N_NODES * 4);
    int*   csr  = (int*)alloc((size_t)ETOT * 4);
    int*   bsums= (int*)alloc(256 * 4);

    const int nscan = (N_NODES + 255) / 256;   // 196
    const int ntileb = (3125 + 3) / 4;         // 782 blocks for MFMA gemms
    const int ngat = 3125;                     // 16 nodes per block

    hipMemsetAsync(cnt, 0, (size_t)N_NODES * 4, stream);
    k_prep<<<NPREPB + NEDGEB, 256, 0, stream>>>(x, W1, W2, ei,
                                                b1, g1, be1, m1, v1,
                                                b2, g2, be2, m2, v2,
                                                xbf, W1T, W2T, A1s, B1s, A2s, B2s, cnt);
    k_scan_local<<<nscan, 256, 0, stream>>>(cnt, offs, bsums);
    k_scan_sums<<<1, 256, 0, stream>>>(bsums, nscan);
    k_scan_add<<<nscan, 256, 0, stream>>>(offs, curs, bsums);
    k_fill<<<NEDGEB, 256, 0, stream>>>(ei, curs, csr);

    k_gemm1<<<ntileb, 256, 0, stream>>>(xbf, W1T, a_s1, a_d1, h1, es1, ed1);
    k_gat1<<<ngat, 256, 0, stream>>>(h1, es1, ed1, offs, csr, A1s, B1s, hb);
    k_gemm2<<<ntileb, 256, 0, stream>>>(hb, W2T, a_s2, a_d2, h2, es2, ed2);
    k_gat2<<<ngat, 256, 0, stream>>>(h2, es2, ed2, offs, csr, A2s, B2s, out2);
    k_pool<<<GGRAPHS, 256, 0, stream>>>(out2, batch, pooled);
    k_head<<<1, 64, 0, stream>>>(pooled, lw1, lb1, lw2, lb2, out);
}

// Round 9
// 313.582 us; speedup vs baseline: 1.2632x; 1.1255x over previous
//
#include <hip/hip_runtime.h>
#include <math.h>

#define N_NODES 50000
#define N_EDGES 800000
#define ETOT    (N_EDGES + N_NODES)   // self-loops appended
#define GGRAPHS 64
#define EPS_BN  1e-5f

typedef __attribute__((ext_vector_type(8))) short short8;
typedef __attribute__((ext_vector_type(4))) float f32x4;
typedef __attribute__((ext_vector_type(2))) float f32x2;

__device__ __forceinline__ unsigned short f2bf(float f) {
    union { float f; unsigned u; } v; v.f = f;
    unsigned r = v.u + 0x7fffu + ((v.u >> 16) & 1u);   // round-nearest-even
    return (unsigned short)(r >> 16);
}
__device__ __forceinline__ float leaky(float e) {
    return fmaxf(e, 0.2f * e);
}
// pack 4 f32 -> 4 fp8 (e4m3, OCP on gfx950)
__device__ __forceinline__ unsigned pack4_fp8(float a, float b, float c, float d) {
    int v = __builtin_amdgcn_cvt_pk_fp8_f32(a, b, 0, false);
    v = __builtin_amdgcn_cvt_pk_fp8_f32(c, d, v, true);
    return (unsigned)v;
}

// ---------------- prep (x->bf16, W1T, W2T, BN-fold) + hist, merged ----------

#define XQ (N_NODES * 64 / 4)
#define PREP_T (XQ + 32768 + 320)
#define NPREPB ((PREP_T + 255) / 256)
#define NEDGEB ((ETOT + 255) / 256)

__global__ void k_prep(const float* __restrict__ x, const float* __restrict__ W1,
                       const float* __restrict__ W2, const int* __restrict__ ei,
                       const float* __restrict__ b1, const float* __restrict__ g1,
                       const float* __restrict__ be1, const float* __restrict__ m1,
                       const float* __restrict__ v1,
                       const float* __restrict__ b2, const float* __restrict__ g2,
                       const float* __restrict__ be2, const float* __restrict__ m2,
                       const float* __restrict__ v2,
                       unsigned short* __restrict__ xbf,
                       unsigned short* __restrict__ W1T,
                       unsigned short* __restrict__ W2T,
                       float* __restrict__ A1s, float* __restrict__ B1s,
                       float* __restrict__ A2s, float* __restrict__ B2s,
                       int* __restrict__ cnt) {
    int b = blockIdx.x;
    if (b < NPREPB) {
        int t = b * 256 + threadIdx.x;
        if (t < XQ) {
            float4 v = *(const float4*)&x[t * 4];
            ushort4 o;
            o.x = f2bf(v.x); o.y = f2bf(v.y); o.z = f2bf(v.z); o.w = f2bf(v.w);
            *(ushort4*)&xbf[t * 4] = o;
        } else if (t < XQ + 16384) {
            int i = t - XQ;                 // W1T[n*64+k] = W1[k*256+n]
            int n = i >> 6, k = i & 63;
            W1T[i] = f2bf(W1[k * 256 + n]);
        } else if (t < XQ + 32768) {
            int i = t - XQ - 16384;         // W2T[n*256+k'] = W2[real(k')*64+n]
            int n = i >> 8, kp = i & 255;
            int rk = (kp & 15) * 16 + (kp >> 4);
            W2T[i] = f2bf(W2[rk * 64 + n]);
        } else if (t < XQ + 32768 + 256) {
            int z = t - XQ - 32768;         // hb slot z holds real (z&15)*16+(z>>4)
            int r = (z & 15) * 16 + (z >> 4);
            float A = g1[r] * rsqrtf(v1[r] + EPS_BN);
            A1s[z] = A;
            B1s[z] = (b1[r] - m1[r]) * A + be1[r];
        } else if (t < PREP_T) {
            int z = t - XQ - 32768 - 256;   // out2 slot z holds real (z&3)*16+(z>>2)
            int r = (z & 3) * 16 + (z >> 2);
            float A = g2[r] * rsqrtf(v2[r] + EPS_BN);
            A2s[z] = A;
            B2s[z] = (b2[r] - m2[r]) * A + be2[r];
        }
    } else {
        int e = (b - NPREPB) * 256 + threadIdx.x;
        if (e < ETOT) {
            int d = (e < N_EDGES) ? ei[N_EDGES + e] : (e - N_EDGES);
            atomicAdd(&cnt[d], 1);
        }
    }
}

// ---------------- CSR build (scan + fill, csr entries are ushort) ----------

__global__ void k_scan_local(const int* __restrict__ cnt, int* __restrict__ offs,
                             int* __restrict__ bsums) {
    __shared__ int s[256];
    int t = threadIdx.x, idx = blockIdx.x * 256 + t;
    int v = (idx < N_NODES) ? cnt[idx] : 0;
    s[t] = v; __syncthreads();
    for (int d2 = 1; d2 < 256; d2 <<= 1) {
        int add = (t >= d2) ? s[t - d2] : 0;
        __syncthreads();
        s[t] += add;
        __syncthreads();
    }
    if (idx < N_NODES) offs[idx] = s[t] - v;       // local exclusive
    if (t == 255) bsums[blockIdx.x] = s[255];
}

__global__ void k_scan_sums(int* __restrict__ bsums, int nb) {
    __shared__ int s[256];
    int t = threadIdx.x;
    int v = (t < nb) ? bsums[t] : 0;
    s[t] = v; __syncthreads();
    for (int d2 = 1; d2 < 256; d2 <<= 1) {
        int add = (t >= d2) ? s[t - d2] : 0;
        __syncthreads();
        s[t] += add;
        __syncthreads();
    }
    if (t < nb) bsums[t] = s[t] - v;               // exclusive
}

__global__ void k_scan_add(int* __restrict__ offs, int* __restrict__ cursor,
                           const int* __restrict__ bsums) {
    int idx = blockIdx.x * 256 + threadIdx.x;
    if (idx < N_NODES) {
        int o = offs[idx] + bsums[blockIdx.x];
        offs[idx] = o;
        cursor[idx] = o;
    }
    if (idx == 0) offs[N_NODES] = ETOT;
}

__global__ void k_fill(const int* __restrict__ ei, int* __restrict__ cursor,
                       unsigned short* __restrict__ csr) {
    int e = blockIdx.x * 256 + threadIdx.x;
    if (e >= ETOT) return;
    int s, d;
    if (e < N_EDGES) { s = ei[e]; d = ei[N_EDGES + e]; }
    else             { s = d = e - N_EDGES; }
    int pos = atomicAdd(&cursor[d], 1);
    csr[pos] = (unsigned short)s;
}

// ---------------- GEMM1 (MFMA): h1(fp8, perm layout) = x @ W1, scores ----------
// h1 slot s of a row holds real channel (s&15)*16 + (s>>4).

__global__ __launch_bounds__(256)
void k_gemm1(const unsigned short* __restrict__ xbf, const unsigned short* __restrict__ W1Tg,
             const float* __restrict__ a_s, const float* __restrict__ a_d,
             unsigned char* __restrict__ h1f8, float* __restrict__ es1, float* __restrict__ ed1) {
    __shared__ unsigned short W1T[256 * 72];
    int t = threadIdx.x;
    for (int c = t; c < 2048; c += 256) {            // 2048 chunks of 8 bf16
        int n = c >> 3, k8 = (c & 7) * 8;
        *(short8*)&W1T[n * 72 + k8] = *(const short8*)&W1Tg[n * 64 + k8];
    }
    __syncthreads();
    int wid = t >> 6, lane = t & 63;
    int quad = lane >> 4, col = lane & 15;
    float as_r[16], ad_r[16];
#pragma unroll
    for (int i = 0; i < 16; ++i) {
        as_r[i] = a_s[i * 16 + col];
        ad_r[i] = a_d[i * 16 + col];
    }
    int tile = blockIdx.x * 4 + wid;
    if (tile >= 3125) return;
    int base = tile * 16;
    short8 a0 = *(const short8*)&xbf[(size_t)(base + col) * 64 + quad * 8];
    short8 a1 = *(const short8*)&xbf[(size_t)(base + col) * 64 + 32 + quad * 8];
    f32x4 acc[16];
#pragma unroll
    for (int nt = 0; nt < 16; ++nt) acc[nt] = (f32x4){0.f, 0.f, 0.f, 0.f};
#pragma unroll
    for (int nt = 0; nt < 16; ++nt) {
        short8 b0 = *(const short8*)&W1T[(nt * 16 + col) * 72 + quad * 8];
        short8 b1 = *(const short8*)&W1T[(nt * 16 + col) * 72 + 32 + quad * 8];
        acc[nt] = __builtin_amdgcn_mfma_f32_16x16x32_bf16(a0, b0, acc[nt], 0, 0, 0);
        acc[nt] = __builtin_amdgcn_mfma_f32_16x16x32_bf16(a1, b1, acc[nt], 0, 0, 0);
    }
    float esp[16], edp[16];
#pragma unroll
    for (int i = 0; i < 16; ++i) { esp[i] = 0.f; edp[i] = 0.f; }
#pragma unroll
    for (int nt = 0; nt < 16; ++nt) {
        int hd = nt >> 2;
#pragma unroll
        for (int r = 0; r < 4; ++r) {
            esp[hd * 4 + r] += acc[nt][r] * as_r[nt];
            edp[hd * 4 + r] += acc[nt][r] * ad_r[nt];
        }
    }
#pragma unroll
    for (int i = 0; i < 16; ++i) {
        float v = esp[i], w = edp[i];
#pragma unroll
        for (int m = 1; m <= 8; m <<= 1) { v += __shfl_xor(v, m); w += __shfl_xor(w, m); }
        esp[i] = v; edp[i] = w;
    }
    if (col == 0) {
#pragma unroll
        for (int hd = 0; hd < 4; ++hd)
#pragma unroll
            for (int r = 0; r < 4; ++r) {
                int node = base + quad * 4 + r;
                es1[node * 4 + hd] = esp[hd * 4 + r];
                ed1[node * 4 + hd] = edp[hd * 4 + r];
            }
    }
    // h1 fp8 store, permuted: byte slot col*16+nt  (16B vector store per row)
#pragma unroll
    for (int r = 0; r < 4; ++r) {
        uint4 pk;
        pk.x = pack4_fp8(acc[0][r],  acc[1][r],  acc[2][r],  acc[3][r]);
        pk.y = pack4_fp8(acc[4][r],  acc[5][r],  acc[6][r],  acc[7][r]);
        pk.z = pack4_fp8(acc[8][r],  acc[9][r],  acc[10][r], acc[11][r]);
        pk.w = pack4_fp8(acc[12][r], acc[13][r], acc[14][r], acc[15][r]);
        *(uint4*)&h1f8[(size_t)(base + quad * 4 + r) * 256 + col * 16] = pk;
    }
}

// ---------------- GAT1: 16-lane group per dst node, chunk=4 edges ----------

__global__ __launch_bounds__(256)
void k_gat1(const unsigned char* __restrict__ h1f8, const float* __restrict__ es1,
            const float* __restrict__ ed1, const int* __restrict__ offs,
            const unsigned short* __restrict__ csr,
            const float* __restrict__ A1s, const float* __restrict__ B1s,
            unsigned short* __restrict__ hb) {
    int tid = threadIdx.x;
    int l = tid & 63;
    int gbase = l & 48;
    int q = tid & 15;
    int d = blockIdx.x * 16 + (tid >> 4);
    int start = offs[d], deg = offs[d + 1] - start;
    int e4 = q >> 2, hd = q & 3;
    float edv = ed1[d * 4 + hd];
    const unsigned char* hrow = h1f8 + q * 16;
    float a[16];
#pragma unroll
    for (int i = 0; i < 16; ++i) a[i] = 0.f;
    float wsum = 0.f;
    for (int c0 = 0; c0 < deg; c0 += 4) {
        int idx = c0 + e4;
        int s = csr[start + min(idx, deg - 1)];
        float w = (idx < deg) ? __expf(leaky(es1[s * 4 + hd] + edv)) : 0.f;
        wsum += w;
        int se[4];
#pragma unroll
        for (int e = 0; e < 4; ++e) se[e] = __shfl(s, gbase | (e << 2));
        uint4 rv[4];
#pragma unroll
        for (int e = 0; e < 4; ++e)
            rv[e] = *(const uint4*)(hrow + ((size_t)(unsigned)se[e] << 8));
#pragma unroll
        for (int e = 0; e < 4; ++e) {
            float w0 = __shfl(w, gbase | (e << 2) | 0);
            float w1 = __shfl(w, gbase | (e << 2) | 1);
            float w2 = __shfl(w, gbase | (e << 2) | 2);
            float w3 = __shfl(w, gbase | (e << 2) | 3);
            f32x2 p;
            p = __builtin_amdgcn_cvt_pk_f32_fp8((int)rv[e].x, false); a[0]  += w0 * p.x; a[1]  += w0 * p.y;
            p = __builtin_amdgcn_cvt_pk_f32_fp8((int)rv[e].x, true);  a[2]  += w0 * p.x; a[3]  += w0 * p.y;
            p = __builtin_amdgcn_cvt_pk_f32_fp8((int)rv[e].y, false); a[4]  += w1 * p.x; a[5]  += w1 * p.y;
            p = __builtin_amdgcn_cvt_pk_f32_fp8((int)rv[e].y, true);  a[6]  += w1 * p.x; a[7]  += w1 * p.y;
            p = __builtin_amdgcn_cvt_pk_f32_fp8((int)rv[e].z, false); a[8]  += w2 * p.x; a[9]  += w2 * p.y;
            p = __builtin_amdgcn_cvt_pk_f32_fp8((int)rv[e].z, true);  a[10] += w2 * p.x; a[11] += w2 * p.y;
            p = __builtin_amdgcn_cvt_pk_f32_fp8((int)rv[e].w, false); a[12] += w3 * p.x; a[13] += w3 * p.y;
            p = __builtin_amdgcn_cvt_pk_f32_fp8((int)rv[e].w, true);  a[14] += w3 * p.x; a[15] += w3 * p.y;
        }
    }
    wsum += __shfl_xor(wsum, 4);
    wsum += __shfl_xor(wsum, 8);        // lane q now holds dn[head q&3]
    float inv[4];
#pragma unroll
    for (int h = 0; h < 4; ++h) inv[h] = 1.f / __shfl(wsum, gbase | h);
    ushort4 ov[4];
#pragma unroll
    for (int i0 = 0; i0 < 4; ++i0) {     // head of a[i0*4+j] = i0
        float4 Av = *(const float4*)&A1s[q * 16 + i0 * 4];
        float4 Bv = *(const float4*)&B1s[q * 16 + i0 * 4];
        float o0 = a[i0 * 4 + 0] * inv[i0] * Av.x + Bv.x;
        float o1 = a[i0 * 4 + 1] * inv[i0] * Av.y + Bv.y;
        float o2 = a[i0 * 4 + 2] * inv[i0] * Av.z + Bv.z;
        float o3 = a[i0 * 4 + 3] * inv[i0] * Av.w + Bv.w;
        o0 = (o0 > 0.f) ? o0 : expm1f(o0);
        o1 = (o1 > 0.f) ? o1 : expm1f(o1);
        o2 = (o2 > 0.f) ? o2 : expm1f(o2);
        o3 = (o3 > 0.f) ? o3 : expm1f(o3);
        ov[i0].x = f2bf(o0); ov[i0].y = f2bf(o1); ov[i0].z = f2bf(o2); ov[i0].w = f2bf(o3);
    }
#pragma unroll
    for (int i0 = 0; i0 < 4; ++i0)
        *(ushort4*)&hb[(size_t)d * 256 + q * 16 + i0 * 4] = ov[i0];
}

// ---------------- GEMM2 (MFMA): h2(fp8, perm) = hb @ W2, scores es2/ed2 --------

__global__ __launch_bounds__(256)
void k_gemm2(const unsigned short* __restrict__ hbbf, const unsigned short* __restrict__ W2Tg,
             const float* __restrict__ a_s, const float* __restrict__ a_d,
             unsigned char* __restrict__ h2f8, float* __restrict__ es2, float* __restrict__ ed2) {
    __shared__ unsigned short W2T[64 * 264];
    int t = threadIdx.x;
    for (int c = t; c < 2048; c += 256) {            // 2048 chunks of 8 bf16
        int n = c >> 5, k8 = (c & 31) * 8;
        *(short8*)&W2T[n * 264 + k8] = *(const short8*)&W2Tg[n * 256 + k8];
    }
    __syncthreads();
    int wid = t >> 6, lane = t & 63;
    int quad = lane >> 4, col = lane & 15;
    float as_r[4], ad_r[4];
#pragma unroll
    for (int i = 0; i < 4; ++i) {
        as_r[i] = a_s[i * 16 + col];
        ad_r[i] = a_d[i * 16 + col];
    }
    int tile = blockIdx.x * 4 + wid;
    if (tile >= 3125) return;
    int base = tile * 16;
    short8 af[8];
#pragma unroll
    for (int kk = 0; kk < 8; ++kk)
        af[kk] = *(const short8*)&hbbf[(size_t)(base + col) * 256 + kk * 32 + quad * 8];
    f32x4 acc[4];
#pragma unroll
    for (int nt = 0; nt < 4; ++nt) acc[nt] = (f32x4){0.f, 0.f, 0.f, 0.f};
#pragma unroll
    for (int kk = 0; kk < 8; ++kk) {
#pragma unroll
        for (int nt = 0; nt < 4; ++nt) {
            short8 b = *(const short8*)&W2T[(nt * 16 + col) * 264 + kk * 32 + quad * 8];
            acc[nt] = __builtin_amdgcn_mfma_f32_16x16x32_bf16(af[kk], b, acc[nt], 0, 0, 0);
        }
    }
    float esp[4], edp[4];
#pragma unroll
    for (int r = 0; r < 4; ++r) { esp[r] = 0.f; edp[r] = 0.f; }
#pragma unroll
    for (int nt = 0; nt < 4; ++nt)
#pragma unroll
        for (int r = 0; r < 4; ++r) {
            esp[r] += acc[nt][r] * as_r[nt];
            edp[r] += acc[nt][r] * ad_r[nt];
        }
#pragma unroll
    for (int r = 0; r < 4; ++r) {
        float v = esp[r], w = edp[r];
#pragma unroll
        for (int m = 1; m <= 8; m <<= 1) { v += __shfl_xor(v, m); w += __shfl_xor(w, m); }
        esp[r] = v; edp[r] = w;
    }
    if (col == 0) {
#pragma unroll
        for (int r = 0; r < 4; ++r) {
            int node = base + quad * 4 + r;
            es2[node] = esp[r];
            ed2[node] = edp[r];
        }
    }
    // h2 fp8 store, permuted: byte slot col*4+nt (4B store per row)
#pragma unroll
    for (int r = 0; r < 4; ++r) {
        unsigned pk = pack4_fp8(acc[0][r], acc[1][r], acc[2][r], acc[3][r]);
        *(unsigned*)&h2f8[(size_t)(base + quad * 4 + r) * 64 + col * 4] = pk;
    }
}

// ---------------- GAT2: 16-lane group per dst node, chunk=4 edges ----------

__global__ __launch_bounds__(256)
void k_gat2(const unsigned char* __restrict__ h2f8, const float* __restrict__ es2,
            const float* __restrict__ ed2, const int* __restrict__ offs,
            const unsigned short* __restrict__ csr,
            const float* __restrict__ A2s, const float* __restrict__ B2s,
            float* __restrict__ out2) {
    int tid = threadIdx.x;
    int l = tid & 63;
    int gbase = l & 48;
    int q = tid & 15;
    int d = blockIdx.x * 16 + (tid >> 4);
    int start = offs[d], deg = offs[d + 1] - start;
    float edv = ed2[d];
    const unsigned char* hrow = h2f8 + q * 4;
    float a0 = 0.f, a1 = 0.f, a2 = 0.f, a3 = 0.f, wsum = 0.f;
    int e4 = q & 3;
    for (int c0 = 0; c0 < deg; c0 += 4) {
        int idx = c0 + e4;
        int s = csr[start + min(idx, deg - 1)];
        float w = (idx < deg) ? __expf(leaky(es2[s] + edv)) : 0.f;
        wsum += w;
        int se[4];
#pragma unroll
        for (int e = 0; e < 4; ++e) se[e] = __shfl(s, gbase | e);
        unsigned rv[4];
#pragma unroll
        for (int e = 0; e < 4; ++e)
            rv[e] = *(const unsigned*)(hrow + ((size_t)(unsigned)se[e] << 6));
#pragma unroll
        for (int e = 0; e < 4; ++e) {
            float we = __shfl(w, gbase | e);
            f32x2 p;
            p = __builtin_amdgcn_cvt_pk_f32_fp8((int)rv[e], false); a0 += we * p.x; a1 += we * p.y;
            p = __builtin_amdgcn_cvt_pk_f32_fp8((int)rv[e], true);  a2 += we * p.x; a3 += we * p.y;
        }
    }
    wsum += __shfl_xor(wsum, 1);
    wsum += __shfl_xor(wsum, 2);        // every lane: dn (each lane quartet covers e=0..3)
    float inv = 1.f / wsum;
    float4 Av = *(const float4*)&A2s[q * 4];
    float4 Bv = *(const float4*)&B2s[q * 4];
    float4 o;
    o.x = a0 * inv * Av.x + Bv.x;
    o.y = a1 * inv * Av.y + Bv.y;
    o.z = a2 * inv * Av.z + Bv.z;
    o.w = a3 * inv * Av.w + Bv.w;
    *(float4*)&out2[(size_t)d * 64 + q * 4] = o;
}

// ---------------- pool stage 1: run-length accumulate + atomic flush --------
// block handles 128 nodes; wave w covers nodes [base+w*32, +32), lane = channel.
// batch is sorted, so per-wave runs are contiguous -> few f32 atomics.

#define POOLB ((N_NODES + 127) / 128)

__global__ __launch_bounds__(256)
void k_pool1(const float* __restrict__ out2, const int* __restrict__ batch,
             float* __restrict__ pooled) {
    int t = threadIdx.x;
    int sub = t >> 6, ch = t & 63;
    int istart = blockIdx.x * 128 + sub * 32;
    int iend = min(istart + 32, N_NODES);
    if (istart >= N_NODES) return;
    int curg = batch[istart];
    float acc = 0.f;
    for (int i = istart; i < iend; ++i) {
        int g = batch[i];
        if (g != curg) {
            atomicAdd(&pooled[curg * 64 + ch], acc);
            acc = 0.f;
            curg = g;
        }
        acc += out2[(size_t)i * 64 + ch];
    }
    atomicAdd(&pooled[curg * 64 + ch], acc);
}

// ---------------- MLP head + log_softmax (divide + slot->real mapping) -------

__device__ int lower_bound_i(const int* a, int n, int key) {
    int lo = 0, hi = n;
    while (lo < hi) {
        int mid = (lo + hi) >> 1;
        if (a[mid] < key) lo = mid + 1; else hi = mid;
    }
    return lo;
}

__global__ void k_head(const float* __restrict__ pooled, const int* __restrict__ batch,
                       const float* __restrict__ lw1, const float* __restrict__ lb1,
                       const float* __restrict__ lw2, const float* __restrict__ lb2,
                       float* __restrict__ out) {
    int g = threadIdx.x;
    if (g >= GGRAPHS) return;
    int s0 = lower_bound_i(batch, N_NODES, g);
    int s1 = lower_bound_i(batch, N_NODES, g + 1);
    int cnt = s1 - s0;
    float invc = 1.f / (float)((cnt > 0) ? cnt : 1);
    float p[64];
#pragma unroll
    for (int c = 0; c < 64; ++c) p[c] = pooled[g * 64 + c] * invc;
    float z0 = lb2[0], z1 = lb2[1], z2 = lb2[2];
    for (int j = 0; j < 32; ++j) {
        float hj = lb1[j];
#pragma unroll
        for (int c = 0; c < 64; ++c) {
            int rc = (c & 3) * 16 + (c >> 2);    // slot c holds real channel rc
            hj += p[c] * lw1[rc * 32 + j];
        }
        hj = fmaxf(hj, 0.f);
        z0 += hj * lw2[j * 3 + 0];
        z1 += hj * lw2[j * 3 + 1];
        z2 += hj * lw2[j * 3 + 2];
    }
    float m = fmaxf(z0, fmaxf(z1, z2));
    float lse = logf(expf(z0 - m) + expf(z1 - m) + expf(z2 - m)) + m;
    out[g * 3 + 0] = z0 - lse;
    out[g * 3 + 1] = z1 - lse;
    out[g * 3 + 2] = z2 - lse;
}

// ---------------- launch ----------------

extern "C" void kernel_launch(void* const* d_in, const int* in_sizes, int n_in,
                              void* d_out, int out_size, void* d_ws, size_t ws_size,
                              hipStream_t stream) {
    (void)in_sizes; (void)n_in; (void)out_size; (void)ws_size;
    const float* x    = (const float*)d_in[0];
    const int*   ei   = (const int*)d_in[1];
    const int*   batch= (const int*)d_in[2];
    const float* W1   = (const float*)d_in[3];
    const float* a_s1 = (const float*)d_in[4];
    const float* a_d1 = (const float*)d_in[5];
    const float* b1   = (const float*)d_in[6];
    const float* g1   = (const float*)d_in[7];
    const float* be1  = (const float*)d_in[8];
    const float* m1   = (const float*)d_in[9];
    const float* v1   = (const float*)d_in[10];
    const float* W2   = (const float*)d_in[11];
    const float* a_s2 = (const float*)d_in[12];
    const float* a_d2 = (const float*)d_in[13];
    const float* b2   = (const float*)d_in[14];
    const float* g2   = (const float*)d_in[15];
    const float* be2  = (const float*)d_in[16];
    const float* m2   = (const float*)d_in[17];
    const float* v2   = (const float*)d_in[18];
    const float* lw1  = (const float*)d_in[19];
    const float* lb1  = (const float*)d_in[20];
    const float* lw2  = (const float*)d_in[21];
    const float* lb2  = (const float*)d_in[22];
    float* out = (float*)d_out;

    char* ws = (char*)d_ws;
    size_t off = 0;
    auto alloc = [&](size_t bytes) -> void* {
        void* p = ws + off;
        off += (bytes + 255) & ~(size_t)255;
        return p;
    };
    unsigned short* xbf = (unsigned short*)alloc((size_t)N_NODES * 64 * 2);    // bf16
    unsigned short* W1T = (unsigned short*)alloc((size_t)16384 * 2);           // bf16 [n][k]
    unsigned short* W2T = (unsigned short*)alloc((size_t)16384 * 2);           // bf16 [n][k'] perm
    unsigned char*  h1  = (unsigned char*)alloc((size_t)N_NODES * 256);        // fp8 perm
    unsigned short* hb  = (unsigned short*)alloc((size_t)N_NODES * 256 * 2);   // bf16 perm slots
    unsigned char*  h2  = (unsigned char*)alloc((size_t)N_NODES * 64);         // fp8 perm
    float* out2 = (float*)alloc((size_t)N_NODES * 64 * 4);                     // f32 slot layout
    float* es1  = (float*)alloc((size_t)N_NODES * 4 * 4);
    float* ed1  = (float*)alloc((size_t)N_NODES * 4 * 4);
    float* es2  = (float*)alloc((size_t)N_NODES * 4);
    float* ed2  = (float*)alloc((size_t)N_NODES * 4);
    float* pooled = (float*)alloc((size_t)GGRAPHS * 64 * 4);
    float* A1s  = (float*)alloc(256 * 4);
    float* B1s  = (float*)alloc(256 * 4);
    float* A2s  = (float*)alloc(64 * 4);
    float* B2s  = (float*)alloc(64 * 4);
    int*   cnt  = (int*)alloc((size_t)N_NODES * 4);
    int*   offs = (int*)alloc((size_t)(N_NODES + 1) * 4);
    int*   curs = (int*)alloc((size_t)N_NODES * 4);
    unsigned short* csr = (unsigned short*)alloc((size_t)ETOT * 2);
    int*   bsums= (int*)alloc(256 * 4);

    const int nscan = (N_NODES + 255) / 256;   // 196
    const int ntileb = (3125 + 3) / 4;         // 782 blocks for MFMA gemms
    const int ngat = 3125;                     // 16 nodes per block

    hipMemsetAsync(cnt, 0, (size_t)N_NODES * 4, stream);
    hipMemsetAsync(pooled, 0, (size_t)GGRAPHS * 64 * 4, stream);
    k_prep<<<NPREPB + NEDGEB, 256, 0, stream>>>(x, W1, W2, ei,
                                                b1, g1, be1, m1, v1,
                                                b2, g2, be2, m2, v2,
                                                xbf, W1T, W2T, A1s, B1s, A2s, B2s, cnt);
    k_scan_local<<<nscan, 256, 0, stream>>>(cnt, offs, bsums);
    k_scan_sums<<<1, 256, 0, stream>>>(bsums, nscan);
    k_scan_add<<<nscan, 256, 0, stream>>>(offs, curs, bsums);
    k_fill<<<NEDGEB, 256, 0, stream>>>(ei, curs, csr);

    k_gemm1<<<ntileb, 256, 0, stream>>>(xbf, W1T, a_s1, a_d1, h1, es1, ed1);
    k_gat1<<<ngat, 256, 0, stream>>>(h1, es1, ed1, offs, csr, A1s, B1s, hb);
    k_gemm2<<<ntileb, 256, 0, stream>>>(hb, W2T, a_s2, a_d2, h2, es2, ed2);
    k_gat2<<<ngat, 256, 0, stream>>>(h2, es2, ed2, offs, csr, A2s, B2s, out2);
    k_pool1<<<POOLB, 256, 0, stream>>>(out2, batch, pooled);
    k_head<<<1, 64, 0, stream>>>(pooled, batch, lw1, lb1, lw2, lb2, out);
}

// Round 10
// 294.024 us; speedup vs baseline: 1.3472x; 1.0665x over previous
//
#include <hip/hip_runtime.h>
#include <math.h>

#define N_NODES 50000
#define N_EDGES 800000
#define ETOT    (N_EDGES + N_NODES)   // self-loops appended
#define GGRAPHS 64
#define EPS_BN  1e-5f

typedef __attribute__((ext_vector_type(8))) short short8;
typedef __attribute__((ext_vector_type(4))) float f32x4;
typedef __attribute__((ext_vector_type(2))) float f32x2;

__device__ __forceinline__ unsigned short f2bf(float f) {
    union { float f; unsigned u; } v; v.f = f;
    unsigned r = v.u + 0x7fffu + ((v.u >> 16) & 1u);   // round-nearest-even
    return (unsigned short)(r >> 16);
}
__device__ __forceinline__ float leaky(float e) {
    return fmaxf(e, 0.2f * e);
}
// pack 4 f32 -> 4 fp8 (e4m3, OCP on gfx950)
__device__ __forceinline__ unsigned pack4_fp8(float a, float b, float c, float d) {
    int v = __builtin_amdgcn_cvt_pk_fp8_f32(a, b, 0, false);
    v = __builtin_amdgcn_cvt_pk_fp8_f32(c, d, v, true);
    return (unsigned)v;
}

// ---------------- prep (x->bf16, W1T, W2T, BN-fold) + hist, merged ----------

#define XQ (N_NODES * 64 / 4)
#define PREP_T (XQ + 32768 + 320)
#define NPREPB ((PREP_T + 255) / 256)
#define NEDGEB ((ETOT + 255) / 256)

// bucket-sort CSR build params
#define NBUK 196                       // dst >> 8
#define EPB  4096                      // edges per fill block
#define NBLK2 ((ETOT + EPB - 1) / EPB) // 208
#define CAP  5120                      // k_csr LDS capacity per bucket

__global__ void k_prep(const float* __restrict__ x, const float* __restrict__ W1,
                       const float* __restrict__ W2, const int* __restrict__ ei,
                       const float* __restrict__ b1, const float* __restrict__ g1,
                       const float* __restrict__ be1, const float* __restrict__ m1,
                       const float* __restrict__ v1,
                       const float* __restrict__ b2, const float* __restrict__ g2,
                       const float* __restrict__ be2, const float* __restrict__ m2,
                       const float* __restrict__ v2,
                       unsigned short* __restrict__ xbf,
                       unsigned short* __restrict__ W1T,
                       unsigned short* __restrict__ W2T,
                       float* __restrict__ A1s, float* __restrict__ B1s,
                       float* __restrict__ A2s, float* __restrict__ B2s,
                       int* __restrict__ cnt) {
    int b = blockIdx.x;
    if (b < NPREPB) {
        int t = b * 256 + threadIdx.x;
        if (t < XQ) {
            float4 v = *(const float4*)&x[t * 4];
            ushort4 o;
            o.x = f2bf(v.x); o.y = f2bf(v.y); o.z = f2bf(v.z); o.w = f2bf(v.w);
            *(ushort4*)&xbf[t * 4] = o;
        } else if (t < XQ + 16384) {
            int i = t - XQ;                 // W1T[n*64+k] = W1[k*256+n]
            int n = i >> 6, k = i & 63;
            W1T[i] = f2bf(W1[k * 256 + n]);
        } else if (t < XQ + 32768) {
            int i = t - XQ - 16384;         // W2T[n*256+k'] = W2[real(k')*64+n]
            int n = i >> 8, kp = i & 255;
            int rk = (kp & 15) * 16 + (kp >> 4);
            W2T[i] = f2bf(W2[rk * 64 + n]);
        } else if (t < XQ + 32768 + 256) {
            int z = t - XQ - 32768;         // hb slot z holds real (z&15)*16+(z>>4)
            int r = (z & 15) * 16 + (z >> 4);
            float A = g1[r] * rsqrtf(v1[r] + EPS_BN);
            A1s[z] = A;
            B1s[z] = (b1[r] - m1[r]) * A + be1[r];
        } else if (t < PREP_T) {
            int z = t - XQ - 32768 - 256;   // out2 slot z holds real (z&3)*16+(z>>2)
            int r = (z & 3) * 16 + (z >> 2);
            float A = g2[r] * rsqrtf(v2[r] + EPS_BN);
            A2s[z] = A;
            B2s[z] = (b2[r] - m2[r]) * A + be2[r];
        }
    } else {
        int e = (b - NPREPB) * 256 + threadIdx.x;
        if (e < ETOT) {
            int d = (e < N_EDGES) ? ei[N_EDGES + e] : (e - N_EDGES);
            atomicAdd(&cnt[d], 1);
        }
    }
}

// ---------------- node-prefix scan (offs) ----------------

__global__ void k_scan_local(const int* __restrict__ cnt, int* __restrict__ offs,
                             int* __restrict__ bsums) {
    __shared__ int s[256];
    int t = threadIdx.x, idx = blockIdx.x * 256 + t;
    int v = (idx < N_NODES) ? cnt[idx] : 0;
    s[t] = v; __syncthreads();
    for (int d2 = 1; d2 < 256; d2 <<= 1) {
        int add = (t >= d2) ? s[t - d2] : 0;
        __syncthreads();
        s[t] += add;
        __syncthreads();
    }
    if (idx < N_NODES) offs[idx] = s[t] - v;       // local exclusive
    if (t == 255) bsums[blockIdx.x] = s[255];
}

__global__ void k_scan_sums(int* __restrict__ bsums, int nb) {
    __shared__ int s[256];
    int t = threadIdx.x;
    int v = (t < nb) ? bsums[t] : 0;
    s[t] = v; __syncthreads();
    for (int d2 = 1; d2 < 256; d2 <<= 1) {
        int add = (t >= d2) ? s[t - d2] : 0;
        __syncthreads();
        s[t] += add;
        __syncthreads();
    }
    if (t < nb) bsums[t] = s[t] - v;               // exclusive
}

__global__ void k_scan_add(int* __restrict__ offs, int* __restrict__ cursor,
                           const int* __restrict__ bsums) {
    int idx = blockIdx.x * 256 + threadIdx.x;
    if (idx < N_NODES) {
        int o = offs[idx] + bsums[blockIdx.x];
        offs[idx] = o;
        cursor[idx] = o;
    }
    if (idx == 0) offs[N_NODES] = ETOT;
}

// ---------------- bucket-sorted CSR build ----------------
// k_bhist: per-(block,bucket) counts. k_bscan: per-bucket scan over blocks.
// k_bfill: dense (src,dst) pair scatter. k_csr: per-bucket LDS sort -> coalesced csr.

__global__ __launch_bounds__(256)
void k_bhist(const int* __restrict__ ei, int* __restrict__ gcnt) {
    __shared__ int c[NBUK];
    int t = threadIdx.x;
    for (int i = t; i < NBUK; i += 256) c[i] = 0;
    __syncthreads();
    int e0 = blockIdx.x * EPB;
#pragma unroll
    for (int j = 0; j < EPB / 256; ++j) {
        int e = e0 + j * 256 + t;
        if (e < ETOT) {
            int d = (e < N_EDGES) ? ei[N_EDGES + e] : (e - N_EDGES);
            atomicAdd(&c[d >> 8], 1);
        }
    }
    __syncthreads();
    for (int i = t; i < NBUK; i += 256) gcnt[i * NBLK2 + blockIdx.x] = c[i];
}

__global__ __launch_bounds__(256)
void k_bscan(const int* __restrict__ gcnt, const int* __restrict__ offs,
             int* __restrict__ gbase) {
    __shared__ int s[256];
    int b = blockIdx.x, t = threadIdx.x;
    int v = (t < NBLK2) ? gcnt[b * NBLK2 + t] : 0;
    s[t] = v; __syncthreads();
    for (int d2 = 1; d2 < 256; d2 <<= 1) {
        int add = (t >= d2) ? s[t - d2] : 0;
        __syncthreads();
        s[t] += add;
        __syncthreads();
    }
    int base = offs[min(b * 256, N_NODES)];
    if (t < NBLK2) gbase[b * NBLK2 + t] = base + s[t] - v;
}

__global__ __launch_bounds__(256)
void k_bfill(const int* __restrict__ ei, const int* __restrict__ gbase,
             unsigned* __restrict__ pairs) {
    __shared__ int cur[NBUK];
    int t = threadIdx.x;
    for (int i = t; i < NBUK; i += 256) cur[i] = gbase[i * NBLK2 + blockIdx.x];
    __syncthreads();
    int e0 = blockIdx.x * EPB;
#pragma unroll
    for (int j = 0; j < EPB / 256; ++j) {
        int e = e0 + j * 256 + t;
        if (e < ETOT) {
            int s, d;
            if (e < N_EDGES) { s = ei[e]; d = ei[N_EDGES + e]; }
            else             { s = d = e - N_EDGES; }
            int pos = atomicAdd(&cur[d >> 8], 1);
            pairs[pos] = (unsigned)s | ((unsigned)d << 16);
        }
    }
}

__global__ __launch_bounds__(256)
void k_csr(const unsigned* __restrict__ pairs, const int* __restrict__ offs,
           int* __restrict__ curs, unsigned short* __restrict__ csr) {
    __shared__ unsigned sp[CAP];
    __shared__ unsigned short lc[CAP];
    __shared__ int c256[256];
    __shared__ int o256[256];
    __shared__ int s[256];
    int b = blockIdx.x, t = threadIdx.x;
    int base = offs[min(b * 256, N_NODES)];
    int next = offs[min((b + 1) * 256, N_NODES)];
    int n = next - base;
    if (n <= CAP) {
        for (int i = t; i < n; i += 256) sp[i] = pairs[base + i];
        c256[t] = 0;
        __syncthreads();
        for (int i = t; i < n; i += 256) atomicAdd(&c256[(sp[i] >> 16) & 255], 1);
        __syncthreads();
        int v = c256[t];
        s[t] = v; __syncthreads();
        for (int d2 = 1; d2 < 256; d2 <<= 1) {
            int add = (t >= d2) ? s[t - d2] : 0;
            __syncthreads();
            s[t] += add;
            __syncthreads();
        }
        o256[t] = s[t] - v;
        __syncthreads();
        for (int i = t; i < n; i += 256) {
            unsigned p = sp[i];
            int pos = atomicAdd(&o256[(p >> 16) & 255], 1);
            lc[pos] = (unsigned short)(p & 0xffff);
        }
        __syncthreads();
        for (int i = t; i < n; i += 256) csr[base + i] = lc[i];
    } else {
        // statistical impossibility fallback: direct global scatter
        for (int i = t; i < n; i += 256) {
            unsigned p = pairs[base + i];
            int d = b * 256 + ((p >> 16) & 255);
            int pos = atomicAdd(&curs[d], 1);
            csr[pos] = (unsigned short)(p & 0xffff);
        }
    }
}

// ---------------- GEMM1 (MFMA): h1(fp8, perm layout) = x @ W1, scores ----------
// h1 slot s of a row holds real channel (s&15)*16 + (s>>4).

__global__ __launch_bounds__(256)
void k_gemm1(const unsigned short* __restrict__ xbf, const unsigned short* __restrict__ W1Tg,
             const float* __restrict__ a_s, const float* __restrict__ a_d,
             unsigned char* __restrict__ h1f8, float* __restrict__ es1, float* __restrict__ ed1) {
    __shared__ unsigned short W1T[256 * 72];
    int t = threadIdx.x;
    for (int c = t; c < 2048; c += 256) {            // 2048 chunks of 8 bf16
        int n = c >> 3, k8 = (c & 7) * 8;
        *(short8*)&W1T[n * 72 + k8] = *(const short8*)&W1Tg[n * 64 + k8];
    }
    __syncthreads();
    int wid = t >> 6, lane = t & 63;
    int quad = lane >> 4, col = lane & 15;
    float as_r[16], ad_r[16];
#pragma unroll
    for (int i = 0; i < 16; ++i) {
        as_r[i] = a_s[i * 16 + col];
        ad_r[i] = a_d[i * 16 + col];
    }
    int tile = blockIdx.x * 4 + wid;
    if (tile >= 3125) return;
    int base = tile * 16;
    short8 a0 = *(const short8*)&xbf[(size_t)(base + col) * 64 + quad * 8];
    short8 a1 = *(const short8*)&xbf[(size_t)(base + col) * 64 + 32 + quad * 8];
    f32x4 acc[16];
#pragma unroll
    for (int nt = 0; nt < 16; ++nt) acc[nt] = (f32x4){0.f, 0.f, 0.f, 0.f};
#pragma unroll
    for (int nt = 0; nt < 16; ++nt) {
        short8 b0 = *(const short8*)&W1T[(nt * 16 + col) * 72 + quad * 8];
        short8 b1 = *(const short8*)&W1T[(nt * 16 + col) * 72 + 32 + quad * 8];
        acc[nt] = __builtin_amdgcn_mfma_f32_16x16x32_bf16(a0, b0, acc[nt], 0, 0, 0);
        acc[nt] = __builtin_amdgcn_mfma_f32_16x16x32_bf16(a1, b1, acc[nt], 0, 0, 0);
    }
    float esp[16], edp[16];
#pragma unroll
    for (int i = 0; i < 16; ++i) { esp[i] = 0.f; edp[i] = 0.f; }
#pragma unroll
    for (int nt = 0; nt < 16; ++nt) {
        int hd = nt >> 2;
#pragma unroll
        for (int r = 0; r < 4; ++r) {
            esp[hd * 4 + r] += acc[nt][r] * as_r[nt];
            edp[hd * 4 + r] += acc[nt][r] * ad_r[nt];
        }
    }
#pragma unroll
    for (int i = 0; i < 16; ++i) {
        float v = esp[i], w = edp[i];
#pragma unroll
        for (int m = 1; m <= 8; m <<= 1) { v += __shfl_xor(v, m); w += __shfl_xor(w, m); }
        esp[i] = v; edp[i] = w;
    }
    if (col == 0) {
#pragma unroll
        for (int hd = 0; hd < 4; ++hd)
#pragma unroll
            for (int r = 0; r < 4; ++r) {
                int node = base + quad * 4 + r;
                es1[node * 4 + hd] = esp[hd * 4 + r];
                ed1[node * 4 + hd] = edp[hd * 4 + r];
            }
    }
    // h1 fp8 store, permuted: byte slot col*16+nt  (16B vector store per row)
#pragma unroll
    for (int r = 0; r < 4; ++r) {
        uint4 pk;
        pk.x = pack4_fp8(acc[0][r],  acc[1][r],  acc[2][r],  acc[3][r]);
        pk.y = pack4_fp8(acc[4][r],  acc[5][r],  acc[6][r],  acc[7][r]);
        pk.z = pack4_fp8(acc[8][r],  acc[9][r],  acc[10][r], acc[11][r]);
        pk.w = pack4_fp8(acc[12][r], acc[13][r], acc[14][r], acc[15][r]);
        *(uint4*)&h1f8[(size_t)(base + quad * 4 + r) * 256 + col * 16] = pk;
    }
}

// ---------------- GAT1: 16-lane group per dst node, chunk=4 edges ----------

__global__ __launch_bounds__(256)
void k_gat1(const unsigned char* __restrict__ h1f8, const float* __restrict__ es1,
            const float* __restrict__ ed1, const int* __restrict__ offs,
            const unsigned short* __restrict__ csr,
            const float* __restrict__ A1s, const float* __restrict__ B1s,
            unsigned short* __restrict__ hb) {
    int tid = threadIdx.x;
    int l = tid & 63;
    int gbase = l & 48;
    int q = tid & 15;
    int d = blockIdx.x * 16 + (tid >> 4);
    int start = offs[d], deg = offs[d + 1] - start;
    int e4 = q >> 2, hd = q & 3;
    float edv = ed1[d * 4 + hd];
    const unsigned char* hrow = h1f8 + q * 16;
    float a[16];
#pragma unroll
    for (int i = 0; i < 16; ++i) a[i] = 0.f;
    float wsum = 0.f;
    for (int c0 = 0; c0 < deg; c0 += 4) {
        int idx = c0 + e4;
        int s = csr[start + min(idx, deg - 1)];
        float w = (idx < deg) ? __expf(leaky(es1[s * 4 + hd] + edv)) : 0.f;
        wsum += w;
        int se[4];
#pragma unroll
        for (int e = 0; e < 4; ++e) se[e] = __shfl(s, gbase | (e << 2));
        uint4 rv[4];
#pragma unroll
        for (int e = 0; e < 4; ++e)
            rv[e] = *(const uint4*)(hrow + ((size_t)(unsigned)se[e] << 8));
#pragma unroll
        for (int e = 0; e < 4; ++e) {
            float w0 = __shfl(w, gbase | (e << 2) | 0);
            float w1 = __shfl(w, gbase | (e << 2) | 1);
            float w2 = __shfl(w, gbase | (e << 2) | 2);
            float w3 = __shfl(w, gbase | (e << 2) | 3);
            f32x2 p;
            p = __builtin_amdgcn_cvt_pk_f32_fp8((int)rv[e].x, false); a[0]  += w0 * p.x; a[1]  += w0 * p.y;
            p = __builtin_amdgcn_cvt_pk_f32_fp8((int)rv[e].x, true);  a[2]  += w0 * p.x; a[3]  += w0 * p.y;
            p = __builtin_amdgcn_cvt_pk_f32_fp8((int)rv[e].y, false); a[4]  += w1 * p.x; a[5]  += w1 * p.y;
            p = __builtin_amdgcn_cvt_pk_f32_fp8((int)rv[e].y, true);  a[6]  += w1 * p.x; a[7]  += w1 * p.y;
            p = __builtin_amdgcn_cvt_pk_f32_fp8((int)rv[e].z, false); a[8]  += w2 * p.x; a[9]  += w2 * p.y;
            p = __builtin_amdgcn_cvt_pk_f32_fp8((int)rv[e].z, true);  a[10] += w2 * p.x; a[11] += w2 * p.y;
            p = __builtin_amdgcn_cvt_pk_f32_fp8((int)rv[e].w, false); a[12] += w3 * p.x; a[13] += w3 * p.y;
            p = __builtin_amdgcn_cvt_pk_f32_fp8((int)rv[e].w, true);  a[14] += w3 * p.x; a[15] += w3 * p.y;
        }
    }
    wsum += __shfl_xor(wsum, 4);
    wsum += __shfl_xor(wsum, 8);        // lane q now holds dn[head q&3]
    float inv[4];
#pragma unroll
    for (int h = 0; h < 4; ++h) inv[h] = 1.f / __shfl(wsum, gbase | h);
    ushort4 ov[4];
#pragma unroll
    for (int i0 = 0; i0 < 4; ++i0) {     // head of a[i0*4+j] = i0
        float4 Av = *(const float4*)&A1s[q * 16 + i0 * 4];
        float4 Bv = *(const float4*)&B1s[q * 16 + i0 * 4];
        float o0 = a[i0 * 4 + 0] * inv[i0] * Av.x + Bv.x;
        float o1 = a[i0 * 4 + 1] * inv[i0] * Av.y + Bv.y;
        float o2 = a[i0 * 4 + 2] * inv[i0] * Av.z + Bv.z;
        float o3 = a[i0 * 4 + 3] * inv[i0] * Av.w + Bv.w;
        o0 = (o0 > 0.f) ? o0 : expm1f(o0);
        o1 = (o1 > 0.f) ? o1 : expm1f(o1);
        o2 = (o2 > 0.f) ? o2 : expm1f(o2);
        o3 = (o3 > 0.f) ? o3 : expm1f(o3);
        ov[i0].x = f2bf(o0); ov[i0].y = f2bf(o1); ov[i0].z = f2bf(o2); ov[i0].w = f2bf(o3);
    }
#pragma unroll
    for (int i0 = 0; i0 < 4; ++i0)
        *(ushort4*)&hb[(size_t)d * 256 + q * 16 + i0 * 4] = ov[i0];
}

// ---------------- GEMM2 (MFMA): h2(fp8, perm) = hb @ W2, scores es2/ed2 --------

__global__ __launch_bounds__(256)
void k_gemm2(const unsigned short* __restrict__ hbbf, const unsigned short* __restrict__ W2Tg,
             const float* __restrict__ a_s, const float* __restrict__ a_d,
             unsigned char* __restrict__ h2f8, float* __restrict__ es2, float* __restrict__ ed2) {
    __shared__ unsigned short W2T[64 * 264];
    int t = threadIdx.x;
    for (int c = t; c < 2048; c += 256) {            // 2048 chunks of 8 bf16
        int n = c >> 5, k8 = (c & 31) * 8;
        *(short8*)&W2T[n * 264 + k8] = *(const short8*)&W2Tg[n * 256 + k8];
    }
    __syncthreads();
    int wid = t >> 6, lane = t & 63;
    int quad = lane >> 4, col = lane & 15;
    float as_r[4], ad_r[4];
#pragma unroll
    for (int i = 0; i < 4; ++i) {
        as_r[i] = a_s[i * 16 + col];
        ad_r[i] = a_d[i * 16 + col];
    }
    int tile = blockIdx.x * 4 + wid;
    if (tile >= 3125) return;
    int base = tile * 16;
    short8 af[8];
#pragma unroll
    for (int kk = 0; kk < 8; ++kk)
        af[kk] = *(const short8*)&hbbf[(size_t)(base + col) * 256 + kk * 32 + quad * 8];
    f32x4 acc[4];
#pragma unroll
    for (int nt = 0; nt < 4; ++nt) acc[nt] = (f32x4){0.f, 0.f, 0.f, 0.f};
#pragma unroll
    for (int kk = 0; kk < 8; ++kk) {
#pragma unroll
        for (int nt = 0; nt < 4; ++nt) {
            short8 b = *(const short8*)&W2T[(nt * 16 + col) * 264 + kk * 32 + quad * 8];
            acc[nt] = __builtin_amdgcn_mfma_f32_16x16x32_bf16(af[kk], b, acc[nt], 0, 0, 0);
        }
    }
    float esp[4], edp[4];
#pragma unroll
    for (int r = 0; r < 4; ++r) { esp[r] = 0.f; edp[r] = 0.f; }
#pragma unroll
    for (int nt = 0; nt < 4; ++nt)
#pragma unroll
        for (int r = 0; r < 4; ++r) {
            esp[r] += acc[nt][r] * as_r[nt];
            edp[r] += acc[nt][r] * ad_r[nt];
        }
#pragma unroll
    for (int r = 0; r < 4; ++r) {
        float v = esp[r], w = edp[r];
#pragma unroll
        for (int m = 1; m <= 8; m <<= 1) { v += __shfl_xor(v, m); w += __shfl_xor(w, m); }
        esp[r] = v; edp[r] = w;
    }
    if (col == 0) {
#pragma unroll
        for (int r = 0; r < 4; ++r) {
            int node = base + quad * 4 + r;
            es2[node] = esp[r];
            ed2[node] = edp[r];
        }
    }
    // h2 fp8 store, permuted: byte slot col*4+nt (4B store per row)
#pragma unroll
    for (int r = 0; r < 4; ++r) {
        unsigned pk = pack4_fp8(acc[0][r], acc[1][r], acc[2][r], acc[3][r]);
        *(unsigned*)&h2f8[(size_t)(base + quad * 4 + r) * 64 + col * 4] = pk;
    }
}

// ---------------- GAT2: 16-lane group per dst node, chunk=4 edges ----------

__global__ __launch_bounds__(256)
void k_gat2(const unsigned char* __restrict__ h2f8, const float* __restrict__ es2,
            const float* __restrict__ ed2, const int* __restrict__ offs,
            const unsigned short* __restrict__ csr,
            const float* __restrict__ A2s, const float* __restrict__ B2s,
            float* __restrict__ out2) {
    int tid = threadIdx.x;
    int l = tid & 63;
    int gbase = l & 48;
    int q = tid & 15;
    int d = blockIdx.x * 16 + (tid >> 4);
    int start = offs[d], deg = offs[d + 1] - start;
    float edv = ed2[d];
    const unsigned char* hrow = h2f8 + q * 4;
    float a0 = 0.f, a1 = 0.f, a2 = 0.f, a3 = 0.f, wsum = 0.f;
    int e4 = q & 3;
    for (int c0 = 0; c0 < deg; c0 += 4) {
        int idx = c0 + e4;
        int s = csr[start + min(idx, deg - 1)];
        float w = (idx < deg) ? __expf(leaky(es2[s] + edv)) : 0.f;
        wsum += w;
        int se[4];
#pragma unroll
        for (int e = 0; e < 4; ++e) se[e] = __shfl(s, gbase | e);
        unsigned rv[4];
#pragma unroll
        for (int e = 0; e < 4; ++e)
            rv[e] = *(const unsigned*)(hrow + ((size_t)(unsigned)se[e] << 6));
#pragma unroll
        for (int e = 0; e < 4; ++e) {
            float we = __shfl(w, gbase | e);
            f32x2 p;
            p = __builtin_amdgcn_cvt_pk_f32_fp8((int)rv[e], false); a0 += we * p.x; a1 += we * p.y;
            p = __builtin_amdgcn_cvt_pk_f32_fp8((int)rv[e], true);  a2 += we * p.x; a3 += we * p.y;
        }
    }
    wsum += __shfl_xor(wsum, 1);
    wsum += __shfl_xor(wsum, 2);        // every lane: dn (each lane quartet covers e=0..3)
    float inv = 1.f / wsum;
    float4 Av = *(const float4*)&A2s[q * 4];
    float4 Bv = *(const float4*)&B2s[q * 4];
    float4 o;
    o.x = a0 * inv * Av.x + Bv.x;
    o.y = a1 * inv * Av.y + Bv.y;
    o.z = a2 * inv * Av.z + Bv.z;
    o.w = a3 * inv * Av.w + Bv.w;
    *(float4*)&out2[(size_t)d * 64 + q * 4] = o;
}

// ---------------- pool stage 1: run-length accumulate + atomic flush --------

#define POOLB ((N_NODES + 127) / 128)

__global__ __launch_bounds__(256)
void k_pool1(const float* __restrict__ out2, const int* __restrict__ batch,
             float* __restrict__ pooled) {
    int t = threadIdx.x;
    int sub = t >> 6, ch = t & 63;
    int istart = blockIdx.x * 128 + sub * 32;
    int iend = min(istart + 32, N_NODES);
    if (istart >= N_NODES) return;
    int curg = batch[istart];
    float acc = 0.f;
    for (int i = istart; i < iend; ++i) {
        int g = batch[i];
        if (g != curg) {
            atomicAdd(&pooled[curg * 64 + ch], acc);
            acc = 0.f;
            curg = g;
        }
        acc += out2[(size_t)i * 64 + ch];
    }
    atomicAdd(&pooled[curg * 64 + ch], acc);
}

// ---------------- MLP head + log_softmax (divide + slot->real mapping) -------

__device__ int lower_bound_i(const int* a, int n, int key) {
    int lo = 0, hi = n;
    while (lo < hi) {
        int mid = (lo + hi) >> 1;
        if (a[mid] < key) lo = mid + 1; else hi = mid;
    }
    return lo;
}

__global__ void k_head(const float* __restrict__ pooled, const int* __restrict__ batch,
                       const float* __restrict__ lw1, const float* __restrict__ lb1,
                       const float* __restrict__ lw2, const float* __restrict__ lb2,
                       float* __restrict__ out) {
    int g = threadIdx.x;
    if (g >= GGRAPHS) return;
    int s0 = lower_bound_i(batch, N_NODES, g);
    int s1 = lower_bound_i(batch, N_NODES, g + 1);
    int cnt = s1 - s0;
    float invc = 1.f / (float)((cnt > 0) ? cnt : 1);
    float p[64];
#pragma unroll
    for (int c = 0; c < 64; ++c) p[c] = pooled[g * 64 + c] * invc;
    float z0 = lb2[0], z1 = lb2[1], z2 = lb2[2];
    for (int j = 0; j < 32; ++j) {
        float hj = lb1[j];
#pragma unroll
        for (int c = 0; c < 64; ++c) {
            int rc = (c & 3) * 16 + (c >> 2);    // slot c holds real channel rc
            hj += p[c] * lw1[rc * 32 + j];
        }
        hj = fmaxf(hj, 0.f);
        z0 += hj * lw2[j * 3 + 0];
        z1 += hj * lw2[j * 3 + 1];
        z2 += hj * lw2[j * 3 + 2];
    }
    float m = fmaxf(z0, fmaxf(z1, z2));
    float lse = logf(expf(z0 - m) + expf(z1 - m) + expf(z2 - m)) + m;
    out[g * 3 + 0] = z0 - lse;
    out[g * 3 + 1] = z1 - lse;
    out[g * 3 + 2] = z2 - lse;
}

// ---------------- launch ----------------

extern "C" void kernel_launch(void* const* d_in, const int* in_sizes, int n_in,
                              void* d_out, int out_size, void* d_ws, size_t ws_size,
                              hipStream_t stream) {
    (void)in_sizes; (void)n_in; (void)out_size; (void)ws_size;
    const float* x    = (const float*)d_in[0];
    const int*   ei   = (const int*)d_in[1];
    const int*   batch= (const int*)d_in[2];
    const float* W1   = (const float*)d_in[3];
    const float* a_s1 = (const float*)d_in[4];
    const float* a_d1 = (const float*)d_in[5];
    const float* b1   = (const float*)d_in[6];
    const float* g1   = (const float*)d_in[7];
    const float* be1  = (const float*)d_in[8];
    const float* m1   = (const float*)d_in[9];
    const float* v1   = (const float*)d_in[10];
    const float* W2   = (const float*)d_in[11];
    const float* a_s2 = (const float*)d_in[12];
    const float* a_d2 = (const float*)d_in[13];
    const float* b2   = (const float*)d_in[14];
    const float* g2   = (const float*)d_in[15];
    const float* be2  = (const float*)d_in[16];
    const float* m2   = (const float*)d_in[17];
    const float* v2   = (const float*)d_in[18];
    const float* lw1  = (const float*)d_in[19];
    const float* lb1  = (const float*)d_in[20];
    const float* lw2  = (const float*)d_in[21];
    const float* lb2  = (const float*)d_in[22];
    float* out = (float*)d_out;

    char* ws = (char*)d_ws;
    size_t off = 0;
    auto alloc = [&](size_t bytes) -> void* {
        void* p = ws + off;
        off += (bytes + 255) & ~(size_t)255;
        return p;
    };
    unsigned short* xbf = (unsigned short*)alloc((size_t)N_NODES * 64 * 2);    // bf16
    unsigned short* W1T = (unsigned short*)alloc((size_t)16384 * 2);           // bf16 [n][k]
    unsigned short* W2T = (unsigned short*)alloc((size_t)16384 * 2);           // bf16 [n][k'] perm
    unsigned char*  h1  = (unsigned char*)alloc((size_t)N_NODES * 256);        // fp8 perm
    unsigned short* hb  = (unsigned short*)alloc((size_t)N_NODES * 256 * 2);   // bf16 perm slots
    unsigned char*  h2  = (unsigned char*)alloc((size_t)N_NODES * 64);         // fp8 perm
    float* out2 = (float*)alloc((size_t)N_NODES * 64 * 4);                     // f32 slot layout
    float* es1  = (float*)alloc((size_t)N_NODES * 4 * 4);
    float* ed1  = (float*)alloc((size_t)N_NODES * 4 * 4);
    float* es2  = (float*)alloc((size_t)N_NODES * 4);
    float* ed2  = (float*)alloc((size_t)N_NODES * 4);
    float* pooled = (float*)alloc((size_t)GGRAPHS * 64 * 4);
    float* A1s  = (float*)alloc(256 * 4);
    float* B1s  = (float*)alloc(256 * 4);
    float* A2s  = (float*)alloc(64 * 4);
    float* B2s  = (float*)alloc(64 * 4);
    int*   cnt  = (int*)alloc((size_t)N_NODES * 4);
    int*   offs = (int*)alloc((size_t)(N_NODES + 1) * 4);
    int*   curs = (int*)alloc((size_t)N_NODES * 4);
    unsigned short* csr = (unsigned short*)alloc((size_t)ETOT * 2);
    unsigned* pairs = (unsigned*)alloc((size_t)ETOT * 4);
    int* gcnt  = (int*)alloc((size_t)NBUK * NBLK2 * 4);
    int* gbase = (int*)alloc((size_t)NBUK * NBLK2 * 4);
    int*   bsums= (int*)alloc(256 * 4);

    const int nscan = (N_NODES + 255) / 256;   // 196
    const int ntileb = (3125 + 3) / 4;         // 782 blocks for MFMA gemms
    const int ngat = 3125;                     // 16 nodes per block

    hipMemsetAsync(cnt, 0, (size_t)N_NODES * 4, stream);
    hipMemsetAsync(pooled, 0, (size_t)GGRAPHS * 64 * 4, stream);
    k_prep<<<NPREPB + NEDGEB, 256, 0, stream>>>(x, W1, W2, ei,
                                                b1, g1, be1, m1, v1,
                                                b2, g2, be2, m2, v2,
                                                xbf, W1T, W2T, A1s, B1s, A2s, B2s, cnt);
    k_bhist<<<NBLK2, 256, 0, stream>>>(ei, gcnt);
    k_scan_local<<<nscan, 256, 0, stream>>>(cnt, offs, bsums);
    k_scan_sums<<<1, 256, 0, stream>>>(bsums, nscan);
    k_scan_add<<<nscan, 256, 0, stream>>>(offs, curs, bsums);
    k_bscan<<<NBUK, 256, 0, stream>>>(gcnt, offs, gbase);
    k_bfill<<<NBLK2, 256, 0, stream>>>(ei, gbase, pairs);
    k_csr<<<NBUK, 256, 0, stream>>>(pairs, offs, curs, csr);

    k_gemm1<<<ntileb, 256, 0, stream>>>(xbf, W1T, a_s1, a_d1, h1, es1, ed1);
    k_gat1<<<ngat, 256, 0, stream>>>(h1, es1, ed1, offs, csr, A1s, B1s, hb);
    k_gemm2<<<ntileb, 256, 0, stream>>>(hb, W2T, a_s2, a_d2, h2, es2, ed2);
    k_gat2<<<ngat, 256, 0, stream>>>(h2, es2, ed2, offs, csr, A2s, B2s, out2);
    k_pool1<<<POOLB, 256, 0, stream>>>(out2, batch, pooled);
    k_head<<<1, 64, 0, stream>>>(pooled, batch, lw1, lb1, lw2, lb2, out);
}

// Round 11
// 259.732 us; speedup vs baseline: 1.5251x; 1.1320x over previous
//
#include <hip/hip_runtime.h>
#include <math.h>

#define N_NODES 50000
#define N_EDGES 800000
#define ETOT    (N_EDGES + N_NODES)   // self-loops appended
#define GGRAPHS 64
#define EPS_BN  1e-5f

typedef __attribute__((ext_vector_type(8))) short short8;
typedef __attribute__((ext_vector_type(4))) float f32x4;
typedef __attribute__((ext_vector_type(2))) float f32x2;

__device__ __forceinline__ unsigned short f2bf(float f) {
    union { float f; unsigned u; } v; v.f = f;
    unsigned r = v.u + 0x7fffu + ((v.u >> 16) & 1u);   // round-nearest-even
    return (unsigned short)(r >> 16);
}
__device__ __forceinline__ float leaky(float e) {
    return fmaxf(e, 0.2f * e);
}
// pack 4 f32 -> 4 fp8 (e4m3, OCP on gfx950)
__device__ __forceinline__ unsigned pack4_fp8(float a, float b, float c, float d) {
    int v = __builtin_amdgcn_cvt_pk_fp8_f32(a, b, 0, false);
    v = __builtin_amdgcn_cvt_pk_fp8_f32(c, d, v, true);
    return (unsigned)v;
}
// load 8 f32, convert to bf16 short8
__device__ __forceinline__ short8 cvt8(const float* p) {
    float4 u = *(const float4*)p;
    float4 v = *(const float4*)(p + 4);
    short8 r;
    r[0] = (short)f2bf(u.x); r[1] = (short)f2bf(u.y);
    r[2] = (short)f2bf(u.z); r[3] = (short)f2bf(u.w);
    r[4] = (short)f2bf(v.x); r[5] = (short)f2bf(v.y);
    r[6] = (short)f2bf(v.z); r[7] = (short)f2bf(v.w);
    return r;
}

// bucket-sort CSR build params
#define NBUK 196                       // dst >> 8
#define EPB  4096                      // edges per fill block
#define NBLK2 ((ETOT + EPB - 1) / EPB) // 208
#define CAP  8192                      // k_csr LDS capacity per bucket (mean 4352)

// ---------------- prep: W1T, W2T bf16 + BN folds (weights only) ----------

#define PREP2_T (32768 + 320)

__global__ void k_prep(const float* __restrict__ W1, const float* __restrict__ W2,
                       const float* __restrict__ b1, const float* __restrict__ g1,
                       const float* __restrict__ be1, const float* __restrict__ m1,
                       const float* __restrict__ v1,
                       const float* __restrict__ b2, const float* __restrict__ g2,
                       const float* __restrict__ be2, const float* __restrict__ m2,
                       const float* __restrict__ v2,
                       unsigned short* __restrict__ W1T,
                       unsigned short* __restrict__ W2T,
                       float* __restrict__ A1s, float* __restrict__ B1s,
                       float* __restrict__ A2s, float* __restrict__ B2s) {
    int t = blockIdx.x * 256 + threadIdx.x;
    if (t < 16384) {
        int i = t;                      // W1T[n*64+k] = W1[k*256+n]
        int n = i >> 6, k = i & 63;
        W1T[i] = f2bf(W1[k * 256 + n]);
    } else if (t < 32768) {
        int i = t - 16384;              // W2T[n*256+k'] = W2[real(k')*64+n]
        int n = i >> 8, kp = i & 255;
        int rk = (kp & 15) * 16 + (kp >> 4);
        W2T[i] = f2bf(W2[rk * 64 + n]);
    } else if (t < 32768 + 256) {
        int z = t - 32768;              // hb slot z holds real (z&15)*16+(z>>4)
        int r = (z & 15) * 16 + (z >> 4);
        float A = g1[r] * rsqrtf(v1[r] + EPS_BN);
        A1s[z] = A;
        B1s[z] = (b1[r] - m1[r]) * A + be1[r];
    } else if (t < PREP2_T) {
        int z = t - 32768 - 256;        // out2 slot z holds real (z&3)*16+(z>>2)
        int r = (z & 3) * 16 + (z >> 2);
        float A = g2[r] * rsqrtf(v2[r] + EPS_BN);
        A2s[z] = A;
        B2s[z] = (b2[r] - m2[r]) * A + be2[r];
    }
}

// ---------------- bucket-sorted CSR build ----------------
// k_bhist: per-(block,bucket) counts. k_bsum: bucket totals + scan -> bstart.
// k_bscan: per-bucket scan over blocks. k_bfill: dense (src,dst) pair scatter.
// k_csr: per-bucket LDS sort -> coalesced csr + offs (per-node CSR offsets).

__global__ __launch_bounds__(256)
void k_bhist(const int* __restrict__ ei, int* __restrict__ gcnt) {
    __shared__ int c[NBUK];
    int t = threadIdx.x;
    for (int i = t; i < NBUK; i += 256) c[i] = 0;
    __syncthreads();
    int e0 = blockIdx.x * EPB;
#pragma unroll
    for (int j = 0; j < EPB / 256; ++j) {
        int e = e0 + j * 256 + t;
        if (e < ETOT) {
            int d = (e < N_EDGES) ? ei[N_EDGES + e] : (e - N_EDGES);
            atomicAdd(&c[d >> 8], 1);
        }
    }
    __syncthreads();
    for (int i = t; i < NBUK; i += 256) gcnt[i * NBLK2 + blockIdx.x] = c[i];
}

__global__ __launch_bounds__(256)
void k_bsum(const int* __restrict__ gcnt, int* __restrict__ bstart,
            int* __restrict__ offs) {
    __shared__ int s[256];
    int t = threadIdx.x;
    int total = 0;
    if (t < NBUK)
        for (int b = 0; b < NBLK2; ++b) total += gcnt[t * NBLK2 + b];
    s[t] = total; __syncthreads();
    for (int d2 = 1; d2 < 256; d2 <<= 1) {
        int add = (t >= d2) ? s[t - d2] : 0;
        __syncthreads();
        s[t] += add;
        __syncthreads();
    }
    if (t < NBUK) bstart[t] = s[t] - total;
    if (t == 0) { bstart[NBUK] = ETOT; offs[N_NODES] = ETOT; }
}

__global__ __launch_bounds__(256)
void k_bscan(const int* __restrict__ gcnt, const int* __restrict__ bstart,
             int* __restrict__ gbase) {
    __shared__ int s[256];
    int b = blockIdx.x, t = threadIdx.x;
    int v = (t < NBLK2) ? gcnt[b * NBLK2 + t] : 0;
    s[t] = v; __syncthreads();
    for (int d2 = 1; d2 < 256; d2 <<= 1) {
        int add = (t >= d2) ? s[t - d2] : 0;
        __syncthreads();
        s[t] += add;
        __syncthreads();
    }
    int base = bstart[b];
    if (t < NBLK2) gbase[b * NBLK2 + t] = base + s[t] - v;
}

__global__ __launch_bounds__(256)
void k_bfill(const int* __restrict__ ei, const int* __restrict__ gbase,
             unsigned* __restrict__ pairs) {
    __shared__ int cur[NBUK];
    int t = threadIdx.x;
    for (int i = t; i < NBUK; i += 256) cur[i] = gbase[i * NBLK2 + blockIdx.x];
    __syncthreads();
    int e0 = blockIdx.x * EPB;
#pragma unroll
    for (int j = 0; j < EPB / 256; ++j) {
        int e = e0 + j * 256 + t;
        if (e < ETOT) {
            int s, d;
            if (e < N_EDGES) { s = ei[e]; d = ei[N_EDGES + e]; }
            else             { s = d = e - N_EDGES; }
            int pos = atomicAdd(&cur[d >> 8], 1);
            pairs[pos] = (unsigned)s | ((unsigned)d << 16);
        }
    }
}

__global__ __launch_bounds__(256)
void k_csr(const unsigned* __restrict__ pairs, const int* __restrict__ bstart,
           int* __restrict__ offs, unsigned short* __restrict__ csr) {
    __shared__ unsigned sp[CAP];
    __shared__ unsigned short lc[CAP];
    __shared__ int c256[256];
    __shared__ int o256[256];
    __shared__ int s[256];
    int b = blockIdx.x, t = threadIdx.x;
    int base = bstart[b];
    int n = bstart[b + 1] - base;
    int node = b * 256 + t;
    if (n <= CAP) {
        for (int i = t; i < n; i += 256) sp[i] = pairs[base + i];
        c256[t] = 0;
        __syncthreads();
        for (int i = t; i < n; i += 256) atomicAdd(&c256[(sp[i] >> 16) & 255], 1);
        __syncthreads();
        int v = c256[t];
        s[t] = v; __syncthreads();
        for (int d2 = 1; d2 < 256; d2 <<= 1) {
            int add = (t >= d2) ? s[t - d2] : 0;
            __syncthreads();
            s[t] += add;
            __syncthreads();
        }
        int myoff = s[t] - v;
        o256[t] = myoff;
        if (node < N_NODES) offs[node] = base + myoff;
        __syncthreads();
        for (int i = t; i < n; i += 256) {
            unsigned p = sp[i];
            int pos = atomicAdd(&o256[(p >> 16) & 255], 1);
            lc[pos] = (unsigned short)(p & 0xffff);
        }
        __syncthreads();
        for (int i = t; i < n; i += 256) csr[base + i] = lc[i];
    } else {
        // statistical-impossibility fallback: stream from global twice
        c256[t] = 0;
        __syncthreads();
        for (int i = t; i < n; i += 256) atomicAdd(&c256[(pairs[base + i] >> 16) & 255], 1);
        __syncthreads();
        int v = c256[t];
        s[t] = v; __syncthreads();
        for (int d2 = 1; d2 < 256; d2 <<= 1) {
            int add = (t >= d2) ? s[t - d2] : 0;
            __syncthreads();
            s[t] += add;
            __syncthreads();
        }
        int myoff = s[t] - v;
        o256[t] = base + myoff;
        if (node < N_NODES) offs[node] = base + myoff;
        __syncthreads();
        for (int i = t; i < n; i += 256) {
            unsigned p = pairs[base + i];
            int pos = atomicAdd(&o256[(p >> 16) & 255], 1);
            csr[pos] = (unsigned short)(p & 0xffff);
        }
    }
}

// ---------------- GEMM1 (MFMA): h1(fp8, perm layout) = x @ W1, scores ----------
// A from f32 x with in-register bf16 cvt. h1 slot s holds real ch (s&15)*16+(s>>4).

__global__ __launch_bounds__(256)
void k_gemm1(const float* __restrict__ x, const unsigned short* __restrict__ W1Tg,
             const float* __restrict__ a_s, const float* __restrict__ a_d,
             unsigned char* __restrict__ h1f8, float* __restrict__ es1, float* __restrict__ ed1) {
    __shared__ unsigned short W1T[256 * 72];
    int t = threadIdx.x;
    for (int c = t; c < 2048; c += 256) {            // 2048 chunks of 8 bf16
        int n = c >> 3, k8 = (c & 7) * 8;
        *(short8*)&W1T[n * 72 + k8] = *(const short8*)&W1Tg[n * 64 + k8];
    }
    __syncthreads();
    int wid = t >> 6, lane = t & 63;
    int quad = lane >> 4, col = lane & 15;
    float as_r[16], ad_r[16];
#pragma unroll
    for (int i = 0; i < 16; ++i) {
        as_r[i] = a_s[i * 16 + col];
        ad_r[i] = a_d[i * 16 + col];
    }
    int tile = blockIdx.x * 4 + wid;
    if (tile >= 3125) return;
    int base = tile * 16;
    short8 a0 = cvt8(&x[(size_t)(base + col) * 64 + quad * 8]);
    short8 a1 = cvt8(&x[(size_t)(base + col) * 64 + 32 + quad * 8]);
    f32x4 acc[16];
#pragma unroll
    for (int nt = 0; nt < 16; ++nt) acc[nt] = (f32x4){0.f, 0.f, 0.f, 0.f};
#pragma unroll
    for (int nt = 0; nt < 16; ++nt) {
        short8 b0 = *(const short8*)&W1T[(nt * 16 + col) * 72 + quad * 8];
        short8 b1 = *(const short8*)&W1T[(nt * 16 + col) * 72 + 32 + quad * 8];
        acc[nt] = __builtin_amdgcn_mfma_f32_16x16x32_bf16(a0, b0, acc[nt], 0, 0, 0);
        acc[nt] = __builtin_amdgcn_mfma_f32_16x16x32_bf16(a1, b1, acc[nt], 0, 0, 0);
    }
    float esp[16], edp[16];
#pragma unroll
    for (int i = 0; i < 16; ++i) { esp[i] = 0.f; edp[i] = 0.f; }
#pragma unroll
    for (int nt = 0; nt < 16; ++nt) {
        int hd = nt >> 2;
#pragma unroll
        for (int r = 0; r < 4; ++r) {
            esp[hd * 4 + r] += acc[nt][r] * as_r[nt];
            edp[hd * 4 + r] += acc[nt][r] * ad_r[nt];
        }
    }
#pragma unroll
    for (int i = 0; i < 16; ++i) {
        float v = esp[i], w = edp[i];
#pragma unroll
        for (int m = 1; m <= 8; m <<= 1) { v += __shfl_xor(v, m); w += __shfl_xor(w, m); }
        esp[i] = v; edp[i] = w;
    }
    if (col == 0) {
#pragma unroll
        for (int hd = 0; hd < 4; ++hd)
#pragma unroll
            for (int r = 0; r < 4; ++r) {
                int node = base + quad * 4 + r;
                es1[node * 4 + hd] = esp[hd * 4 + r];
                ed1[node * 4 + hd] = edp[hd * 4 + r];
            }
    }
    // h1 fp8 store, permuted: byte slot col*16+nt  (16B vector store per row)
#pragma unroll
    for (int r = 0; r < 4; ++r) {
        uint4 pk;
        pk.x = pack4_fp8(acc[0][r],  acc[1][r],  acc[2][r],  acc[3][r]);
        pk.y = pack4_fp8(acc[4][r],  acc[5][r],  acc[6][r],  acc[7][r]);
        pk.z = pack4_fp8(acc[8][r],  acc[9][r],  acc[10][r], acc[11][r]);
        pk.w = pack4_fp8(acc[12][r], acc[13][r], acc[14][r], acc[15][r]);
        *(uint4*)&h1f8[(size_t)(base + quad * 4 + r) * 256 + col * 16] = pk;
    }
}

// ---------------- GAT1: 16-lane group per dst node, chunk=4 edges ----------

__global__ __launch_bounds__(256)
void k_gat1(const unsigned char* __restrict__ h1f8, const float* __restrict__ es1,
            const float* __restrict__ ed1, const int* __restrict__ offs,
            const unsigned short* __restrict__ csr,
            const float* __restrict__ A1s, const float* __restrict__ B1s,
            unsigned short* __restrict__ hb) {
    int tid = threadIdx.x;
    int l = tid & 63;
    int gbase = l & 48;
    int q = tid & 15;
    int d = blockIdx.x * 16 + (tid >> 4);
    int start = offs[d], deg = offs[d + 1] - start;
    int e4 = q >> 2, hd = q & 3;
    float edv = ed1[d * 4 + hd];
    const unsigned char* hrow = h1f8 + q * 16;
    float a[16];
#pragma unroll
    for (int i = 0; i < 16; ++i) a[i] = 0.f;
    float wsum = 0.f;
    for (int c0 = 0; c0 < deg; c0 += 4) {
        int idx = c0 + e4;
        int s = csr[start + min(idx, deg - 1)];
        float w = (idx < deg) ? __expf(leaky(es1[s * 4 + hd] + edv)) : 0.f;
        wsum += w;
        int se[4];
#pragma unroll
        for (int e = 0; e < 4; ++e) se[e] = __shfl(s, gbase | (e << 2));
        uint4 rv[4];
#pragma unroll
        for (int e = 0; e < 4; ++e)
            rv[e] = *(const uint4*)(hrow + ((size_t)(unsigned)se[e] << 8));
#pragma unroll
        for (int e = 0; e < 4; ++e) {
            float w0 = __shfl(w, gbase | (e << 2) | 0);
            float w1 = __shfl(w, gbase | (e << 2) | 1);
            float w2 = __shfl(w, gbase | (e << 2) | 2);
            float w3 = __shfl(w, gbase | (e << 2) | 3);
            f32x2 p;
            p = __builtin_amdgcn_cvt_pk_f32_fp8((int)rv[e].x, false); a[0]  += w0 * p.x; a[1]  += w0 * p.y;
            p = __builtin_amdgcn_cvt_pk_f32_fp8((int)rv[e].x, true);  a[2]  += w0 * p.x; a[3]  += w0 * p.y;
            p = __builtin_amdgcn_cvt_pk_f32_fp8((int)rv[e].y, false); a[4]  += w1 * p.x; a[5]  += w1 * p.y;
            p = __builtin_amdgcn_cvt_pk_f32_fp8((int)rv[e].y, true);  a[6]  += w1 * p.x; a[7]  += w1 * p.y;
            p = __builtin_amdgcn_cvt_pk_f32_fp8((int)rv[e].z, false); a[8]  += w2 * p.x; a[9]  += w2 * p.y;
            p = __builtin_amdgcn_cvt_pk_f32_fp8((int)rv[e].z, true);  a[10] += w2 * p.x; a[11] += w2 * p.y;
            p = __builtin_amdgcn_cvt_pk_f32_fp8((int)rv[e].w, false); a[12] += w3 * p.x; a[13] += w3 * p.y;
            p = __builtin_amdgcn_cvt_pk_f32_fp8((int)rv[e].w, true);  a[14] += w3 * p.x; a[15] += w3 * p.y;
        }
    }
    wsum += __shfl_xor(wsum, 4);
    wsum += __shfl_xor(wsum, 8);        // lane q now holds dn[head q&3]
    float inv[4];
#pragma unroll
    for (int h = 0; h < 4; ++h) inv[h] = 1.f / __shfl(wsum, gbase | h);
    ushort4 ov[4];
#pragma unroll
    for (int i0 = 0; i0 < 4; ++i0) {     // head of a[i0*4+j] = i0
        float4 Av = *(const float4*)&A1s[q * 16 + i0 * 4];
        float4 Bv = *(const float4*)&B1s[q * 16 + i0 * 4];
        float o0 = a[i0 * 4 + 0] * inv[i0] * Av.x + Bv.x;
        float o1 = a[i0 * 4 + 1] * inv[i0] * Av.y + Bv.y;
        float o2 = a[i0 * 4 + 2] * inv[i0] * Av.z + Bv.z;
        float o3 = a[i0 * 4 + 3] * inv[i0] * Av.w + Bv.w;
        o0 = (o0 > 0.f) ? o0 : expm1f(o0);
        o1 = (o1 > 0.f) ? o1 : expm1f(o1);
        o2 = (o2 > 0.f) ? o2 : expm1f(o2);
        o3 = (o3 > 0.f) ? o3 : expm1f(o3);
        ov[i0].x = f2bf(o0); ov[i0].y = f2bf(o1); ov[i0].z = f2bf(o2); ov[i0].w = f2bf(o3);
    }
#pragma unroll
    for (int i0 = 0; i0 < 4; ++i0)
        *(ushort4*)&hb[(size_t)d * 256 + q * 16 + i0 * 4] = ov[i0];
}

// ---------------- GEMM2 (MFMA): h2(fp8, perm) = hb @ W2, scores es2/ed2 --------

__global__ __launch_bounds__(256)
void k_gemm2(const unsigned short* __restrict__ hbbf, const unsigned short* __restrict__ W2Tg,
             const float* __restrict__ a_s, const float* __restrict__ a_d,
             unsigned char* __restrict__ h2f8, float* __restrict__ es2, float* __restrict__ ed2) {
    __shared__ unsigned short W2T[64 * 264];
    int t = threadIdx.x;
    for (int c = t; c < 2048; c += 256) {            // 2048 chunks of 8 bf16
        int n = c >> 5, k8 = (c & 31) * 8;
        *(short8*)&W2T[n * 264 + k8] = *(const short8*)&W2Tg[n * 256 + k8];
    }
    __syncthreads();
    int wid = t >> 6, lane = t & 63;
    int quad = lane >> 4, col = lane & 15;
    float as_r[4], ad_r[4];
#pragma unroll
    for (int i = 0; i < 4; ++i) {
        as_r[i] = a_s[i * 16 + col];
        ad_r[i] = a_d[i * 16 + col];
    }
    int tile = blockIdx.x * 4 + wid;
    if (tile >= 3125) return;
    int base = tile * 16;
    short8 af[8];
#pragma unroll
    for (int kk = 0; kk < 8; ++kk)
        af[kk] = *(const short8*)&hbbf[(size_t)(base + col) * 256 + kk * 32 + quad * 8];
    f32x4 acc[4];
#pragma unroll
    for (int nt = 0; nt < 4; ++nt) acc[nt] = (f32x4){0.f, 0.f, 0.f, 0.f};
#pragma unroll
    for (int kk = 0; kk < 8; ++kk) {
#pragma unroll
        for (int nt = 0; nt < 4; ++nt) {
            short8 b = *(const short8*)&W2T[(nt * 16 + col) * 264 + kk * 32 + quad * 8];
            acc[nt] = __builtin_amdgcn_mfma_f32_16x16x32_bf16(af[kk], b, acc[nt], 0, 0, 0);
        }
    }
    float esp[4], edp[4];
#pragma unroll
    for (int r = 0; r < 4; ++r) { esp[r] = 0.f; edp[r] = 0.f; }
#pragma unroll
    for (int nt = 0; nt < 4; ++nt)
#pragma unroll
        for (int r = 0; r < 4; ++r) {
            esp[r] += acc[nt][r] * as_r[nt];
            edp[r] += acc[nt][r] * ad_r[nt];
        }
#pragma unroll
    for (int r = 0; r < 4; ++r) {
        float v = esp[r], w = edp[r];
#pragma unroll
        for (int m = 1; m <= 8; m <<= 1) { v += __shfl_xor(v, m); w += __shfl_xor(w, m); }
        esp[r] = v; edp[r] = w;
    }
    if (col == 0) {
#pragma unroll
        for (int r = 0; r < 4; ++r) {
            int node = base + quad * 4 + r;
            es2[node] = esp[r];
            ed2[node] = edp[r];
        }
    }
    // h2 fp8 store, permuted: byte slot col*4+nt (4B store per row)
#pragma unroll
    for (int r = 0; r < 4; ++r) {
        unsigned pk = pack4_fp8(acc[0][r], acc[1][r], acc[2][r], acc[3][r]);
        *(unsigned*)&h2f8[(size_t)(base + quad * 4 + r) * 64 + col * 4] = pk;
    }
}

// ---------------- GAT2: 16-lane group per dst node, chunk=4 edges ----------

__global__ __launch_bounds__(256)
void k_gat2(const unsigned char* __restrict__ h2f8, const float* __restrict__ es2,
            const float* __restrict__ ed2, const int* __restrict__ offs,
            const unsigned short* __restrict__ csr,
            const float* __restrict__ A2s, const float* __restrict__ B2s,
            float* __restrict__ out2) {
    int tid = threadIdx.x;
    int l = tid & 63;
    int gbase = l & 48;
    int q = tid & 15;
    int d = blockIdx.x * 16 + (tid >> 4);
    int start = offs[d], deg = offs[d + 1] - start;
    float edv = ed2[d];
    const unsigned char* hrow = h2f8 + q * 4;
    float a0 = 0.f, a1 = 0.f, a2 = 0.f, a3 = 0.f, wsum = 0.f;
    int e4 = q & 3;
    for (int c0 = 0; c0 < deg; c0 += 4) {
        int idx = c0 + e4;
        int s = csr[start + min(idx, deg - 1)];
        float w = (idx < deg) ? __expf(leaky(es2[s] + edv)) : 0.f;
        wsum += w;
        int se[4];
#pragma unroll
        for (int e = 0; e < 4; ++e) se[e] = __shfl(s, gbase | e);
        unsigned rv[4];
#pragma unroll
        for (int e = 0; e < 4; ++e)
            rv[e] = *(const unsigned*)(hrow + ((size_t)(unsigned)se[e] << 6));
#pragma unroll
        for (int e = 0; e < 4; ++e) {
            float we = __shfl(w, gbase | e);
            f32x2 p;
            p = __builtin_amdgcn_cvt_pk_f32_fp8((int)rv[e], false); a0 += we * p.x; a1 += we * p.y;
            p = __builtin_amdgcn_cvt_pk_f32_fp8((int)rv[e], true);  a2 += we * p.x; a3 += we * p.y;
        }
    }
    wsum += __shfl_xor(wsum, 1);
    wsum += __shfl_xor(wsum, 2);        // every lane: dn (each lane quartet covers e=0..3)
    float inv = 1.f / wsum;
    float4 Av = *(const float4*)&A2s[q * 4];
    float4 Bv = *(const float4*)&B2s[q * 4];
    float4 o;
    o.x = a0 * inv * Av.x + Bv.x;
    o.y = a1 * inv * Av.y + Bv.y;
    o.z = a2 * inv * Av.z + Bv.z;
    o.w = a3 * inv * Av.w + Bv.w;
    *(float4*)&out2[(size_t)d * 64 + q * 4] = o;
}

// ---------------- pool stage 1: run-length accumulate + atomic flush --------

#define POOLB ((N_NODES + 127) / 128)

__global__ __launch_bounds__(256)
void k_pool1(const float* __restrict__ out2, const int* __restrict__ batch,
             float* __restrict__ pooled) {
    int t = threadIdx.x;
    int sub = t >> 6, ch = t & 63;
    int istart = blockIdx.x * 128 + sub * 32;
    int iend = min(istart + 32, N_NODES);
    if (istart >= N_NODES) return;
    int curg = batch[istart];
    float acc = 0.f;
    for (int i = istart; i < iend; ++i) {
        int g = batch[i];
        if (g != curg) {
            atomicAdd(&pooled[curg * 64 + ch], acc);
            acc = 0.f;
            curg = g;
        }
        acc += out2[(size_t)i * 64 + ch];
    }
    atomicAdd(&pooled[curg * 64 + ch], acc);
}

// ---------------- MLP head + log_softmax (divide + slot->real mapping) -------

__device__ int lower_bound_i(const int* a, int n, int key) {
    int lo = 0, hi = n;
    while (lo < hi) {
        int mid = (lo + hi) >> 1;
        if (a[mid] < key) lo = mid + 1; else hi = mid;
    }
    return lo;
}

__global__ void k_head(const float* __restrict__ pooled, const int* __restrict__ batch,
                       const float* __restrict__ lw1, const float* __restrict__ lb1,
                       const float* __restrict__ lw2, const float* __restrict__ lb2,
                       float* __restrict__ out) {
    int g = threadIdx.x;
    if (g >= GGRAPHS) return;
    int s0 = lower_bound_i(batch, N_NODES, g);
    int s1 = lower_bound_i(batch, N_NODES, g + 1);
    int cnt = s1 - s0;
    float invc = 1.f / (float)((cnt > 0) ? cnt : 1);
    float p[64];
#pragma unroll
    for (int c = 0; c < 64; ++c) p[c] = pooled[g * 64 + c] * invc;
    float z0 = lb2[0], z1 = lb2[1], z2 = lb2[2];
    for (int j = 0; j < 32; ++j) {
        float hj = lb1[j];
#pragma unroll
        for (int c = 0; c < 64; ++c) {
            int rc = (c & 3) * 16 + (c >> 2);    // slot c holds real channel rc
            hj += p[c] * lw1[rc * 32 + j];
        }
        hj = fmaxf(hj, 0.f);
        z0 += hj * lw2[j * 3 + 0];
        z1 += hj * lw2[j * 3 + 1];
        z2 += hj * lw2[j * 3 + 2];
    }
    float m = fmaxf(z0, fmaxf(z1, z2));
    float lse = logf(expf(z0 - m) + expf(z1 - m) + expf(z2 - m)) + m;
    out[g * 3 + 0] = z0 - lse;
    out[g * 3 + 1] = z1 - lse;
    out[g * 3 + 2] = z2 - lse;
}

// ---------------- launch ----------------

extern "C" void kernel_launch(void* const* d_in, const int* in_sizes, int n_in,
                              void* d_out, int out_size, void* d_ws, size_t ws_size,
                              hipStream_t stream) {
    (void)in_sizes; (void)n_in; (void)out_size; (void)ws_size;
    const float* x    = (const float*)d_in[0];
    const int*   ei   = (const int*)d_in[1];
    const int*   batch= (const int*)d_in[2];
    const float* W1   = (const float*)d_in[3];
    const float* a_s1 = (const float*)d_in[4];
    const float* a_d1 = (const float*)d_in[5];
    const float* b1   = (const float*)d_in[6];
    const float* g1   = (const float*)d_in[7];
    const float* be1  = (const float*)d_in[8];
    const float* m1   = (const float*)d_in[9];
    const float* v1   = (const float*)d_in[10];
    const float* W2   = (const float*)d_in[11];
    const float* a_s2 = (const float*)d_in[12];
    const float* a_d2 = (const float*)d_in[13];
    const float* b2   = (const float*)d_in[14];
    const float* g2   = (const float*)d_in[15];
    const float* be2  = (const float*)d_in[16];
    const float* m2   = (const float*)d_in[17];
    const float* v2   = (const float*)d_in[18];
    const float* lw1  = (const float*)d_in[19];
    const float* lb1  = (const float*)d_in[20];
    const float* lw2  = (const float*)d_in[21];
    const float* lb2  = (const float*)d_in[22];
    float* out = (float*)d_out;

    char* ws = (char*)d_ws;
    size_t off = 0;
    auto alloc = [&](size_t bytes) -> void* {
        void* p = ws + off;
        off += (bytes + 255) & ~(size_t)255;
        return p;
    };
    unsigned short* W1T = (unsigned short*)alloc((size_t)16384 * 2);           // bf16 [n][k]
    unsigned short* W2T = (unsigned short*)alloc((size_t)16384 * 2);           // bf16 [n][k'] perm
    unsigned char*  h1  = (unsigned char*)alloc((size_t)N_NODES * 256);        // fp8 perm
    unsigned short* hb  = (unsigned short*)alloc((size_t)N_NODES * 256 * 2);   // bf16 perm slots
    unsigned char*  h2  = (unsigned char*)alloc((size_t)N_NODES * 64);         // fp8 perm
    float* out2 = (float*)alloc((size_t)N_NODES * 64 * 4);                     // f32 slot layout
    float* es1  = (float*)alloc((size_t)N_NODES * 4 * 4);
    float* ed1  = (float*)alloc((size_t)N_NODES * 4 * 4);
    float* es2  = (float*)alloc((size_t)N_NODES * 4);
    float* ed2  = (float*)alloc((size_t)N_NODES * 4);
    float* pooled = (float*)alloc((size_t)GGRAPHS * 64 * 4);
    float* A1s  = (float*)alloc(256 * 4);
    float* B1s  = (float*)alloc(256 * 4);
    float* A2s  = (float*)alloc(64 * 4);
    float* B2s  = (float*)alloc(64 * 4);
    int*   offs = (int*)alloc((size_t)(N_NODES + 1) * 4);
    unsigned short* csr = (unsigned short*)alloc((size_t)ETOT * 2);
    unsigned* pairs = (unsigned*)alloc((size_t)ETOT * 4);
    int* gcnt  = (int*)alloc((size_t)NBUK * NBLK2 * 4);
    int* gbase = (int*)alloc((size_t)NBUK * NBLK2 * 4);
    int* bstart = (int*)alloc((size_t)(NBUK + 1) * 4);

    const int ntileb = (3125 + 3) / 4;         // 782 blocks for MFMA gemms
    const int ngat = 3125;                     // 16 nodes per block
    const int nprep = (PREP2_T + 255) / 256;   // 130

    hipMemsetAsync(pooled, 0, (size_t)GGRAPHS * 64 * 4, stream);
    k_prep<<<nprep, 256, 0, stream>>>(W1, W2, b1, g1, be1, m1, v1,
                                      b2, g2, be2, m2, v2,
                                      W1T, W2T, A1s, B1s, A2s, B2s);
    k_bhist<<<NBLK2, 256, 0, stream>>>(ei, gcnt);
    k_bsum<<<1, 256, 0, stream>>>(gcnt, bstart, offs);
    k_bscan<<<NBUK, 256, 0, stream>>>(gcnt, bstart, gbase);
    k_bfill<<<NBLK2, 256, 0, stream>>>(ei, gbase, pairs);
    k_csr<<<NBUK, 256, 0, stream>>>(pairs, bstart, offs, csr);

    k_gemm1<<<ntileb, 256, 0, stream>>>(x, W1T, a_s1, a_d1, h1, es1, ed1);
    k_gat1<<<ngat, 256, 0, stream>>>(h1, es1, ed1, offs, csr, A1s, B1s, hb);
    k_gemm2<<<ntileb, 256, 0, stream>>>(hb, W2T, a_s2, a_d2, h2, es2, ed2);
    k_gat2<<<ngat, 256, 0, stream>>>(h2, es2, ed2, offs, csr, A2s, B2s, out2);
    k_pool1<<<POOLB, 256, 0, stream>>>(out2, batch, pooled);
    k_head<<<1, 64, 0, stream>>>(pooled, batch, lw1, lb1, lw2, lb2, out);
}

// Round 12
// 236.361 us; speedup vs baseline: 1.6759x; 1.0989x over previous
//
#include <hip/hip_runtime.h>
#include <math.h>

#define N_NODES 50000
#define N_EDGES 800000
#define ETOT    (N_EDGES + N_NODES)   // self-loops appended
#define GGRAPHS 64
#define EPS_BN  1e-5f

typedef __attribute__((ext_vector_type(8))) short short8;
typedef __attribute__((ext_vector_type(4))) float f32x4;
typedef __attribute__((ext_vector_type(2))) float f32x2;

__device__ __forceinline__ unsigned short f2bf(float f) {
    union { float f; unsigned u; } v; v.f = f;
    unsigned r = v.u + 0x7fffu + ((v.u >> 16) & 1u);   // round-nearest-even
    return (unsigned short)(r >> 16);
}
__device__ __forceinline__ float leaky(float e) {
    return fmaxf(e, 0.2f * e);
}
// pack 4 f32 -> 4 fp8 (e4m3, OCP on gfx950)
__device__ __forceinline__ unsigned pack4_fp8(float a, float b, float c, float d) {
    int v = __builtin_amdgcn_cvt_pk_fp8_f32(a, b, 0, false);
    v = __builtin_amdgcn_cvt_pk_fp8_f32(c, d, v, true);
    return (unsigned)v;
}
// load 8 f32, convert to bf16 short8
__device__ __forceinline__ short8 cvt8(const float* p) {
    float4 u = *(const float4*)p;
    float4 v = *(const float4*)(p + 4);
    short8 r;
    r[0] = (short)f2bf(u.x); r[1] = (short)f2bf(u.y);
    r[2] = (short)f2bf(u.z); r[3] = (short)f2bf(u.w);
    r[4] = (short)f2bf(v.x); r[5] = (short)f2bf(v.y);
    r[6] = (short)f2bf(v.z); r[7] = (short)f2bf(v.w);
    return r;
}

// bucket-sort CSR build params
#define NBUK 196                       // dst >> 8
#define EPB  4096                      // edges per fill block
#define NBLK2 ((ETOT + EPB - 1) / EPB) // 208
#define CAPR 6144                      // fixed pairs region per bucket (mean 4352, +28 sigma)

// ---------------- prep (W1T/W2T/BN folds) + bucket fill, merged ----------

#define PREP2_T (32768 + 320)
#define NPREP ((PREP2_T + 255) / 256)  // 130

__global__ __launch_bounds__(256)
void k_prepfill(const float* __restrict__ W1, const float* __restrict__ W2,
                const float* __restrict__ b1, const float* __restrict__ g1,
                const float* __restrict__ be1, const float* __restrict__ m1,
                const float* __restrict__ v1,
                const float* __restrict__ b2, const float* __restrict__ g2,
                const float* __restrict__ be2, const float* __restrict__ m2,
                const float* __restrict__ v2,
                const int* __restrict__ ei,
                unsigned short* __restrict__ W1T,
                unsigned short* __restrict__ W2T,
                float* __restrict__ A1s, float* __restrict__ B1s,
                float* __restrict__ A2s, float* __restrict__ B2s,
                int* __restrict__ gcur, unsigned* __restrict__ pairs) {
    __shared__ int lcnt[NBUK];
    __shared__ int lbase[NBUK];
    if (blockIdx.x < NPREP) {
        int t = blockIdx.x * 256 + threadIdx.x;
        if (t < 16384) {
            int i = t;                      // W1T[n*64+k] = W1[k*256+n]
            int n = i >> 6, k = i & 63;
            W1T[i] = f2bf(W1[k * 256 + n]);
        } else if (t < 32768) {
            int i = t - 16384;              // W2T[n*256+k'] = W2[real(k')*64+n]
            int n = i >> 8, kp = i & 255;
            int rk = (kp & 15) * 16 + (kp >> 4);
            W2T[i] = f2bf(W2[rk * 64 + n]);
        } else if (t < 32768 + 256) {
            int z = t - 32768;              // hb slot z holds real (z&15)*16+(z>>4)
            int r = (z & 15) * 16 + (z >> 4);
            float A = g1[r] * rsqrtf(v1[r] + EPS_BN);
            A1s[z] = A;
            B1s[z] = (b1[r] - m1[r]) * A + be1[r];
        } else if (t < PREP2_T) {
            int z = t - 32768 - 256;        // pooled slot z holds real (z&3)*16+(z>>2)
            int r = (z & 3) * 16 + (z >> 2);
            float A = g2[r] * rsqrtf(v2[r] + EPS_BN);
            A2s[z] = A;
            B2s[z] = (b2[r] - m2[r]) * A + be2[r];
        }
        return;
    }
    // bucket fill: count in LDS, reserve global range, scatter pairs densely
    int t = threadIdx.x;
    int blk = blockIdx.x - NPREP;
    for (int i = t; i < NBUK; i += 256) lcnt[i] = 0;
    __syncthreads();
    int e0 = blk * EPB;
    int ds[16], ss[16];
#pragma unroll
    for (int j = 0; j < 16; ++j) {
        int e = e0 + j * 256 + t;
        int s = -1, d = -1;
        if (e < ETOT) {
            if (e < N_EDGES) { s = ei[e]; d = ei[N_EDGES + e]; }
            else             { s = d = e - N_EDGES; }
            atomicAdd(&lcnt[d >> 8], 1);
        }
        ds[j] = d; ss[j] = s;
    }
    __syncthreads();
    for (int i = t; i < NBUK; i += 256) {
        int c = lcnt[i];
        lbase[i] = i * CAPR + (c ? atomicAdd(&gcur[i], c) : 0);
    }
    __syncthreads();
#pragma unroll
    for (int j = 0; j < 16; ++j) {
        if (ds[j] >= 0) {
            int bk = ds[j] >> 8;
            int pos = atomicAdd(&lbase[bk], 1);
            if (pos < (bk + 1) * CAPR)
                pairs[pos] = (unsigned)ss[j] | ((unsigned)(ds[j] & 255) << 16);
        }
    }
}

// ---------------- bucket totals scan -> bstart ----------------

__global__ __launch_bounds__(256)
void k_bsum(const int* __restrict__ gcur, int* __restrict__ bstart,
            int* __restrict__ offs) {
    __shared__ int s[256];
    int t = threadIdx.x;
    int v = (t < NBUK) ? gcur[t] : 0;
    s[t] = v; __syncthreads();
    for (int d2 = 1; d2 < 256; d2 <<= 1) {
        int add = (t >= d2) ? s[t - d2] : 0;
        __syncthreads();
        s[t] += add;
        __syncthreads();
    }
    if (t < NBUK) bstart[t] = s[t] - v;
    if (t == 0) { bstart[NBUK] = ETOT; offs[N_NODES] = ETOT; }
}

// ---------------- per-bucket LDS sort -> coalesced csr + offs ----------------

#define CAP 6144

__global__ __launch_bounds__(256)
void k_csr(const unsigned* __restrict__ pairs, const int* __restrict__ gcur,
           const int* __restrict__ bstart, int* __restrict__ offs,
           unsigned short* __restrict__ csr) {
    __shared__ unsigned sp[CAP];
    __shared__ unsigned short lc[CAP];
    __shared__ int c256[256];
    __shared__ int o256[256];
    __shared__ int s[256];
    int b = blockIdx.x, t = threadIdx.x;
    int base = bstart[b];
    int n = gcur[b];
    int node = b * 256 + t;
    const unsigned* reg = pairs + (size_t)b * CAPR;
    for (int i = t; i < n; i += 256) sp[i] = reg[i];
    c256[t] = 0;
    __syncthreads();
    for (int i = t; i < n; i += 256) atomicAdd(&c256[(sp[i] >> 16) & 255], 1);
    __syncthreads();
    int v = c256[t];
    s[t] = v; __syncthreads();
    for (int d2 = 1; d2 < 256; d2 <<= 1) {
        int add = (t >= d2) ? s[t - d2] : 0;
        __syncthreads();
        s[t] += add;
        __syncthreads();
    }
    int myoff = s[t] - v;
    o256[t] = myoff;
    if (node < N_NODES) offs[node] = base + myoff;
    __syncthreads();
    for (int i = t; i < n; i += 256) {
        unsigned p = sp[i];
        int pos = atomicAdd(&o256[(p >> 16) & 255], 1);
        lc[pos] = (unsigned short)(p & 0xffff);
    }
    __syncthreads();
    for (int i = t; i < n; i += 256) csr[base + i] = lc[i];
}

// ---------------- GEMM1 (MFMA): h1(fp8, perm layout) = x @ W1, scores ----------
// A from f32 x with in-register bf16 cvt. h1 slot s holds real ch (s&15)*16+(s>>4).

__global__ __launch_bounds__(256)
void k_gemm1(const float* __restrict__ x, const unsigned short* __restrict__ W1Tg,
             const float* __restrict__ a_s, const float* __restrict__ a_d,
             unsigned char* __restrict__ h1f8, float* __restrict__ es1, float* __restrict__ ed1) {
    __shared__ unsigned short W1T[256 * 72];
    int t = threadIdx.x;
    for (int c = t; c < 2048; c += 256) {            // 2048 chunks of 8 bf16
        int n = c >> 3, k8 = (c & 7) * 8;
        *(short8*)&W1T[n * 72 + k8] = *(const short8*)&W1Tg[n * 64 + k8];
    }
    __syncthreads();
    int wid = t >> 6, lane = t & 63;
    int quad = lane >> 4, col = lane & 15;
    float as_r[16], ad_r[16];
#pragma unroll
    for (int i = 0; i < 16; ++i) {
        as_r[i] = a_s[i * 16 + col];
        ad_r[i] = a_d[i * 16 + col];
    }
    int tile = blockIdx.x * 4 + wid;
    if (tile >= 3125) return;
    int base = tile * 16;
    short8 a0 = cvt8(&x[(size_t)(base + col) * 64 + quad * 8]);
    short8 a1 = cvt8(&x[(size_t)(base + col) * 64 + 32 + quad * 8]);
    f32x4 acc[16];
#pragma unroll
    for (int nt = 0; nt < 16; ++nt) acc[nt] = (f32x4){0.f, 0.f, 0.f, 0.f};
#pragma unroll
    for (int nt = 0; nt < 16; ++nt) {
        short8 b0 = *(const short8*)&W1T[(nt * 16 + col) * 72 + quad * 8];
        short8 b1 = *(const short8*)&W1T[(nt * 16 + col) * 72 + 32 + quad * 8];
        acc[nt] = __builtin_amdgcn_mfma_f32_16x16x32_bf16(a0, b0, acc[nt], 0, 0, 0);
        acc[nt] = __builtin_amdgcn_mfma_f32_16x16x32_bf16(a1, b1, acc[nt], 0, 0, 0);
    }
    float esp[16], edp[16];
#pragma unroll
    for (int i = 0; i < 16; ++i) { esp[i] = 0.f; edp[i] = 0.f; }
#pragma unroll
    for (int nt = 0; nt < 16; ++nt) {
        int hd = nt >> 2;
#pragma unroll
        for (int r = 0; r < 4; ++r) {
            esp[hd * 4 + r] += acc[nt][r] * as_r[nt];
            edp[hd * 4 + r] += acc[nt][r] * ad_r[nt];
        }
    }
#pragma unroll
    for (int i = 0; i < 16; ++i) {
        float v = esp[i], w = edp[i];
#pragma unroll
        for (int m = 1; m <= 8; m <<= 1) { v += __shfl_xor(v, m); w += __shfl_xor(w, m); }
        esp[i] = v; edp[i] = w;
    }
    if (col == 0) {
#pragma unroll
        for (int hd = 0; hd < 4; ++hd)
#pragma unroll
            for (int r = 0; r < 4; ++r) {
                int node = base + quad * 4 + r;
                es1[node * 4 + hd] = esp[hd * 4 + r];
                ed1[node * 4 + hd] = edp[hd * 4 + r];
            }
    }
#pragma unroll
    for (int r = 0; r < 4; ++r) {
        uint4 pk;
        pk.x = pack4_fp8(acc[0][r],  acc[1][r],  acc[2][r],  acc[3][r]);
        pk.y = pack4_fp8(acc[4][r],  acc[5][r],  acc[6][r],  acc[7][r]);
        pk.z = pack4_fp8(acc[8][r],  acc[9][r],  acc[10][r], acc[11][r]);
        pk.w = pack4_fp8(acc[12][r], acc[13][r], acc[14][r], acc[15][r]);
        *(uint4*)&h1f8[(size_t)(base + quad * 4 + r) * 256 + col * 16] = pk;
    }
}

// ---------------- fused GAT1 + GEMM2 ----------------
// Phase 1 (gat1): 16-lane group per dst node, chunk=4 edges; hb -> LDS (bf16 slots).
// Phase 2 (gemm2): block tile = 16 nodes; wave w computes ntile w (output cols
// w*16..w*16+15) with A from LDS hbt, B from L2-resident W2Tg; scores reduced
// cross-wave in LDS; h2 fp8 staged in LDS then coalesced store.

__global__ __launch_bounds__(256)
void k_gat1g2(const unsigned char* __restrict__ h1f8, const float* __restrict__ es1,
              const float* __restrict__ ed1, const int* __restrict__ offs,
              const unsigned short* __restrict__ csr,
              const float* __restrict__ A1s, const float* __restrict__ B1s,
              const unsigned short* __restrict__ W2Tg,
              const float* __restrict__ a_s2, const float* __restrict__ a_d2,
              unsigned char* __restrict__ h2f8, float* __restrict__ es2,
              float* __restrict__ ed2) {
    __shared__ unsigned short hbt[16][264];
    __shared__ float esps[4][16], edps[4][16];
    __shared__ uint4 h2t4[64];                  // 16 nodes x 64 B
    unsigned char* h2t = (unsigned char*)h2t4;
    int tid = threadIdx.x;
    int l = tid & 63;
    int gbase = l & 48;
    int q = tid & 15;
    int dl = tid >> 4;
    int nbase = blockIdx.x * 16;
    int d = nbase + dl;
    int start = offs[d], deg = offs[d + 1] - start;
    int e4 = q >> 2, hd = q & 3;
    float edv = ed1[d * 4 + hd];
    const unsigned char* hrow = h1f8 + q * 16;
    float a[16];
#pragma unroll
    for (int i = 0; i < 16; ++i) a[i] = 0.f;
    float wsum = 0.f;
    for (int c0 = 0; c0 < deg; c0 += 4) {
        int idx = c0 + e4;
        int s = csr[start + min(idx, deg - 1)];
        float w = (idx < deg) ? __expf(leaky(es1[s * 4 + hd] + edv)) : 0.f;
        wsum += w;
        int se[4];
#pragma unroll
        for (int e = 0; e < 4; ++e) se[e] = __shfl(s, gbase | (e << 2));
        uint4 rv[4];
#pragma unroll
        for (int e = 0; e < 4; ++e)
            rv[e] = *(const uint4*)(hrow + ((size_t)(unsigned)se[e] << 8));
#pragma unroll
        for (int e = 0; e < 4; ++e) {
            float w0 = __shfl(w, gbase | (e << 2) | 0);
            float w1 = __shfl(w, gbase | (e << 2) | 1);
            float w2 = __shfl(w, gbase | (e << 2) | 2);
            float w3 = __shfl(w, gbase | (e << 2) | 3);
            f32x2 p;
            p = __builtin_amdgcn_cvt_pk_f32_fp8((int)rv[e].x, false); a[0]  += w0 * p.x; a[1]  += w0 * p.y;
            p = __builtin_amdgcn_cvt_pk_f32_fp8((int)rv[e].x, true);  a[2]  += w0 * p.x; a[3]  += w0 * p.y;
            p = __builtin_amdgcn_cvt_pk_f32_fp8((int)rv[e].y, false); a[4]  += w1 * p.x; a[5]  += w1 * p.y;
            p = __builtin_amdgcn_cvt_pk_f32_fp8((int)rv[e].y, true);  a[6]  += w1 * p.x; a[7]  += w1 * p.y;
            p = __builtin_amdgcn_cvt_pk_f32_fp8((int)rv[e].z, false); a[8]  += w2 * p.x; a[9]  += w2 * p.y;
            p = __builtin_amdgcn_cvt_pk_f32_fp8((int)rv[e].z, true);  a[10] += w2 * p.x; a[11] += w2 * p.y;
            p = __builtin_amdgcn_cvt_pk_f32_fp8((int)rv[e].w, false); a[12] += w3 * p.x; a[13] += w3 * p.y;
            p = __builtin_amdgcn_cvt_pk_f32_fp8((int)rv[e].w, true);  a[14] += w3 * p.x; a[15] += w3 * p.y;
        }
    }
    wsum += __shfl_xor(wsum, 4);
    wsum += __shfl_xor(wsum, 8);
    float inv[4];
#pragma unroll
    for (int h = 0; h < 4; ++h) inv[h] = 1.f / __shfl(wsum, gbase | h);
#pragma unroll
    for (int i0 = 0; i0 < 4; ++i0) {
        float4 Av = *(const float4*)&A1s[q * 16 + i0 * 4];
        float4 Bv = *(const float4*)&B1s[q * 16 + i0 * 4];
        float o0 = a[i0 * 4 + 0] * inv[i0] * Av.x + Bv.x;
        float o1 = a[i0 * 4 + 1] * inv[i0] * Av.y + Bv.y;
        float o2 = a[i0 * 4 + 2] * inv[i0] * Av.z + Bv.z;
        float o3 = a[i0 * 4 + 3] * inv[i0] * Av.w + Bv.w;
        o0 = (o0 > 0.f) ? o0 : expm1f(o0);
        o1 = (o1 > 0.f) ? o1 : expm1f(o1);
        o2 = (o2 > 0.f) ? o2 : expm1f(o2);
        o3 = (o3 > 0.f) ? o3 : expm1f(o3);
        ushort4 ov;
        ov.x = f2bf(o0); ov.y = f2bf(o1); ov.z = f2bf(o2); ov.w = f2bf(o3);
        *(ushort4*)&hbt[dl][q * 16 + i0 * 4] = ov;
    }
    __syncthreads();
    // ---- phase 2: gemm2 for this 16-node tile ----
    int w = tid >> 6;
    int quad = l >> 4, col = l & 15;
    short8 af[8];
#pragma unroll
    for (int kk = 0; kk < 8; ++kk)
        af[kk] = *(const short8*)&hbt[col][kk * 32 + quad * 8];
    f32x4 acc = (f32x4){0.f, 0.f, 0.f, 0.f};
#pragma unroll
    for (int kk = 0; kk < 8; ++kk) {
        short8 b = *(const short8*)&W2Tg[(w * 16 + col) * 256 + kk * 32 + quad * 8];
        acc = __builtin_amdgcn_mfma_f32_16x16x32_bf16(af[kk], b, acc, 0, 0, 0);
    }
    float asw = a_s2[w * 16 + col], adw = a_d2[w * 16 + col];
    float esp[4], edp[4];
#pragma unroll
    for (int r = 0; r < 4; ++r) { esp[r] = acc[r] * asw; edp[r] = acc[r] * adw; }
#pragma unroll
    for (int r = 0; r < 4; ++r) {
#pragma unroll
        for (int m = 1; m <= 8; m <<= 1) {
            esp[r] += __shfl_xor(esp[r], m);
            edp[r] += __shfl_xor(edp[r], m);
        }
    }
    if (col == 0) {
#pragma unroll
        for (int r = 0; r < 4; ++r) {
            esps[w][quad * 4 + r] = esp[r];
            edps[w][quad * 4 + r] = edp[r];
        }
    }
    // h2 fp8 bytes -> LDS (slot col*4+w holds output col w*16+col)
#pragma unroll
    for (int r = 0; r < 4; ++r) {
        unsigned pk = pack4_fp8(acc[r], acc[r], acc[r], acc[r]);
        h2t[(quad * 4 + r) * 64 + col * 4 + w] = (unsigned char)(pk & 0xff);
    }
    __syncthreads();
    if (tid < 16) {
        es2[nbase + tid] = esps[0][tid] + esps[1][tid] + esps[2][tid] + esps[3][tid];
        ed2[nbase + tid] = edps[0][tid] + edps[1][tid] + edps[2][tid] + edps[3][tid];
    }
    if (tid < 64) {
        int node = tid >> 2, c = tid & 3;
        *(uint4*)&h2f8[(size_t)(nbase + node) * 64 + c * 16] = h2t4[node * 4 + c];
    }
}

// ---------------- fused GAT2 + mean-pool ----------------
// Phase 1 (gat2): 16-lane group per dst node, chunk=4 edges. Phase 2: block's
// 16 node-vectors in LDS, 64 threads run-length reduce per graph segment,
// atomicAdd into pooled (slot layout).

__global__ __launch_bounds__(256)
void k_gat2p(const unsigned char* __restrict__ h2f8, const float* __restrict__ es2,
             const float* __restrict__ ed2, const int* __restrict__ offs,
             const unsigned short* __restrict__ csr,
             const float* __restrict__ A2s, const float* __restrict__ B2s,
             const int* __restrict__ batch, float* __restrict__ pooled) {
    __shared__ float ot[16][68];
    __shared__ int gbat[16];
    int tid = threadIdx.x;
    int l = tid & 63;
    int gbase = l & 48;
    int q = tid & 15;
    int dl = tid >> 4;
    int nbase = blockIdx.x * 16;
    int d = nbase + dl;
    int start = offs[d], deg = offs[d + 1] - start;
    float edv = ed2[d];
    const unsigned char* hrow = h2f8 + q * 4;
    float a0 = 0.f, a1 = 0.f, a2 = 0.f, a3 = 0.f, wsum = 0.f;
    int e4 = q & 3;
    for (int c0 = 0; c0 < deg; c0 += 4) {
        int idx = c0 + e4;
        int s = csr[start + min(idx, deg - 1)];
        float w = (idx < deg) ? __expf(leaky(es2[s] + edv)) : 0.f;
        wsum += w;
        int se[4];
#pragma unroll
        for (int e = 0; e < 4; ++e) se[e] = __shfl(s, gbase | e);
        unsigned rv[4];
#pragma unroll
        for (int e = 0; e < 4; ++e)
            rv[e] = *(const unsigned*)(hrow + ((size_t)(unsigned)se[e] << 6));
#pragma unroll
        for (int e = 0; e < 4; ++e) {
            float we = __shfl(w, gbase | e);
            f32x2 p;
            p = __builtin_amdgcn_cvt_pk_f32_fp8((int)rv[e], false); a0 += we * p.x; a1 += we * p.y;
            p = __builtin_amdgcn_cvt_pk_f32_fp8((int)rv[e], true);  a2 += we * p.x; a3 += we * p.y;
        }
    }
    wsum += __shfl_xor(wsum, 1);
    wsum += __shfl_xor(wsum, 2);
    float inv = 1.f / wsum;
    float4 Av = *(const float4*)&A2s[q * 4];
    float4 Bv = *(const float4*)&B2s[q * 4];
    ot[dl][q * 4 + 0] = a0 * inv * Av.x + Bv.x;
    ot[dl][q * 4 + 1] = a1 * inv * Av.y + Bv.y;
    ot[dl][q * 4 + 2] = a2 * inv * Av.z + Bv.z;
    ot[dl][q * 4 + 3] = a3 * inv * Av.w + Bv.w;
    if (tid < 16) gbat[tid] = batch[nbase + tid];
    __syncthreads();
    if (tid < 64) {
        int ch = tid;
        int curg = gbat[0];
        float acc = 0.f;
#pragma unroll
        for (int n = 0; n < 16; ++n) {
            int g = gbat[n];
            if (g != curg) {
                atomicAdd(&pooled[curg * 64 + ch], acc);
                acc = 0.f;
                curg = g;
            }
            acc += ot[n][ch];
        }
        atomicAdd(&pooled[curg * 64 + ch], acc);
    }
}

// ---------------- MLP head + log_softmax (divide + slot->real mapping) -------

__device__ int lower_bound_i(const int* a, int n, int key) {
    int lo = 0, hi = n;
    while (lo < hi) {
        int mid = (lo + hi) >> 1;
        if (a[mid] < key) lo = mid + 1; else hi = mid;
    }
    return lo;
}

__global__ void k_head(const float* __restrict__ pooled, const int* __restrict__ batch,
                       const float* __restrict__ lw1, const float* __restrict__ lb1,
                       const float* __restrict__ lw2, const float* __restrict__ lb2,
                       float* __restrict__ out) {
    int g = threadIdx.x;
    if (g >= GGRAPHS) return;
    int s0 = lower_bound_i(batch, N_NODES, g);
    int s1 = lower_bound_i(batch, N_NODES, g + 1);
    int cnt = s1 - s0;
    float invc = 1.f / (float)((cnt > 0) ? cnt : 1);
    float p[64];
#pragma unroll
    for (int c = 0; c < 64; ++c) p[c] = pooled[g * 64 + c] * invc;
    float z0 = lb2[0], z1 = lb2[1], z2 = lb2[2];
    for (int j = 0; j < 32; ++j) {
        float hj = lb1[j];
#pragma unroll
        for (int c = 0; c < 64; ++c) {
            int rc = (c & 3) * 16 + (c >> 2);    // slot c holds real channel rc
            hj += p[c] * lw1[rc * 32 + j];
        }
        hj = fmaxf(hj, 0.f);
        z0 += hj * lw2[j * 3 + 0];
        z1 += hj * lw2[j * 3 + 1];
        z2 += hj * lw2[j * 3 + 2];
    }
    float m = fmaxf(z0, fmaxf(z1, z2));
    float lse = logf(expf(z0 - m) + expf(z1 - m) + expf(z2 - m)) + m;
    out[g * 3 + 0] = z0 - lse;
    out[g * 3 + 1] = z1 - lse;
    out[g * 3 + 2] = z2 - lse;
}

// ---------------- launch ----------------

extern "C" void kernel_launch(void* const* d_in, const int* in_sizes, int n_in,
                              void* d_out, int out_size, void* d_ws, size_t ws_size,
                              hipStream_t stream) {
    (void)in_sizes; (void)n_in; (void)out_size; (void)ws_size;
    const float* x    = (const float*)d_in[0];
    const int*   ei   = (const int*)d_in[1];
    const int*   batch= (const int*)d_in[2];
    const float* W1   = (const float*)d_in[3];
    const float* a_s1 = (const float*)d_in[4];
    const float* a_d1 = (const float*)d_in[5];
    const float* b1   = (const float*)d_in[6];
    const float* g1   = (const float*)d_in[7];
    const float* be1  = (const float*)d_in[8];
    const float* m1   = (const float*)d_in[9];
    const float* v1   = (const float*)d_in[10];
    const float* W2   = (const float*)d_in[11];
    const float* a_s2 = (const float*)d_in[12];
    const float* a_d2 = (const float*)d_in[13];
    const float* b2   = (const float*)d_in[14];
    const float* g2   = (const float*)d_in[15];
    const float* be2  = (const float*)d_in[16];
    const float* m2   = (const float*)d_in[17];
    const float* v2   = (const float*)d_in[18];
    const float* lw1  = (const float*)d_in[19];
    const float* lb1  = (const float*)d_in[20];
    const float* lw2  = (const float*)d_in[21];
    const float* lb2  = (const float*)d_in[22];
    float* out = (float*)d_out;

    char* ws = (char*)d_ws;
    size_t off = 0;
    auto alloc = [&](size_t bytes) -> void* {
        void* p = ws + off;
        off += (bytes + 255) & ~(size_t)255;
        return p;
    };
    // pooled + gcur adjacent: one memset covers both (16384 + 1024 bytes)
    float* pooled = (float*)alloc((size_t)GGRAPHS * 64 * 4);     // 16384 B
    int*   gcur   = (int*)alloc((size_t)NBUK * 4);               // -> 1024 B slot
    unsigned short* W1T = (unsigned short*)alloc((size_t)16384 * 2);
    unsigned short* W2T = (unsigned short*)alloc((size_t)16384 * 2);
    unsigned char*  h1  = (unsigned char*)alloc((size_t)N_NODES * 256);   // fp8 perm
    unsigned char*  h2  = (unsigned char*)alloc((size_t)N_NODES * 64);    // fp8 perm
    float* es1  = (float*)alloc((size_t)N_NODES * 4 * 4);
    float* ed1  = (float*)alloc((size_t)N_NODES * 4 * 4);
    float* es2  = (float*)alloc((size_t)N_NODES * 4);
    float* ed2  = (float*)alloc((size_t)N_NODES * 4);
    float* A1s  = (float*)alloc(256 * 4);
    float* B1s  = (float*)alloc(256 * 4);
    float* A2s  = (float*)alloc(64 * 4);
    float* B2s  = (float*)alloc(64 * 4);
    int*   offs = (int*)alloc((size_t)(N_NODES + 1) * 4);
    unsigned short* csr = (unsigned short*)alloc((size_t)ETOT * 2);
    unsigned* pairs = (unsigned*)alloc((size_t)NBUK * CAPR * 4);
    int* bstart = (int*)alloc((size_t)(NBUK + 1) * 4);

    const int ntileb = (3125 + 3) / 4;         // 782 blocks for gemm1
    const int ngat = 3125;                     // 16 nodes per block

    hipMemsetAsync(pooled, 0, 16384 + 1024, stream);   // pooled + gcur
    k_prepfill<<<NPREP + NBLK2, 256, 0, stream>>>(W1, W2, b1, g1, be1, m1, v1,
                                                  b2, g2, be2, m2, v2, ei,
                                                  W1T, W2T, A1s, B1s, A2s, B2s,
                                                  gcur, pairs);
    k_bsum<<<1, 256, 0, stream>>>(gcur, bstart, offs);
    k_csr<<<NBUK, 256, 0, stream>>>(pairs, gcur, bstart, offs, csr);

    k_gemm1<<<ntileb, 256, 0, stream>>>(x, W1T, a_s1, a_d1, h1, es1, ed1);
    k_gat1g2<<<ngat, 256, 0, stream>>>(h1, es1, ed1, offs, csr, A1s, B1s,
                                       W2T, a_s2, a_d2, h2, es2, ed2);
    k_gat2p<<<ngat, 256, 0, stream>>>(h2, es2, ed2, offs, csr, A2s, B2s,
                                      batch, pooled);
    k_head<<<1, 64, 0, stream>>>(pooled, batch, lw1, lb1, lw2, lb2, out);
}

// Round 13
// 226.409 us; speedup vs baseline: 1.7496x; 1.0440x over previous
//
#include <hip/hip_runtime.h>
#include <math.h>

#define N_NODES 50000
#define N_EDGES 800000
#define ETOT    (N_EDGES + N_NODES)   // self-loops appended
#define GGRAPHS 64
#define EPS_BN  1e-5f

typedef __attribute__((ext_vector_type(8))) short short8;
typedef __attribute__((ext_vector_type(4))) float f32x4;
typedef __attribute__((ext_vector_type(2))) float f32x2;

__device__ __forceinline__ unsigned short f2bf(float f) {
    union { float f; unsigned u; } v; v.f = f;
    unsigned r = v.u + 0x7fffu + ((v.u >> 16) & 1u);   // round-nearest-even
    return (unsigned short)(r >> 16);
}
__device__ __forceinline__ float leaky(float e) {
    return fmaxf(e, 0.2f * e);
}
// pack 4 f32 -> 4 fp8 (e4m3, OCP on gfx950)
__device__ __forceinline__ unsigned pack4_fp8(float a, float b, float c, float d) {
    int v = __builtin_amdgcn_cvt_pk_fp8_f32(a, b, 0, false);
    v = __builtin_amdgcn_cvt_pk_fp8_f32(c, d, v, true);
    return (unsigned)v;
}

// bucket-sort CSR build params
#define NBUK 196                       // dst >> 8
#define EPB  4096                      // edges per fill block
#define NBLK2 ((ETOT + EPB - 1) / EPB) // 208
#define CAPR 6144                      // fixed pairs region per bucket (mean 4352, +28 sigma)
#define CAP  6144

// mega-kernel block ranges
#define PREPW_T (16384 + 320)
#define NPREPW ((PREPW_T + 255) / 256) // 66
#define NT1B 782                       // gemm1 tile blocks (4 tiles each, 3125 tiles)
#define NMEGA (NBLK2 + NPREPW + NT1B)  // 1056

// ---------------- MEGA: bucket fill | W2T+BN prep | gemm1 ----------------

__global__ __launch_bounds__(256)
void k_mega(const float* __restrict__ x, const int* __restrict__ ei,
            const float* __restrict__ W1, const float* __restrict__ W2,
            const float* __restrict__ b1, const float* __restrict__ g1,
            const float* __restrict__ be1, const float* __restrict__ m1,
            const float* __restrict__ v1,
            const float* __restrict__ b2, const float* __restrict__ g2,
            const float* __restrict__ be2, const float* __restrict__ m2,
            const float* __restrict__ v2,
            const float* __restrict__ a_s, const float* __restrict__ a_d,
            unsigned short* __restrict__ W2T,
            float* __restrict__ A1s, float* __restrict__ B1s,
            float* __restrict__ A2s, float* __restrict__ B2s,
            int* __restrict__ gcur, unsigned* __restrict__ pairs,
            unsigned char* __restrict__ h1f8,
            float* __restrict__ es1, float* __restrict__ ed1) {
    __shared__ unsigned short W1T[256 * 72];     // gemm1 branch (36.9 KB)
    __shared__ int lcnt[NBUK];                   // fill branch
    __shared__ int lbase[NBUK];
    int t = threadIdx.x;
    int b = blockIdx.x;

    if (b < NBLK2) {
        // ---- bucket fill: count in LDS, reserve global range, dense scatter ----
        for (int i = t; i < NBUK; i += 256) lcnt[i] = 0;
        __syncthreads();
        int e0 = b * EPB;
        int ds[16], ss[16];
#pragma unroll
        for (int j = 0; j < 16; ++j) {
            int e = e0 + j * 256 + t;
            int s = -1, d = -1;
            if (e < ETOT) {
                if (e < N_EDGES) { s = ei[e]; d = ei[N_EDGES + e]; }
                else             { s = d = e - N_EDGES; }
                atomicAdd(&lcnt[d >> 8], 1);
            }
            ds[j] = d; ss[j] = s;
        }
        __syncthreads();
        for (int i = t; i < NBUK; i += 256) {
            int c = lcnt[i];
            lbase[i] = i * CAPR + (c ? atomicAdd(&gcur[i], c) : 0);
        }
        __syncthreads();
#pragma unroll
        for (int j = 0; j < 16; ++j) {
            if (ds[j] >= 0) {
                int bk = ds[j] >> 8;
                int pos = atomicAdd(&lbase[bk], 1);
                if (pos < (bk + 1) * CAPR)
                    pairs[pos] = (unsigned)ss[j] | ((unsigned)(ds[j] & 255) << 16);
            }
        }
        return;
    }
    if (b < NBLK2 + NPREPW) {
        // ---- W2T (perm rows) + BN folds ----
        int t2 = (b - NBLK2) * 256 + t;
        if (t2 < 16384) {
            int n = t2 >> 8, kp = t2 & 255;     // W2T[n*256+k'] = W2[real(k')*64+n]
            int rk = (kp & 15) * 16 + (kp >> 4);
            W2T[t2] = f2bf(W2[rk * 64 + n]);
        } else if (t2 < 16384 + 256) {
            int z = t2 - 16384;                 // hb slot z holds real (z&15)*16+(z>>4)
            int r = (z & 15) * 16 + (z >> 4);
            float A = g1[r] * rsqrtf(v1[r] + EPS_BN);
            A1s[z] = A;
            B1s[z] = (b1[r] - m1[r]) * A + be1[r];
        } else if (t2 < PREPW_T) {
            int z = t2 - 16384 - 256;           // pooled slot z holds real (z&3)*16+(z>>2)
            int r = (z & 3) * 16 + (z >> 2);
            float A = g2[r] * rsqrtf(v2[r] + EPS_BN);
            A2s[z] = A;
            B2s[z] = (b2[r] - m2[r]) * A + be2[r];
        }
        return;
    }
    // ---- gemm1: h1(fp8, perm) = x @ W1, scores es1/ed1 ----
    // stage W1 f32 -> bf16 transposed into LDS (t = output col n, coalesced reads)
    for (int k = 0; k < 64; ++k)
        W1T[t * 72 + k] = f2bf(W1[k * 256 + t]);
    __syncthreads();
    int wid = t >> 6, lane = t & 63;
    int quad = lane >> 4, col = lane & 15;
    float as_r[16], ad_r[16];
#pragma unroll
    for (int i = 0; i < 16; ++i) {
        as_r[i] = a_s[i * 16 + col];
        ad_r[i] = a_d[i * 16 + col];
    }
    int tile = (b - NBLK2 - NPREPW) * 4 + wid;
    if (tile >= 3125) return;
    int base = tile * 16;
    const float* xr = &x[(size_t)(base + col) * 64 + quad * 8];
    float4 u0 = *(const float4*)xr;
    float4 u1 = *(const float4*)(xr + 4);
    float4 u2 = *(const float4*)(xr + 32);
    float4 u3 = *(const float4*)(xr + 36);
    short8 a0, a1;
    a0[0] = (short)f2bf(u0.x); a0[1] = (short)f2bf(u0.y);
    a0[2] = (short)f2bf(u0.z); a0[3] = (short)f2bf(u0.w);
    a0[4] = (short)f2bf(u1.x); a0[5] = (short)f2bf(u1.y);
    a0[6] = (short)f2bf(u1.z); a0[7] = (short)f2bf(u1.w);
    a1[0] = (short)f2bf(u2.x); a1[1] = (short)f2bf(u2.y);
    a1[2] = (short)f2bf(u2.z); a1[3] = (short)f2bf(u2.w);
    a1[4] = (short)f2bf(u3.x); a1[5] = (short)f2bf(u3.y);
    a1[6] = (short)f2bf(u3.z); a1[7] = (short)f2bf(u3.w);
    f32x4 acc[16];
#pragma unroll
    for (int nt = 0; nt < 16; ++nt) acc[nt] = (f32x4){0.f, 0.f, 0.f, 0.f};
#pragma unroll
    for (int nt = 0; nt < 16; ++nt) {
        short8 b0 = *(const short8*)&W1T[(nt * 16 + col) * 72 + quad * 8];
        short8 b1 = *(const short8*)&W1T[(nt * 16 + col) * 72 + 32 + quad * 8];
        acc[nt] = __builtin_amdgcn_mfma_f32_16x16x32_bf16(a0, b0, acc[nt], 0, 0, 0);
        acc[nt] = __builtin_amdgcn_mfma_f32_16x16x32_bf16(a1, b1, acc[nt], 0, 0, 0);
    }
    float esp[16], edp[16];
#pragma unroll
    for (int i = 0; i < 16; ++i) { esp[i] = 0.f; edp[i] = 0.f; }
#pragma unroll
    for (int nt = 0; nt < 16; ++nt) {
        int hd = nt >> 2;
#pragma unroll
        for (int r = 0; r < 4; ++r) {
            esp[hd * 4 + r] += acc[nt][r] * as_r[nt];
            edp[hd * 4 + r] += acc[nt][r] * ad_r[nt];
        }
    }
#pragma unroll
    for (int i = 0; i < 16; ++i) {
        float v = esp[i], w = edp[i];
#pragma unroll
        for (int m = 1; m <= 8; m <<= 1) { v += __shfl_xor(v, m); w += __shfl_xor(w, m); }
        esp[i] = v; edp[i] = w;
    }
    if (col == 0) {
#pragma unroll
        for (int hd = 0; hd < 4; ++hd)
#pragma unroll
            for (int r = 0; r < 4; ++r) {
                int node = base + quad * 4 + r;
                es1[node * 4 + hd] = esp[hd * 4 + r];
                ed1[node * 4 + hd] = edp[hd * 4 + r];
            }
    }
#pragma unroll
    for (int r = 0; r < 4; ++r) {
        uint4 pk;
        pk.x = pack4_fp8(acc[0][r],  acc[1][r],  acc[2][r],  acc[3][r]);
        pk.y = pack4_fp8(acc[4][r],  acc[5][r],  acc[6][r],  acc[7][r]);
        pk.z = pack4_fp8(acc[8][r],  acc[9][r],  acc[10][r], acc[11][r]);
        pk.w = pack4_fp8(acc[12][r], acc[13][r], acc[14][r], acc[15][r]);
        *(uint4*)&h1f8[(size_t)(base + quad * 4 + r) * 256 + col * 16] = pk;
    }
}

// ---------------- per-bucket LDS sort -> coalesced csr + offs ----------------
// Each block re-derives its bucket base via a 196-wide scan of gcur (no k_bsum).

__global__ __launch_bounds__(256)
void k_csr(const unsigned* __restrict__ pairs, const int* __restrict__ gcur,
           int* __restrict__ offs, unsigned short* __restrict__ csr) {
    __shared__ unsigned sp[CAP];
    __shared__ unsigned short lc[CAP];
    __shared__ int c256[256];
    __shared__ int o256[256];
    __shared__ int s[256];
    int b = blockIdx.x, t = threadIdx.x;
    // bucket-base scan
    int v = (t < NBUK) ? gcur[t] : 0;
    s[t] = v; __syncthreads();
    for (int d2 = 1; d2 < 256; d2 <<= 1) {
        int add = (t >= d2) ? s[t - d2] : 0;
        __syncthreads();
        s[t] += add;
        __syncthreads();
    }
    int gb = gcur[b];
    int base = s[b] - gb;
    int total = s[NBUK - 1];
    if (b == NBUK - 1 && t == 0) offs[N_NODES] = total;
    __syncthreads();
    int n = min(gb, CAP);
    int node = b * 256 + t;
    const unsigned* reg = pairs + (size_t)b * CAPR;
    for (int i = t; i < n; i += 256) sp[i] = reg[i];
    c256[t] = 0;
    __syncthreads();
    for (int i = t; i < n; i += 256) atomicAdd(&c256[(sp[i] >> 16) & 255], 1);
    __syncthreads();
    int v2 = c256[t];
    s[t] = v2; __syncthreads();
    for (int d2 = 1; d2 < 256; d2 <<= 1) {
        int add = (t >= d2) ? s[t - d2] : 0;
        __syncthreads();
        s[t] += add;
        __syncthreads();
    }
    int myoff = s[t] - v2;
    o256[t] = myoff;
    if (node < N_NODES) offs[node] = base + myoff;
    __syncthreads();
    for (int i = t; i < n; i += 256) {
        unsigned p = sp[i];
        int pos = atomicAdd(&o256[(p >> 16) & 255], 1);
        lc[pos] = (unsigned short)(p & 0xffff);
    }
    __syncthreads();
    for (int i = t; i < n; i += 256) csr[base + i] = lc[i];
}

// ---------------- fused GAT1 + GEMM2 ----------------
// Phase 1 (gat1): 16-lane group per dst node, chunk=4 edges; hb -> LDS (bf16 slots).
// Phase 2 (gemm2): wave w computes output cols w*16..+15 from LDS hbt + L2 W2Tg.

__global__ __launch_bounds__(256)
void k_gat1g2(const unsigned char* __restrict__ h1f8, const float* __restrict__ es1,
              const float* __restrict__ ed1, const int* __restrict__ offs,
              const unsigned short* __restrict__ csr,
              const float* __restrict__ A1s, const float* __restrict__ B1s,
              const unsigned short* __restrict__ W2Tg,
              const float* __restrict__ a_s2, const float* __restrict__ a_d2,
              unsigned char* __restrict__ h2f8, float* __restrict__ es2,
              float* __restrict__ ed2) {
    __shared__ unsigned short hbt[16][264];
    __shared__ float esps[4][16], edps[4][16];
    __shared__ uint4 h2t4[64];                  // 16 nodes x 64 B
    unsigned char* h2t = (unsigned char*)h2t4;
    int tid = threadIdx.x;
    int l = tid & 63;
    int gbase = l & 48;
    int q = tid & 15;
    int dl = tid >> 4;
    int nbase = blockIdx.x * 16;
    int d = nbase + dl;
    int start = offs[d], deg = offs[d + 1] - start;
    int e4 = q >> 2, hd = q & 3;
    float edv = ed1[d * 4 + hd];
    const unsigned char* hrow = h1f8 + q * 16;
    float a[16];
#pragma unroll
    for (int i = 0; i < 16; ++i) a[i] = 0.f;
    float wsum = 0.f;
    for (int c0 = 0; c0 < deg; c0 += 4) {
        int idx = c0 + e4;
        int s = csr[start + min(idx, deg - 1)];
        float w = (idx < deg) ? __expf(leaky(es1[s * 4 + hd] + edv)) : 0.f;
        wsum += w;
        int se[4];
#pragma unroll
        for (int e = 0; e < 4; ++e) se[e] = __shfl(s, gbase | (e << 2));
        uint4 rv[4];
#pragma unroll
        for (int e = 0; e < 4; ++e)
            rv[e] = *(const uint4*)(hrow + ((size_t)(unsigned)se[e] << 8));
#pragma unroll
        for (int e = 0; e < 4; ++e) {
            float w0 = __shfl(w, gbase | (e << 2) | 0);
            float w1 = __shfl(w, gbase | (e << 2) | 1);
            float w2 = __shfl(w, gbase | (e << 2) | 2);
            float w3 = __shfl(w, gbase | (e << 2) | 3);
            f32x2 p;
            p = __builtin_amdgcn_cvt_pk_f32_fp8((int)rv[e].x, false); a[0]  += w0 * p.x; a[1]  += w0 * p.y;
            p = __builtin_amdgcn_cvt_pk_f32_fp8((int)rv[e].x, true);  a[2]  += w0 * p.x; a[3]  += w0 * p.y;
            p = __builtin_amdgcn_cvt_pk_f32_fp8((int)rv[e].y, false); a[4]  += w1 * p.x; a[5]  += w1 * p.y;
            p = __builtin_amdgcn_cvt_pk_f32_fp8((int)rv[e].y, true);  a[6]  += w1 * p.x; a[7]  += w1 * p.y;
            p = __builtin_amdgcn_cvt_pk_f32_fp8((int)rv[e].z, false); a[8]  += w2 * p.x; a[9]  += w2 * p.y;
            p = __builtin_amdgcn_cvt_pk_f32_fp8((int)rv[e].z, true);  a[10] += w2 * p.x; a[11] += w2 * p.y;
            p = __builtin_amdgcn_cvt_pk_f32_fp8((int)rv[e].w, false); a[12] += w3 * p.x; a[13] += w3 * p.y;
            p = __builtin_amdgcn_cvt_pk_f32_fp8((int)rv[e].w, true);  a[14] += w3 * p.x; a[15] += w3 * p.y;
        }
    }
    wsum += __shfl_xor(wsum, 4);
    wsum += __shfl_xor(wsum, 8);
    float inv[4];
#pragma unroll
    for (int h = 0; h < 4; ++h) inv[h] = 1.f / __shfl(wsum, gbase | h);
#pragma unroll
    for (int i0 = 0; i0 < 4; ++i0) {
        float4 Av = *(const float4*)&A1s[q * 16 + i0 * 4];
        float4 Bv = *(const float4*)&B1s[q * 16 + i0 * 4];
        float o0 = a[i0 * 4 + 0] * inv[i0] * Av.x + Bv.x;
        float o1 = a[i0 * 4 + 1] * inv[i0] * Av.y + Bv.y;
        float o2 = a[i0 * 4 + 2] * inv[i0] * Av.z + Bv.z;
        float o3 = a[i0 * 4 + 3] * inv[i0] * Av.w + Bv.w;
        o0 = (o0 > 0.f) ? o0 : expm1f(o0);
        o1 = (o1 > 0.f) ? o1 : expm1f(o1);
        o2 = (o2 > 0.f) ? o2 : expm1f(o2);
        o3 = (o3 > 0.f) ? o3 : expm1f(o3);
        ushort4 ov;
        ov.x = f2bf(o0); ov.y = f2bf(o1); ov.z = f2bf(o2); ov.w = f2bf(o3);
        *(ushort4*)&hbt[dl][q * 16 + i0 * 4] = ov;
    }
    __syncthreads();
    // ---- phase 2: gemm2 for this 16-node tile ----
    int w = tid >> 6;
    int quad = l >> 4, col = l & 15;
    short8 af[8];
#pragma unroll
    for (int kk = 0; kk < 8; ++kk)
        af[kk] = *(const short8*)&hbt[col][kk * 32 + quad * 8];
    f32x4 acc = (f32x4){0.f, 0.f, 0.f, 0.f};
#pragma unroll
    for (int kk = 0; kk < 8; ++kk) {
        short8 b = *(const short8*)&W2Tg[(w * 16 + col) * 256 + kk * 32 + quad * 8];
        acc = __builtin_amdgcn_mfma_f32_16x16x32_bf16(af[kk], b, acc, 0, 0, 0);
    }
    float asw = a_s2[w * 16 + col], adw = a_d2[w * 16 + col];
    float esp[4], edp[4];
#pragma unroll
    for (int r = 0; r < 4; ++r) { esp[r] = acc[r] * asw; edp[r] = acc[r] * adw; }
#pragma unroll
    for (int r = 0; r < 4; ++r) {
#pragma unroll
        for (int m = 1; m <= 8; m <<= 1) {
            esp[r] += __shfl_xor(esp[r], m);
            edp[r] += __shfl_xor(edp[r], m);
        }
    }
    if (col == 0) {
#pragma unroll
        for (int r = 0; r < 4; ++r) {
            esps[w][quad * 4 + r] = esp[r];
            edps[w][quad * 4 + r] = edp[r];
        }
    }
#pragma unroll
    for (int r = 0; r < 4; ++r) {
        unsigned pk = pack4_fp8(acc[r], acc[r], acc[r], acc[r]);
        h2t[(quad * 4 + r) * 64 + col * 4 + w] = (unsigned char)(pk & 0xff);
    }
    __syncthreads();
    if (tid < 16) {
        es2[nbase + tid] = esps[0][tid] + esps[1][tid] + esps[2][tid] + esps[3][tid];
        ed2[nbase + tid] = edps[0][tid] + edps[1][tid] + edps[2][tid] + edps[3][tid];
    }
    if (tid < 64) {
        int node = tid >> 2, c = tid & 3;
        *(uint4*)&h2f8[(size_t)(nbase + node) * 64 + c * 16] = h2t4[node * 4 + c];
    }
}

// ---------------- fused GAT2 + mean-pool (chunk=8 edges in flight) ----------

__global__ __launch_bounds__(256)
void k_gat2p(const unsigned char* __restrict__ h2f8, const float* __restrict__ es2,
             const float* __restrict__ ed2, const int* __restrict__ offs,
             const unsigned short* __restrict__ csr,
             const float* __restrict__ A2s, const float* __restrict__ B2s,
             const int* __restrict__ batch, float* __restrict__ pooled) {
    __shared__ float ot[16][68];
    __shared__ int gbat[16];
    int tid = threadIdx.x;
    int l = tid & 63;
    int gbase = l & 48;
    int q = tid & 15;
    int dl = tid >> 4;
    int nbase = blockIdx.x * 16;
    int d = nbase + dl;
    int start = offs[d], deg = offs[d + 1] - start;
    float edv = ed2[d];
    const unsigned char* hrow = h2f8 + q * 4;
    float a0 = 0.f, a1 = 0.f, a2 = 0.f, a3 = 0.f, wsum = 0.f;
    int e8 = q & 7;
    for (int c0 = 0; c0 < deg; c0 += 8) {
        int idx = c0 + e8;
        int s = csr[start + min(idx, deg - 1)];
        float w = (idx < deg) ? __expf(leaky(es2[s] + edv)) : 0.f;
        wsum += w;
        int se[8];
#pragma unroll
        for (int e = 0; e < 8; ++e) se[e] = __shfl(s, gbase | e);
        unsigned rv[8];
#pragma unroll
        for (int e = 0; e < 8; ++e)
            rv[e] = *(const unsigned*)(hrow + ((size_t)(unsigned)se[e] << 6));
#pragma unroll
        for (int e = 0; e < 8; ++e) {
            float we = __shfl(w, gbase | e);
            f32x2 p;
            p = __builtin_amdgcn_cvt_pk_f32_fp8((int)rv[e], false); a0 += we * p.x; a1 += we * p.y;
            p = __builtin_amdgcn_cvt_pk_f32_fp8((int)rv[e], true);  a2 += we * p.x; a3 += we * p.y;
        }
    }
    wsum += __shfl_xor(wsum, 1);
    wsum += __shfl_xor(wsum, 2);
    wsum += __shfl_xor(wsum, 4);        // sum over 8-group; both halves complete
    float inv = 1.f / wsum;
    float4 Av = *(const float4*)&A2s[q * 4];
    float4 Bv = *(const float4*)&B2s[q * 4];
    ot[dl][q * 4 + 0] = a0 * inv * Av.x + Bv.x;
    ot[dl][q * 4 + 1] = a1 * inv * Av.y + Bv.y;
    ot[dl][q * 4 + 2] = a2 * inv * Av.z + Bv.z;
    ot[dl][q * 4 + 3] = a3 * inv * Av.w + Bv.w;
    if (tid < 16) gbat[tid] = batch[nbase + tid];
    __syncthreads();
    if (tid < 64) {
        int ch = tid;
        int curg = gbat[0];
        float acc = 0.f;
#pragma unroll
        for (int n = 0; n < 16; ++n) {
            int g = gbat[n];
            if (g != curg) {
                atomicAdd(&pooled[curg * 64 + ch], acc);
                acc = 0.f;
                curg = g;
            }
            acc += ot[n][ch];
        }
        atomicAdd(&pooled[curg * 64 + ch], acc);
    }
}

// ---------------- MLP head + log_softmax (divide + slot->real mapping) -------

__device__ int lower_bound_i(const int* a, int n, int key) {
    int lo = 0, hi = n;
    while (lo < hi) {
        int mid = (lo + hi) >> 1;
        if (a[mid] < key) lo = mid + 1; else hi = mid;
    }
    return lo;
}

__global__ void k_head(const float* __restrict__ pooled, const int* __restrict__ batch,
                       const float* __restrict__ lw1, const float* __restrict__ lb1,
                       const float* __restrict__ lw2, const float* __restrict__ lb2,
                       float* __restrict__ out) {
    int g = threadIdx.x;
    if (g >= GGRAPHS) return;
    int s0 = lower_bound_i(batch, N_NODES, g);
    int s1 = lower_bound_i(batch, N_NODES, g + 1);
    int cnt = s1 - s0;
    float invc = 1.f / (float)((cnt > 0) ? cnt : 1);
    float p[64];
#pragma unroll
    for (int c = 0; c < 64; ++c) p[c] = pooled[g * 64 + c] * invc;
    float z0 = lb2[0], z1 = lb2[1], z2 = lb2[2];
    for (int j = 0; j < 32; ++j) {
        float hj = lb1[j];
#pragma unroll
        for (int c = 0; c < 64; ++c) {
            int rc = (c & 3) * 16 + (c >> 2);    // slot c holds real channel rc
            hj += p[c] * lw1[rc * 32 + j];
        }
        hj = fmaxf(hj, 0.f);
        z0 += hj * lw2[j * 3 + 0];
        z1 += hj * lw2[j * 3 + 1];
        z2 += hj * lw2[j * 3 + 2];
    }
    float m = fmaxf(z0, fmaxf(z1, z2));
    float lse = logf(expf(z0 - m) + expf(z1 - m) + expf(z2 - m)) + m;
    out[g * 3 + 0] = z0 - lse;
    out[g * 3 + 1] = z1 - lse;
    out[g * 3 + 2] = z2 - lse;
}

// ---------------- launch ----------------

extern "C" void kernel_launch(void* const* d_in, const int* in_sizes, int n_in,
                              void* d_out, int out_size, void* d_ws, size_t ws_size,
                              hipStream_t stream) {
    (void)in_sizes; (void)n_in; (void)out_size; (void)ws_size;
    const float* x    = (const float*)d_in[0];
    const int*   ei   = (const int*)d_in[1];
    const int*   batch= (const int*)d_in[2];
    const float* W1   = (const float*)d_in[3];
    const float* a_s1 = (const float*)d_in[4];
    const float* a_d1 = (const float*)d_in[5];
    const float* b1   = (const float*)d_in[6];
    const float* g1   = (const float*)d_in[7];
    const float* be1  = (const float*)d_in[8];
    const float* m1   = (const float*)d_in[9];
    const float* v1   = (const float*)d_in[10];
    const float* W2   = (const float*)d_in[11];
    const float* a_s2 = (const float*)d_in[12];
    const float* a_d2 = (const float*)d_in[13];
    const float* b2   = (const float*)d_in[14];
    const float* g2   = (const float*)d_in[15];
    const float* be2  = (const float*)d_in[16];
    const float* m2   = (const float*)d_in[17];
    const float* v2   = (const float*)d_in[18];
    const float* lw1  = (const float*)d_in[19];
    const float* lb1  = (const float*)d_in[20];
    const float* lw2  = (const float*)d_in[21];
    const float* lb2  = (const float*)d_in[22];
    float* out = (float*)d_out;

    char* ws = (char*)d_ws;
    size_t off = 0;
    auto alloc = [&](size_t bytes) -> void* {
        void* p = ws + off;
        off += (bytes + 255) & ~(size_t)255;
        return p;
    };
    // pooled + gcur adjacent: one memset covers both
    float* pooled = (float*)alloc((size_t)GGRAPHS * 64 * 4);     // 16384 B
    int*   gcur   = (int*)alloc((size_t)NBUK * 4);               // -> 1024 B slot
    unsigned short* W2T = (unsigned short*)alloc((size_t)16384 * 2);
    unsigned char*  h1  = (unsigned char*)alloc((size_t)N_NODES * 256);   // fp8 perm
    unsigned char*  h2  = (unsigned char*)alloc((size_t)N_NODES * 64);    // fp8 perm
    float* es1  = (float*)alloc((size_t)N_NODES * 4 * 4);
    float* ed1  = (float*)alloc((size_t)N_NODES * 4 * 4);
    float* es2  = (float*)alloc((size_t)N_NODES * 4);
    float* ed2  = (float*)alloc((size_t)N_NODES * 4);
    float* A1s  = (float*)alloc(256 * 4);
    float* B1s  = (float*)alloc(256 * 4);
    float* A2s  = (float*)alloc(64 * 4);
    float* B2s  = (float*)alloc(64 * 4);
    int*   offs = (int*)alloc((size_t)(N_NODES + 1) * 4);
    unsigned short* csr = (unsigned short*)alloc((size_t)ETOT * 2);
    unsigned* pairs = (unsigned*)alloc((size_t)NBUK * CAPR * 4);

    const int ngat = 3125;                     // 16 nodes per block

    hipMemsetAsync(pooled, 0, 16384 + 1024, stream);   // pooled + gcur
    k_mega<<<NMEGA, 256, 0, stream>>>(x, ei, W1, W2,
                                      b1, g1, be1, m1, v1,
                                      b2, g2, be2, m2, v2,
                                      a_s1, a_d1,
                                      W2T, A1s, B1s, A2s, B2s,
                                      gcur, pairs, h1, es1, ed1);
    k_csr<<<NBUK, 256, 0, stream>>>(pairs, gcur, offs, csr);
    k_gat1g2<<<ngat, 256, 0, stream>>>(h1, es1, ed1, offs, csr, A1s, B1s,
                                       W2T, a_s2, a_d2, h2, es2, ed2);
    k_gat2p<<<ngat, 256, 0, stream>>>(h2, es2, ed2, offs, csr, A2s, B2s,
                                      batch, pooled);
    k_head<<<1, 64, 0, stream>>>(pooled, batch, lw1, lb1, lw2, lb2, out);
}

// Round 14
// 226.114 us; speedup vs baseline: 1.7519x; 1.0013x over previous
//
#include <hip/hip_runtime.h>
#include <math.h>

#define N_NODES 50000
#define N_EDGES 800000
#define ETOT    (N_EDGES + N_NODES)   // self-loops appended
#define GGRAPHS 64
#define EPS_BN  1e-5f

typedef __attribute__((ext_vector_type(8))) short short8;
typedef __attribute__((ext_vector_type(4))) float f32x4;
typedef __attribute__((ext_vector_type(2))) float f32x2;

__device__ __forceinline__ unsigned short f2bf(float f) {
    union { float f; unsigned u; } v; v.f = f;
    unsigned r = v.u + 0x7fffu + ((v.u >> 16) & 1u);   // round-nearest-even
    return (unsigned short)(r >> 16);
}
__device__ __forceinline__ float leaky(float e) {
    return fmaxf(e, 0.2f * e);
}
// pack 4 f32 -> 4 fp8 (e4m3, OCP on gfx950)
__device__ __forceinline__ unsigned pack4_fp8(float a, float b, float c, float d) {
    int v = __builtin_amdgcn_cvt_pk_fp8_f32(a, b, 0, false);
    v = __builtin_amdgcn_cvt_pk_fp8_f32(c, d, v, true);
    return (unsigned)v;
}

// bucket-sort CSR build params
#define NBUK 196                       // dst >> 8
#define EPB  4096                      // edges per fill block
#define NBLK2 ((ETOT + EPB - 1) / EPB) // 208
#define CAPR 6144                      // fixed pairs region per bucket (mean 4352, +28 sigma)
#define CAP  6144

// mega-kernel block ranges
#define PREPW_T (16384 + 320)
#define NPREPW ((PREPW_T + 255) / 256) // 66
#define NT1B 782                       // gemm1 tile blocks (4 tiles each, 3125 tiles)
#define NMEGA (NBLK2 + NPREPW + NT1B)  // 1056

// ---------------- MEGA: bucket fill | W2T+BN prep | gemm1 ----------------

__global__ __launch_bounds__(256)
void k_mega(const float* __restrict__ x, const int* __restrict__ ei,
            const float* __restrict__ W1, const float* __restrict__ W2,
            const float* __restrict__ b1, const float* __restrict__ g1,
            const float* __restrict__ be1, const float* __restrict__ m1,
            const float* __restrict__ v1,
            const float* __restrict__ b2, const float* __restrict__ g2,
            const float* __restrict__ be2, const float* __restrict__ m2,
            const float* __restrict__ v2,
            const float* __restrict__ a_s, const float* __restrict__ a_d,
            unsigned short* __restrict__ W2T,
            float* __restrict__ A1s, float* __restrict__ B1s,
            float* __restrict__ A2s, float* __restrict__ B2s,
            int* __restrict__ gcur, unsigned* __restrict__ pairs,
            unsigned char* __restrict__ h1f8,
            float* __restrict__ es1, float* __restrict__ ed1) {
    __shared__ unsigned short W1T[256 * 72];     // gemm1 branch (36.9 KB)
    __shared__ int lcnt[NBUK];                   // fill branch
    __shared__ int lbase[NBUK];
    int t = threadIdx.x;
    int b = blockIdx.x;

    if (b < NBLK2) {
        // ---- bucket fill: count in LDS, reserve global range, dense scatter ----
        for (int i = t; i < NBUK; i += 256) lcnt[i] = 0;
        __syncthreads();
        int e0 = b * EPB;
        int ds[16], ss[16];
#pragma unroll
        for (int j = 0; j < 16; ++j) {
            int e = e0 + j * 256 + t;
            int s = -1, d = -1;
            if (e < ETOT) {
                if (e < N_EDGES) { s = ei[e]; d = ei[N_EDGES + e]; }
                else             { s = d = e - N_EDGES; }
                atomicAdd(&lcnt[d >> 8], 1);
            }
            ds[j] = d; ss[j] = s;
        }
        __syncthreads();
        for (int i = t; i < NBUK; i += 256) {
            int c = lcnt[i];
            lbase[i] = i * CAPR + (c ? atomicAdd(&gcur[i], c) : 0);
        }
        __syncthreads();
#pragma unroll
        for (int j = 0; j < 16; ++j) {
            if (ds[j] >= 0) {
                int bk = ds[j] >> 8;
                int pos = atomicAdd(&lbase[bk], 1);
                if (pos < (bk + 1) * CAPR)
                    pairs[pos] = (unsigned)ss[j] | ((unsigned)(ds[j] & 255) << 16);
            }
        }
        return;
    }
    if (b < NBLK2 + NPREPW) {
        // ---- W2T (perm rows) + BN folds ----
        int t2 = (b - NBLK2) * 256 + t;
        if (t2 < 16384) {
            int n = t2 >> 8, kp = t2 & 255;     // W2T[n*256+k'] = W2[real(k')*64+n]
            int rk = (kp & 15) * 16 + (kp >> 4);
            W2T[t2] = f2bf(W2[rk * 64 + n]);
        } else if (t2 < 16384 + 256) {
            int z = t2 - 16384;                 // hb slot z holds real (z&15)*16+(z>>4)
            int r = (z & 15) * 16 + (z >> 4);
            float A = g1[r] * rsqrtf(v1[r] + EPS_BN);
            A1s[z] = A;
            B1s[z] = (b1[r] - m1[r]) * A + be1[r];
        } else if (t2 < PREPW_T) {
            int z = t2 - 16384 - 256;           // pooled slot z holds real (z&3)*16+(z>>2)
            int r = (z & 3) * 16 + (z >> 2);
            float A = g2[r] * rsqrtf(v2[r] + EPS_BN);
            A2s[z] = A;
            B2s[z] = (b2[r] - m2[r]) * A + be2[r];
        }
        return;
    }
    // ---- gemm1: h1(fp8, perm) = x @ W1, scores es1/ed1 ----
    for (int k = 0; k < 64; ++k)
        W1T[t * 72 + k] = f2bf(W1[k * 256 + t]);
    __syncthreads();
    int wid = t >> 6, lane = t & 63;
    int quad = lane >> 4, col = lane & 15;
    float as_r[16], ad_r[16];
#pragma unroll
    for (int i = 0; i < 16; ++i) {
        as_r[i] = a_s[i * 16 + col];
        ad_r[i] = a_d[i * 16 + col];
    }
    int tile = (b - NBLK2 - NPREPW) * 4 + wid;
    if (tile >= 3125) return;
    int base = tile * 16;
    const float* xr = &x[(size_t)(base + col) * 64 + quad * 8];
    float4 u0 = *(const float4*)xr;
    float4 u1 = *(const float4*)(xr + 4);
    float4 u2 = *(const float4*)(xr + 32);
    float4 u3 = *(const float4*)(xr + 36);
    short8 a0, a1;
    a0[0] = (short)f2bf(u0.x); a0[1] = (short)f2bf(u0.y);
    a0[2] = (short)f2bf(u0.z); a0[3] = (short)f2bf(u0.w);
    a0[4] = (short)f2bf(u1.x); a0[5] = (short)f2bf(u1.y);
    a0[6] = (short)f2bf(u1.z); a0[7] = (short)f2bf(u1.w);
    a1[0] = (short)f2bf(u2.x); a1[1] = (short)f2bf(u2.y);
    a1[2] = (short)f2bf(u2.z); a1[3] = (short)f2bf(u2.w);
    a1[4] = (short)f2bf(u3.x); a1[5] = (short)f2bf(u3.y);
    a1[6] = (short)f2bf(u3.z); a1[7] = (short)f2bf(u3.w);
    f32x4 acc[16];
#pragma unroll
    for (int nt = 0; nt < 16; ++nt) acc[nt] = (f32x4){0.f, 0.f, 0.f, 0.f};
#pragma unroll
    for (int nt = 0; nt < 16; ++nt) {
        short8 b0 = *(const short8*)&W1T[(nt * 16 + col) * 72 + quad * 8];
        short8 b1 = *(const short8*)&W1T[(nt * 16 + col) * 72 + 32 + quad * 8];
        acc[nt] = __builtin_amdgcn_mfma_f32_16x16x32_bf16(a0, b0, acc[nt], 0, 0, 0);
        acc[nt] = __builtin_amdgcn_mfma_f32_16x16x32_bf16(a1, b1, acc[nt], 0, 0, 0);
    }
    float esp[16], edp[16];
#pragma unroll
    for (int i = 0; i < 16; ++i) { esp[i] = 0.f; edp[i] = 0.f; }
#pragma unroll
    for (int nt = 0; nt < 16; ++nt) {
        int hd = nt >> 2;
#pragma unroll
        for (int r = 0; r < 4; ++r) {
            esp[hd * 4 + r] += acc[nt][r] * as_r[nt];
            edp[hd * 4 + r] += acc[nt][r] * ad_r[nt];
        }
    }
#pragma unroll
    for (int i = 0; i < 16; ++i) {
        float v = esp[i], w = edp[i];
#pragma unroll
        for (int m = 1; m <= 8; m <<= 1) { v += __shfl_xor(v, m); w += __shfl_xor(w, m); }
        esp[i] = v; edp[i] = w;
    }
    if (col == 0) {
#pragma unroll
        for (int hd = 0; hd < 4; ++hd)
#pragma unroll
            for (int r = 0; r < 4; ++r) {
                int node = base + quad * 4 + r;
                es1[node * 4 + hd] = esp[hd * 4 + r];
                ed1[node * 4 + hd] = edp[hd * 4 + r];
            }
    }
#pragma unroll
    for (int r = 0; r < 4; ++r) {
        uint4 pk;
        pk.x = pack4_fp8(acc[0][r],  acc[1][r],  acc[2][r],  acc[3][r]);
        pk.y = pack4_fp8(acc[4][r],  acc[5][r],  acc[6][r],  acc[7][r]);
        pk.z = pack4_fp8(acc[8][r],  acc[9][r],  acc[10][r], acc[11][r]);
        pk.w = pack4_fp8(acc[12][r], acc[13][r], acc[14][r], acc[15][r]);
        *(uint4*)&h1f8[(size_t)(base + quad * 4 + r) * 256 + col * 16] = pk;
    }
}

// ---------------- per-bucket LDS sort -> coalesced csr + offs ----------------

__global__ __launch_bounds__(256)
void k_csr(const unsigned* __restrict__ pairs, const int* __restrict__ gcur,
           int* __restrict__ offs, unsigned short* __restrict__ csr) {
    __shared__ unsigned sp[CAP];
    __shared__ unsigned short lc[CAP];
    __shared__ int c256[256];
    __shared__ int o256[256];
    __shared__ int s[256];
    int b = blockIdx.x, t = threadIdx.x;
    int v = (t < NBUK) ? gcur[t] : 0;
    s[t] = v; __syncthreads();
    for (int d2 = 1; d2 < 256; d2 <<= 1) {
        int add = (t >= d2) ? s[t - d2] : 0;
        __syncthreads();
        s[t] += add;
        __syncthreads();
    }
    int gb = gcur[b];
    int base = s[b] - gb;
    int total = s[NBUK - 1];
    if (b == NBUK - 1 && t == 0) offs[N_NODES] = total;
    __syncthreads();
    int n = min(gb, CAP);
    int node = b * 256 + t;
    const unsigned* reg = pairs + (size_t)b * CAPR;
    for (int i = t; i < n; i += 256) sp[i] = reg[i];
    c256[t] = 0;
    __syncthreads();
    for (int i = t; i < n; i += 256) atomicAdd(&c256[(sp[i] >> 16) & 255], 1);
    __syncthreads();
    int v2 = c256[t];
    s[t] = v2; __syncthreads();
    for (int d2 = 1; d2 < 256; d2 <<= 1) {
        int add = (t >= d2) ? s[t - d2] : 0;
        __syncthreads();
        s[t] += add;
        __syncthreads();
    }
    int myoff = s[t] - v2;
    o256[t] = myoff;
    if (node < N_NODES) offs[node] = base + myoff;
    __syncthreads();
    for (int i = t; i < n; i += 256) {
        unsigned p = sp[i];
        int pos = atomicAdd(&o256[(p >> 16) & 255], 1);
        lc[pos] = (unsigned short)(p & 0xffff);
    }
    __syncthreads();
    for (int i = t; i < n; i += 256) csr[base + i] = lc[i];
}

// ---------------- fused GAT1 + GEMM2 (phase 1 pipelined 2x: 8 edges/iter) ----

__global__ __launch_bounds__(256)
void k_gat1g2(const unsigned char* __restrict__ h1f8, const float* __restrict__ es1,
              const float* __restrict__ ed1, const int* __restrict__ offs,
              const unsigned short* __restrict__ csr,
              const float* __restrict__ A1s, const float* __restrict__ B1s,
              const unsigned short* __restrict__ W2Tg,
              const float* __restrict__ a_s2, const float* __restrict__ a_d2,
              unsigned char* __restrict__ h2f8, float* __restrict__ es2,
              float* __restrict__ ed2) {
    __shared__ unsigned short hbt[16][264];
    __shared__ float esps[4][16], edps[4][16];
    __shared__ uint4 h2t4[64];                  // 16 nodes x 64 B
    unsigned char* h2t = (unsigned char*)h2t4;
    int tid = threadIdx.x;
    int l = tid & 63;
    int gbase = l & 48;
    int q = tid & 15;
    int dl = tid >> 4;
    int nbase = blockIdx.x * 16;
    int d = nbase + dl;
    int start = offs[d], deg = offs[d + 1] - start;
    int e4 = q >> 2, hd = q & 3;
    float edv = ed1[d * 4 + hd];
    const unsigned char* hrow = h1f8 + q * 16;
    float a[16];
#pragma unroll
    for (int i = 0; i < 16; ++i) a[i] = 0.f;
    float wsum = 0.f;
    for (int c0 = 0; c0 < deg; c0 += 8) {
        int idx0 = c0 + e4;
        int idx1 = c0 + 4 + e4;
        int s0 = csr[start + min(idx0, deg - 1)];
        int s1 = csr[start + min(idx1, deg - 1)];
        float w0l = (idx0 < deg) ? __expf(leaky(es1[s0 * 4 + hd] + edv)) : 0.f;
        float w1l = (idx1 < deg) ? __expf(leaky(es1[s1 * 4 + hd] + edv)) : 0.f;
        wsum += w0l + w1l;
        int se[8];
#pragma unroll
        for (int e = 0; e < 4; ++e) se[e] = __shfl(s0, gbase | (e << 2));
#pragma unroll
        for (int e = 4; e < 8; ++e) se[e] = __shfl(s1, gbase | ((e - 4) << 2));
        uint4 rv[8];
#pragma unroll
        for (int e = 0; e < 8; ++e)
            rv[e] = *(const uint4*)(hrow + ((size_t)(unsigned)se[e] << 8));
#pragma unroll
        for (int e = 0; e < 8; ++e) {
            int lsrc = gbase | ((e & 3) << 2);
            float wl = (e < 4) ? w0l : w1l;
            float w0 = __shfl(wl, lsrc | 0);
            float w1 = __shfl(wl, lsrc | 1);
            float w2 = __shfl(wl, lsrc | 2);
            float w3 = __shfl(wl, lsrc | 3);
            f32x2 p;
            p = __builtin_amdgcn_cvt_pk_f32_fp8((int)rv[e].x, false); a[0]  += w0 * p.x; a[1]  += w0 * p.y;
            p = __builtin_amdgcn_cvt_pk_f32_fp8((int)rv[e].x, true);  a[2]  += w0 * p.x; a[3]  += w0 * p.y;
            p = __builtin_amdgcn_cvt_pk_f32_fp8((int)rv[e].y, false); a[4]  += w1 * p.x; a[5]  += w1 * p.y;
            p = __builtin_amdgcn_cvt_pk_f32_fp8((int)rv[e].y, true);  a[6]  += w1 * p.x; a[7]  += w1 * p.y;
            p = __builtin_amdgcn_cvt_pk_f32_fp8((int)rv[e].z, false); a[8]  += w2 * p.x; a[9]  += w2 * p.y;
            p = __builtin_amdgcn_cvt_pk_f32_fp8((int)rv[e].z, true);  a[10] += w2 * p.x; a[11] += w2 * p.y;
            p = __builtin_amdgcn_cvt_pk_f32_fp8((int)rv[e].w, false); a[12] += w3 * p.x; a[13] += w3 * p.y;
            p = __builtin_amdgcn_cvt_pk_f32_fp8((int)rv[e].w, true);  a[14] += w3 * p.x; a[15] += w3 * p.y;
        }
    }
    wsum += __shfl_xor(wsum, 4);
    wsum += __shfl_xor(wsum, 8);
    float inv[4];
#pragma unroll
    for (int h = 0; h < 4; ++h) inv[h] = 1.f / __shfl(wsum, gbase | h);
#pragma unroll
    for (int i0 = 0; i0 < 4; ++i0) {
        float4 Av = *(const float4*)&A1s[q * 16 + i0 * 4];
        float4 Bv = *(const float4*)&B1s[q * 16 + i0 * 4];
        float o0 = a[i0 * 4 + 0] * inv[i0] * Av.x + Bv.x;
        float o1 = a[i0 * 4 + 1] * inv[i0] * Av.y + Bv.y;
        float o2 = a[i0 * 4 + 2] * inv[i0] * Av.z + Bv.z;
        float o3 = a[i0 * 4 + 3] * inv[i0] * Av.w + Bv.w;
        o0 = (o0 > 0.f) ? o0 : expm1f(o0);
        o1 = (o1 > 0.f) ? o1 : expm1f(o1);
        o2 = (o2 > 0.f) ? o2 : expm1f(o2);
        o3 = (o3 > 0.f) ? o3 : expm1f(o3);
        ushort4 ov;
        ov.x = f2bf(o0); ov.y = f2bf(o1); ov.z = f2bf(o2); ov.w = f2bf(o3);
        *(ushort4*)&hbt[dl][q * 16 + i0 * 4] = ov;
    }
    __syncthreads();
    // ---- phase 2: gemm2 for this 16-node tile ----
    int w = tid >> 6;
    int quad = l >> 4, col = l & 15;
    short8 af[8];
#pragma unroll
    for (int kk = 0; kk < 8; ++kk)
        af[kk] = *(const short8*)&hbt[col][kk * 32 + quad * 8];
    f32x4 acc = (f32x4){0.f, 0.f, 0.f, 0.f};
#pragma unroll
    for (int kk = 0; kk < 8; ++kk) {
        short8 b = *(const short8*)&W2Tg[(w * 16 + col) * 256 + kk * 32 + quad * 8];
        acc = __builtin_amdgcn_mfma_f32_16x16x32_bf16(af[kk], b, acc, 0, 0, 0);
    }
    float asw = a_s2[w * 16 + col], adw = a_d2[w * 16 + col];
    float esp[4], edp[4];
#pragma unroll
    for (int r = 0; r < 4; ++r) { esp[r] = acc[r] * asw; edp[r] = acc[r] * adw; }
#pragma unroll
    for (int r = 0; r < 4; ++r) {
#pragma unroll
        for (int m = 1; m <= 8; m <<= 1) {
            esp[r] += __shfl_xor(esp[r], m);
            edp[r] += __shfl_xor(edp[r], m);
        }
    }
    if (col == 0) {
#pragma unroll
        for (int r = 0; r < 4; ++r) {
            esps[w][quad * 4 + r] = esp[r];
            edps[w][quad * 4 + r] = edp[r];
        }
    }
#pragma unroll
    for (int r = 0; r < 4; ++r) {
        unsigned pk = pack4_fp8(acc[r], acc[r], acc[r], acc[r]);
        h2t[(quad * 4 + r) * 64 + col * 4 + w] = (unsigned char)(pk & 0xff);
    }
    __syncthreads();
    if (tid < 16) {
        es2[nbase + tid] = esps[0][tid] + esps[1][tid] + esps[2][tid] + esps[3][tid];
        ed2[nbase + tid] = edps[0][tid] + edps[1][tid] + edps[2][tid] + edps[3][tid];
    }
    if (tid < 64) {
        int node = tid >> 2, c = tid & 3;
        *(uint4*)&h2f8[(size_t)(nbase + node) * 64 + c * 16] = h2t4[node * 4 + c];
    }
}

// ---------------- fused GAT2 + mean-pool (pipelined 2x: 16 edges/iter) ------

__global__ __launch_bounds__(256)
void k_gat2p(const unsigned char* __restrict__ h2f8, const float* __restrict__ es2,
             const float* __restrict__ ed2, const int* __restrict__ offs,
             const unsigned short* __restrict__ csr,
             const float* __restrict__ A2s, const float* __restrict__ B2s,
             const int* __restrict__ batch, float* __restrict__ pooled) {
    __shared__ float ot[16][68];
    __shared__ int gbat[16];
    int tid = threadIdx.x;
    int l = tid & 63;
    int gbase = l & 48;
    int q = tid & 15;
    int dl = tid >> 4;
    int nbase = blockIdx.x * 16;
    int d = nbase + dl;
    int start = offs[d], deg = offs[d + 1] - start;
    float edv = ed2[d];
    const unsigned char* hrow = h2f8 + q * 4;
    float a0 = 0.f, a1 = 0.f, a2 = 0.f, a3 = 0.f, wsum = 0.f;
    int e8 = q & 7;
    for (int c0 = 0; c0 < deg; c0 += 16) {
        int idx0 = c0 + e8;
        int idx1 = c0 + 8 + e8;
        int s0 = csr[start + min(idx0, deg - 1)];
        int s1 = csr[start + min(idx1, deg - 1)];
        float w0l = (idx0 < deg) ? __expf(leaky(es2[s0] + edv)) : 0.f;
        float w1l = (idx1 < deg) ? __expf(leaky(es2[s1] + edv)) : 0.f;
        wsum += w0l + w1l;
        int se[16];
#pragma unroll
        for (int e = 0; e < 8; ++e) se[e] = __shfl(s0, gbase | e);
#pragma unroll
        for (int e = 8; e < 16; ++e) se[e] = __shfl(s1, gbase | (e - 8));
        unsigned rv[16];
#pragma unroll
        for (int e = 0; e < 16; ++e)
            rv[e] = *(const unsigned*)(hrow + ((size_t)(unsigned)se[e] << 6));
#pragma unroll
        for (int e = 0; e < 16; ++e) {
            float wl = (e < 8) ? w0l : w1l;
            float we = __shfl(wl, gbase | (e & 7));
            f32x2 p;
            p = __builtin_amdgcn_cvt_pk_f32_fp8((int)rv[e], false); a0 += we * p.x; a1 += we * p.y;
            p = __builtin_amdgcn_cvt_pk_f32_fp8((int)rv[e], true);  a2 += we * p.x; a3 += we * p.y;
        }
    }
    wsum += __shfl_xor(wsum, 1);
    wsum += __shfl_xor(wsum, 2);
    wsum += __shfl_xor(wsum, 4);        // sum over 8-group; both halves complete
    float inv = 1.f / wsum;
    float4 Av = *(const float4*)&A2s[q * 4];
    float4 Bv = *(const float4*)&B2s[q * 4];
    ot[dl][q * 4 + 0] = a0 * inv * Av.x + Bv.x;
    ot[dl][q * 4 + 1] = a1 * inv * Av.y + Bv.y;
    ot[dl][q * 4 + 2] = a2 * inv * Av.z + Bv.z;
    ot[dl][q * 4 + 3] = a3 * inv * Av.w + Bv.w;
    if (tid < 16) gbat[tid] = batch[nbase + tid];
    __syncthreads();
    if (tid < 64) {
        int ch = tid;
        int curg = gbat[0];
        float acc = 0.f;
#pragma unroll
        for (int n = 0; n < 16; ++n) {
            int g = gbat[n];
            if (g != curg) {
                atomicAdd(&pooled[curg * 64 + ch], acc);
                acc = 0.f;
                curg = g;
            }
            acc += ot[n][ch];
        }
        atomicAdd(&pooled[curg * 64 + ch], acc);
    }
}

// ---------------- MLP head + log_softmax (divide + slot->real mapping) -------

__device__ int lower_bound_i(const int* a, int n, int key) {
    int lo = 0, hi = n;
    while (lo < hi) {
        int mid = (lo + hi) >> 1;
        if (a[mid] < key) lo = mid + 1; else hi = mid;
    }
    return lo;
}

__global__ void k_head(const float* __restrict__ pooled, const int* __restrict__ batch,
                       const float* __restrict__ lw1, const float* __restrict__ lb1,
                       const float* __restrict__ lw2, const float* __restrict__ lb2,
                       float* __restrict__ out) {
    int g = threadIdx.x;
    if (g >= GGRAPHS) return;
    int s0 = lower_bound_i(batch, N_NODES, g);
    int s1 = lower_bound_i(batch, N_NODES, g + 1);
    int cnt = s1 - s0;
    float invc = 1.f / (float)((cnt > 0) ? cnt : 1);
    float p[64];
#pragma unroll
    for (int c = 0; c < 64; ++c) p[c] = pooled[g * 64 + c] * invc;
    float z0 = lb2[0], z1 = lb2[1], z2 = lb2[2];
    for (int j = 0; j < 32; ++j) {
        float hj = lb1[j];
#pragma unroll
        for (int c = 0; c < 64; ++c) {
            int rc = (c & 3) * 16 + (c >> 2);    // slot c holds real channel rc
            hj += p[c] * lw1[rc * 32 + j];
        }
        hj = fmaxf(hj, 0.f);
        z0 += hj * lw2[j * 3 + 0];
        z1 += hj * lw2[j * 3 + 1];
        z2 += hj * lw2[j * 3 + 2];
    }
    float m = fmaxf(z0, fmaxf(z1, z2));
    float lse = logf(expf(z0 - m) + expf(z1 - m) + expf(z2 - m)) + m;
    out[g * 3 + 0] = z0 - lse;
    out[g * 3 + 1] = z1 - lse;
    out[g * 3 + 2] = z2 - lse;
}

// ---------------- launch ----------------

extern "C" void kernel_launch(void* const* d_in, const int* in_sizes, int n_in,
                              void* d_out, int out_size, void* d_ws, size_t ws_size,
                              hipStream_t stream) {
    (void)in_sizes; (void)n_in; (void)out_size; (void)ws_size;
    const float* x    = (const float*)d_in[0];
    const int*   ei   = (const int*)d_in[1];
    const int*   batch= (const int*)d_in[2];
    const float* W1   = (const float*)d_in[3];
    const float* a_s1 = (const float*)d_in[4];
    const float* a_d1 = (const float*)d_in[5];
    const float* b1   = (const float*)d_in[6];
    const float* g1   = (const float*)d_in[7];
    const float* be1  = (const float*)d_in[8];
    const float* m1   = (const float*)d_in[9];
    const float* v1   = (const float*)d_in[10];
    const float* W2   = (const float*)d_in[11];
    const float* a_s2 = (const float*)d_in[12];
    const float* a_d2 = (const float*)d_in[13];
    const float* b2   = (const float*)d_in[14];
    const float* g2   = (const float*)d_in[15];
    const float* be2  = (const float*)d_in[16];
    const float* m2   = (const float*)d_in[17];
    const float* v2   = (const float*)d_in[18];
    const float* lw1  = (const float*)d_in[19];
    const float* lb1  = (const float*)d_in[20];
    const float* lw2  = (const float*)d_in[21];
    const float* lb2  = (const float*)d_in[22];
    float* out = (float*)d_out;

    char* ws = (char*)d_ws;
    size_t off = 0;
    auto alloc = [&](size_t bytes) -> void* {
        void* p = ws + off;
        off += (bytes + 255) & ~(size_t)255;
        return p;
    };
    float* pooled = (float*)alloc((size_t)GGRAPHS * 64 * 4);     // 16384 B
    int*   gcur   = (int*)alloc((size_t)NBUK * 4);               // -> 1024 B slot
    unsigned short* W2T = (unsigned short*)alloc((size_t)16384 * 2);
    unsigned char*  h1  = (unsigned char*)alloc((size_t)N_NODES * 256);   // fp8 perm
    unsigned char*  h2  = (unsigned char*)alloc((size_t)N_NODES * 64);    // fp8 perm
    float* es1  = (float*)alloc((size_t)N_NODES * 4 * 4);
    float* ed1  = (float*)alloc((size_t)N_NODES * 4 * 4);
    float* es2  = (float*)alloc((size_t)N_NODES * 4);
    float* ed2  = (float*)alloc((size_t)N_NODES * 4);
    float* A1s  = (float*)alloc(256 * 4);
    float* B1s  = (float*)alloc(256 * 4);
    float* A2s  = (float*)alloc(64 * 4);
    float* B2s  = (float*)alloc(64 * 4);
    int*   offs = (int*)alloc((size_t)(N_NODES + 1) * 4);
    unsigned short* csr = (unsigned short*)alloc((size_t)ETOT * 2);
    unsigned* pairs = (unsigned*)alloc((size_t)NBUK * CAPR * 4);

    const int ngat = 3125;                     // 16 nodes per block

    hipMemsetAsync(pooled, 0, 16384 + 1024, stream);   // pooled + gcur
    k_mega<<<NMEGA, 256, 0, stream>>>(x, ei, W1, W2,
                                      b1, g1, be1, m1, v1,
                                      b2, g2, be2, m2, v2,
                                      a_s1, a_d1,
                                      W2T, A1s, B1s, A2s, B2s,
                                      gcur, pairs, h1, es1, ed1);
    k_csr<<<NBUK, 256, 0, stream>>>(pairs, gcur, offs, csr);
    k_gat1g2<<<ngat, 256, 0, stream>>>(h1, es1, ed1, offs, csr, A1s, B1s,
                                       W2T, a_s2, a_d2, h2, es2, ed2);
    k_gat2p<<<ngat, 256, 0, stream>>>(h2, es2, ed2, offs, csr, A2s, B2s,
                                      batch, pooled);
    k_head<<<1, 64, 0, stream>>>(pooled, batch, lw1, lb1, lw2, lb2, out);
}